// Round 10
// baseline (235.113 us; speedup 1.0000x reference)
//
#include <hip/hip_runtime.h>
#include <cfloat>
#include <cstdint>

#define BATCH 2
#define NSEQ 2048
#define CIN 512
#define HEADS 8
#define DIM 64
#define HD 512
#define QKV3 1536

typedef short short8 __attribute__((ext_vector_type(8)));
typedef float f32x4 __attribute__((ext_vector_type(4)));
typedef unsigned short ushort_t;

__device__ __forceinline__ unsigned short f2bf(float f) {
    return (unsigned short)(__float_as_uint(f) >> 16);
}
__device__ __forceinline__ float bf2f(unsigned short h) {
    return __uint_as_float(((unsigned int)h) << 16);
}

// ---------- split + transpose BOTH weights in one launch ------------------
__global__ __launch_bounds__(256) void split_wT_kernel(
    const float* __restrict__ Wq, const float* __restrict__ Wo,
    ushort_t* __restrict__ WqTh, ushort_t* __restrict__ WqTl,
    ushort_t* __restrict__ WoTh, ushort_t* __restrict__ WoTl)
{
    __shared__ float T[64][65];
    const int bx = blockIdx.x;
    const float* W; ushort_t *WTh, *WTl; int N, n0;
    if (bx < 24) { W = Wq; WTh = WqTh; WTl = WqTl; N = QKV3; n0 = bx * 64; }
    else         { W = Wo; WTh = WoTh; WTl = WoTl; N = HD;   n0 = (bx - 24) * 64; }
    const int K = CIN;
    const int k0 = blockIdx.y * 64;
    const int tid = threadIdx.x;
    #pragma unroll
    for (int i = 0; i < 4; ++i) {
        int c = tid + i * 256;
        int row = c >> 4, c4 = c & 15;
        *(float4*)&T[row][c4*4] = *(const float4*)(W + (size_t)(k0 + row) * N + n0 + c4*4);
    }
    __syncthreads();
    const int n = tid >> 2, kseg = tid & 3;
    short8 hh0, ll0, hh1, ll1;
    #pragma unroll
    for (int e = 0; e < 8; ++e) {
        float x0 = T[kseg*16 + e][n];
        unsigned short h0 = f2bf(x0);
        hh0[e] = (short)h0; ll0[e] = (short)f2bf(x0 - bf2f(h0));
        float x1 = T[kseg*16 + 8 + e][n];
        unsigned short h1 = f2bf(x1);
        hh1[e] = (short)h1; ll1[e] = (short)f2bf(x1 - bf2f(h1));
    }
    size_t o = (size_t)(n0 + n) * K + k0 + kseg * 16;
    *(short8*)(WTh + o)     = hh0;
    *(short8*)(WTh + o + 8) = hh1;
    *(short8*)(WTl + o)     = ll0;
    *(short8*)(WTl + o + 8) = ll1;
}

// ---------- MFMA GEMM, A f32 in LDS: C[M][N] = A @ BT[N][K](bf16 h/l) -----
// BM=128 BN=64 BK=64; LDS 52.2KB -> 3 blocks/CU co-schedulable
__global__ __launch_bounds__(256, 2) void gemm_f32A_kernel(
    const float* __restrict__ A, const ushort_t* __restrict__ BTh,
    const ushort_t* __restrict__ BTl, float* __restrict__ C,
    int M, int N, int K)
{
    __shared__ float As[128][68];                  // 34,816 B
    __shared__ ushort_t Bsh[64][72], Bsl[64][72];  // 18,432 B
    const int bm = blockIdx.y * 128, bn = blockIdx.x * 64;
    const int tid = threadIdx.x;
    const int wave = tid >> 6, lane = tid & 63;
    const int lg = lane >> 4, lm = lane & 15;
    const int wm = wave >> 1, wn = wave & 1;
    const int arow = tid >> 3, aseg = tid & 7;

    f32x4 acc[4][2];
    #pragma unroll
    for (int mf = 0; mf < 4; ++mf)
        #pragma unroll
        for (int nf = 0; nf < 2; ++nf) acc[mf][nf] = (f32x4){0.f,0.f,0.f,0.f};

    float4 ar[8];
    uint4 brh[2], brl[2];
    const int nkt = K >> 6;

    #define G_ISSUE(K0)                                                          \
        { _Pragma("unroll")                                                      \
          for (int i = 0; i < 4; ++i) {                                          \
            const float* ap = A + (size_t)(bm + arow + 32*i) * K + (K0) + aseg*8;\
            ar[2*i]   = *(const float4*)ap;                                      \
            ar[2*i+1] = *(const float4*)(ap + 4);                                \
          }                                                                      \
          _Pragma("unroll")                                                      \
          for (int i = 0; i < 2; ++i) {                                          \
            size_t bo = (size_t)(bn + arow + 32*i) * K + (K0) + aseg*8;          \
            brh[i] = *(const uint4*)(BTh + bo);                                  \
            brl[i] = *(const uint4*)(BTl + bo);                                  \
          } }

    G_ISSUE(0)
    for (int kt = 0; kt < nkt; ++kt) {
        __syncthreads();
        #pragma unroll
        for (int i = 0; i < 4; ++i) {
            *(float4*)&As[arow + 32*i][aseg*8]     = ar[2*i];
            *(float4*)&As[arow + 32*i][aseg*8 + 4] = ar[2*i+1];
        }
        #pragma unroll
        for (int i = 0; i < 2; ++i) {
            *(uint4*)&Bsh[arow + 32*i][aseg*8] = brh[i];
            *(uint4*)&Bsl[arow + 32*i][aseg*8] = brl[i];
        }
        if (kt + 1 < nkt) G_ISSUE((kt + 1) * 64)
        __syncthreads();
        #pragma unroll
        for (int ks = 0; ks < 2; ++ks) {
            short8 afh[4], afl[4], bfh[2], bfl[2];
            #pragma unroll
            for (int mf = 0; mf < 4; ++mf) {
                float a[8];
                *(float4*)&a[0] = *(const float4*)&As[wm*64 + mf*16 + lm][ks*32 + lg*8];
                *(float4*)&a[4] = *(const float4*)&As[wm*64 + mf*16 + lm][ks*32 + lg*8 + 4];
                #pragma unroll
                for (int e = 0; e < 8; ++e) {
                    unsigned short hi = f2bf(a[e]);
                    afh[mf][e] = (short)hi;
                    afl[mf][e] = (short)f2bf(a[e] - bf2f(hi));
                }
            }
            #pragma unroll
            for (int nf = 0; nf < 2; ++nf) {
                bfh[nf] = *(const short8*)&Bsh[wn*32 + nf*16 + lm][ks*32 + lg*8];
                bfl[nf] = *(const short8*)&Bsl[wn*32 + nf*16 + lm][ks*32 + lg*8];
            }
            #pragma unroll
            for (int mf = 0; mf < 4; ++mf)
                #pragma unroll
                for (int nf = 0; nf < 2; ++nf) {
                    acc[mf][nf] = __builtin_amdgcn_mfma_f32_16x16x32_bf16(afh[mf], bfh[nf], acc[mf][nf], 0, 0, 0);
                    acc[mf][nf] = __builtin_amdgcn_mfma_f32_16x16x32_bf16(afh[mf], bfl[nf], acc[mf][nf], 0, 0, 0);
                    acc[mf][nf] = __builtin_amdgcn_mfma_f32_16x16x32_bf16(afl[mf], bfh[nf], acc[mf][nf], 0, 0, 0);
                }
        }
    }
    #pragma unroll
    for (int mf = 0; mf < 4; ++mf)
        #pragma unroll
        for (int nf = 0; nf < 2; ++nf)
            #pragma unroll
            for (int r = 0; r < 4; ++r)
                C[(size_t)(bm + wm*64 + mf*16 + lg*4 + r) * N + bn + wn*32 + nf*16 + lm]
                    = acc[mf][nf][r];
    #undef G_ISSUE
}

// ---------- out-proj GEMM with FUSED 3-way merge of attn partials --------
// out[M][512] = merge(Opart,Ml) @ WoutT;  BM=64 BN=64 BK=64 (h = kt)
__global__ __launch_bounds__(256, 2) void gemm_merge_kernel(
    const float* __restrict__ Opart, const float* __restrict__ Ml,
    const ushort_t* __restrict__ BTh, const ushort_t* __restrict__ BTl,
    float* __restrict__ C)
{
    __shared__ float As[64][68];                   // 17,408 B
    __shared__ ushort_t Bsh[64][72], Bsl[64][72];  // 18,432 B
    const int bm = blockIdx.y * 64, bn = blockIdx.x * 64;
    const int tid = threadIdx.x;
    const int wave = tid >> 6, lane = tid & 63;
    const int lg = lane >> 4, lm = lane & 15;
    const int wm = wave >> 1, wn = wave & 1;
    const int srow = tid >> 2, sseg = tid & 3;    // stage: 64 rows x 4 segs

    f32x4 acc[2][2];
    #pragma unroll
    for (int mf = 0; mf < 2; ++mf)
        #pragma unroll
        for (int nf = 0; nf < 2; ++nf) acc[mf][nf] = (f32x4){0.f,0.f,0.f,0.f};

    float4 ar[4];
    uint4 brh[2], brl[2];

    #define GM_ISSUE(KT) {                                                      \
        const int h_ = (KT);                                                    \
        const int mrow = bm + srow;                                             \
        const int b_ = mrow >> 11, n_ = mrow & (NSEQ - 1);                      \
        float mv0, mv1, mv2, lv0, lv1, lv2;                                     \
        { size_t mi = ((size_t)(b_*8 + h_) * NSEQ + n_) * 2;                    \
          mv0 = Ml[mi]; lv0 = Ml[mi+1];                                         \
          mi = ((size_t)(16 + b_*8 + h_) * NSEQ + n_) * 2;                      \
          mv1 = Ml[mi]; lv1 = Ml[mi+1];                                         \
          mi = ((size_t)(32 + b_*8 + h_) * NSEQ + n_) * 2;                      \
          mv2 = Ml[mi]; lv2 = Ml[mi+1]; }                                       \
        float mm = fmaxf(fmaxf(mv0, mv1), mv2);                                 \
        float w0 = __expf(mv0 - mm), w1 = __expf(mv1 - mm), w2 = __expf(mv2 - mm);\
        float inv = 1.f / (lv0*w0 + lv1*w1 + lv2*w2);                           \
        size_t o0 = ((size_t)(b_*8 + h_) * NSEQ + n_) * 64 + sseg*16;           \
        size_t o1 = ((size_t)(16 + b_*8 + h_) * NSEQ + n_) * 64 + sseg*16;      \
        size_t o2 = ((size_t)(32 + b_*8 + h_) * NSEQ + n_) * 64 + sseg*16;      \
        _Pragma("unroll")                                                       \
        for (int c = 0; c < 4; ++c) {                                           \
            float4 v0 = *(const float4*)(Opart + o0 + c*4);                     \
            float4 v1 = *(const float4*)(Opart + o1 + c*4);                     \
            float4 v2 = *(const float4*)(Opart + o2 + c*4);                     \
            ar[c].x = (v0.x*w0 + v1.x*w1 + v2.x*w2) * inv;                      \
            ar[c].y = (v0.y*w0 + v1.y*w1 + v2.y*w2) * inv;                      \
            ar[c].z = (v0.z*w0 + v1.z*w1 + v2.z*w2) * inv;                      \
            ar[c].w = (v0.w*w0 + v1.w*w1 + v2.w*w2) * inv;                      \
        }                                                                       \
        size_t bo = (size_t)(bn + srow) * CIN + (KT)*64 + sseg*16;              \
        brh[0] = *(const uint4*)(BTh + bo);                                     \
        brh[1] = *(const uint4*)(BTh + bo + 8);                                 \
        brl[0] = *(const uint4*)(BTl + bo);                                     \
        brl[1] = *(const uint4*)(BTl + bo + 8); }

    GM_ISSUE(0)
    for (int kt = 0; kt < 8; ++kt) {
        __syncthreads();
        *(float4*)&As[srow][sseg*16]      = ar[0];
        *(float4*)&As[srow][sseg*16 + 4]  = ar[1];
        *(float4*)&As[srow][sseg*16 + 8]  = ar[2];
        *(float4*)&As[srow][sseg*16 + 12] = ar[3];
        *(uint4*)&Bsh[srow][sseg*16]     = brh[0];
        *(uint4*)&Bsh[srow][sseg*16 + 8] = brh[1];
        *(uint4*)&Bsl[srow][sseg*16]     = brl[0];
        *(uint4*)&Bsl[srow][sseg*16 + 8] = brl[1];
        if (kt + 1 < 8) GM_ISSUE(kt + 1)
        __syncthreads();
        #pragma unroll
        for (int ks = 0; ks < 2; ++ks) {
            short8 afh[2], afl[2], bfh[2], bfl[2];
            #pragma unroll
            for (int mf = 0; mf < 2; ++mf) {
                float a[8];
                *(float4*)&a[0] = *(const float4*)&As[wm*32 + mf*16 + lm][ks*32 + lg*8];
                *(float4*)&a[4] = *(const float4*)&As[wm*32 + mf*16 + lm][ks*32 + lg*8 + 4];
                #pragma unroll
                for (int e = 0; e < 8; ++e) {
                    unsigned short hi = f2bf(a[e]);
                    afh[mf][e] = (short)hi;
                    afl[mf][e] = (short)f2bf(a[e] - bf2f(hi));
                }
            }
            #pragma unroll
            for (int nf = 0; nf < 2; ++nf) {
                bfh[nf] = *(const short8*)&Bsh[wn*32 + nf*16 + lm][ks*32 + lg*8];
                bfl[nf] = *(const short8*)&Bsl[wn*32 + nf*16 + lm][ks*32 + lg*8];
            }
            #pragma unroll
            for (int mf = 0; mf < 2; ++mf)
                #pragma unroll
                for (int nf = 0; nf < 2; ++nf) {
                    acc[mf][nf] = __builtin_amdgcn_mfma_f32_16x16x32_bf16(afh[mf], bfh[nf], acc[mf][nf], 0, 0, 0);
                    acc[mf][nf] = __builtin_amdgcn_mfma_f32_16x16x32_bf16(afh[mf], bfl[nf], acc[mf][nf], 0, 0, 0);
                    acc[mf][nf] = __builtin_amdgcn_mfma_f32_16x16x32_bf16(afl[mf], bfh[nf], acc[mf][nf], 0, 0, 0);
                }
        }
    }
    #pragma unroll
    for (int mf = 0; mf < 2; ++mf)
        #pragma unroll
        for (int nf = 0; nf < 2; ++nf)
            #pragma unroll
            for (int r = 0; r < 4; ++r)
                C[(size_t)(bm + wm*32 + mf*16 + lg*4 + r) * CIN + bn + wn*32 + nf*16 + lm]
                    = acc[mf][nf][r];
    #undef GM_ISSUE
}

// ------- fused qkv prep: l2norm+split Q,K  and  transposed/permuted V ----
__global__ __launch_bounds__(256) void qkv_prep_kernel(
    const float* __restrict__ qkv,
    ushort_t* __restrict__ Qh, ushort_t* __restrict__ Ql,
    ushort_t* __restrict__ Kh, ushort_t* __restrict__ Kl,
    ushort_t* __restrict__ Vth, ushort_t* __restrict__ Vtl)
{
    __shared__ float Vf[64][65];
    const int id = blockIdx.x;
    const int bh = id >> 5, nt = id & 31;
    const int b = bh >> 3, h = bh & 7;
    const int n0 = nt * 64;
    const int tid = threadIdx.x;
    {
        const int row = tid >> 2, dseg = tid & 3;
        const float* src = qkv + ((size_t)(b * NSEQ + n0 + row)) * QKV3
                         + h * 192 + dseg * 48;
        float f[48];
        #pragma unroll
        for (int i = 0; i < 12; ++i)
            *(float4*)&f[i*4] = *(const float4*)(src + i*4);
        float nq = 0.f, nk = 0.f;
        #pragma unroll
        for (int e = 0; e < 16; ++e) {
            nq = fmaf(f[3*e], f[3*e], nq);
            nk = fmaf(f[3*e+1], f[3*e+1], nk);
        }
        nq += __shfl_xor(nq, 1); nq += __shfl_xor(nq, 2);
        nk += __shfl_xor(nk, 1); nk += __shfl_xor(nk, 2);
        float rq = 1.f / fmaxf(sqrtf(nq), 1e-12f);
        float rk = 1.f / fmaxf(sqrtf(nk), 1e-12f);
        short8 qh8[2], ql8[2], kh8[2], kl8[2];
        #pragma unroll
        for (int e = 0; e < 16; ++e) {
            float q = f[3*e] * rq, k = f[3*e+1] * rk;
            unsigned short qhi = f2bf(q), khi = f2bf(k);
            qh8[e>>3][e&7] = (short)qhi;
            ql8[e>>3][e&7] = (short)f2bf(q - bf2f(qhi));
            kh8[e>>3][e&7] = (short)khi;
            kl8[e>>3][e&7] = (short)f2bf(k - bf2f(khi));
            Vf[dseg*16 + e][row] = f[3*e+2];
        }
        size_t o = ((size_t)bh * NSEQ + n0 + row) * DIM + dseg * 16;
        *(short8*)(Qh + o) = qh8[0]; *(short8*)(Qh + o + 8) = qh8[1];
        *(short8*)(Ql + o) = ql8[0]; *(short8*)(Ql + o + 8) = ql8[1];
        *(short8*)(Kh + o) = kh8[0]; *(short8*)(Kh + o + 8) = kh8[1];
        *(short8*)(Kl + o) = kl8[0]; *(short8*)(Kl + o + 8) = kl8[1];
    }
    __syncthreads();
    {   // Vt[bh][d][n] with the PV fragment j-permutation (within 32-blocks)
        const int d = tid >> 2, seg = tid & 3;
        ushort_t th[16], tl[16];
        #pragma unroll
        for (int t = 0; t < 16; ++t) {
            int p = seg * 16 + t;
            int s = (p & 35) | ((p & 4) << 2) | ((p >> 1) & 12);
            float v = Vf[d][s];
            unsigned short hi = f2bf(v);
            th[t] = hi;
            tl[t] = f2bf(v - bf2f(hi));
        }
        size_t o = ((size_t)bh * DIM + d) * NSEQ + n0 + seg * 16;
        *(uint4*)(Vth + o)     = *(uint4*)&th[0];
        *(uint4*)(Vth + o + 8) = *(uint4*)&th[8];
        *(uint4*)(Vtl + o)     = *(uint4*)&tl[0];
        *(uint4*)(Vtl + o + 8) = *(uint4*)&tl[8];
    }
}

// ---------------- MFMA flash attention (R7-proven, j-split 3) ------------
__global__ __launch_bounds__(256, 3) void attn_mfma_kernel(
    const ushort_t* __restrict__ Qh, const ushort_t* __restrict__ Ql,
    const ushort_t* __restrict__ Kh, const ushort_t* __restrict__ Kl,
    const ushort_t* __restrict__ Vth, const ushort_t* __restrict__ Vtl,
    const float* __restrict__ bias, const float* __restrict__ temp_p,
    const uint8_t* __restrict__ mask,
    float* __restrict__ Opart, float* __restrict__ Ml,
    int ns, int base, int rem)
{
    __shared__ ushort_t KsH[2][32][72], KsL[2][32][72];   // [buf][j][d]
    __shared__ ushort_t VsH[2][64][36], VsL[2][64][36];   // [buf][d][j-perm]

    const int id = blockIdx.x;
    const int h = id & 7;                  // XCD-grouped
    const int rest = id >> 3;
    const int per_b = 16 * ns;
    const int b = rest / per_b;
    const int r2 = rest - b * per_b;
    const int js = r2 >> 4;
    const int qt = r2 & 15;
    const int bh = b * 8 + h;
    const int i0 = qt * 128;
    const int tid = threadIdx.x;
    const int wave = tid >> 6, lane = tid & 63;
    const int lg = lane >> 4, lm = lane & 15;
    const int qbase = i0 + wave * 32;
    const float temp = *temp_p;
    const int krow = tid >> 3, kseg = tid & 7;
    const int vrow = tid >> 2, vseg = tid & 3;

    short8 qfh[2][2], qfl[2][2];
    #pragma unroll
    for (int m = 0; m < 2; ++m) {
        size_t qo = ((size_t)(bh * NSEQ + qbase + 16*m + lm)) * DIM + lg * 8;
        qfh[m][0] = *(const short8*)(Qh + qo);
        qfh[m][1] = *(const short8*)(Qh + qo + 32);
        qfl[m][0] = *(const short8*)(Ql + qo);
        qfl[m][1] = *(const short8*)(Ql + qo + 32);
    }
    bool rowm[2];
    rowm[0] = mask[(size_t)b * NSEQ + qbase + lm] != 0;
    rowm[1] = mask[(size_t)b * NSEQ + qbase + 16 + lm] != 0;

    float m_r[2] = {-FLT_MAX, -FLT_MAX};
    float l_r[2] = {0.f, 0.f};
    f32x4 oa[2][4];
    #pragma unroll
    for (int m = 0; m < 2; ++m)
        #pragma unroll
        for (int dt = 0; dt < 4; ++dt) oa[m][dt] = (f32x4){0.f,0.f,0.f,0.f};

    const int NT = base + (js < rem ? 1 : 0);
    const int tstart = js * base + (js < rem ? js : rem);
    const int jbase = tstart * 32;
    uint4 skh, skl, svh, svl;

    #define A_ISSUE(J0) {                                                      \
        size_t gk = ((size_t)(bh * NSEQ) + (J0) + krow) * DIM + kseg*8;        \
        size_t gv = ((size_t)(bh * DIM) + vrow) * NSEQ + (J0) + vseg*8;        \
        skh = *(const uint4*)(Kh  + gk);                                       \
        skl = *(const uint4*)(Kl  + gk);                                       \
        svh = *(const uint4*)(Vth + gv);                                       \
        svl = *(const uint4*)(Vtl + gv); }
    #define STAGE(BUF) {                                                       \
        *(uint4*)&KsH[BUF][krow][kseg*8] = skh;                                \
        *(uint4*)&KsL[BUF][krow][kseg*8] = skl;                                \
        *(uint4*)&VsH[BUF][vrow][vseg*8] = svh;                                \
        *(uint4*)&VsL[BUF][vrow][vseg*8] = svl; }

    A_ISSUE(jbase)
    STAGE(0)
    A_ISSUE(jbase + 32)
    float4 bb[2][2];
    #pragma unroll
    for (int m = 0; m < 2; ++m)
        #pragma unroll
        for (int jt = 0; jt < 2; ++jt)
            bb[m][jt] = *(const float4*)(bias
                + ((size_t)h * NSEQ + qbase + 16*m + lm) * NSEQ
                + jbase + jt*16 + lg*4);
    uint8_t mk = mask[(size_t)b * NSEQ + jbase + (lane & 31)];
    __syncthreads();

    #pragma unroll 2
    for (int t = 0; t < NT; ++t) {
        const int cur = t & 1;
        const int j0 = jbase + t * 32;

        float4 bbn[2][2];
        uint8_t mkn = 0;
        if (t + 1 < NT) {
            #pragma unroll
            for (int m = 0; m < 2; ++m)
                #pragma unroll
                for (int jt = 0; jt < 2; ++jt)
                    bbn[m][jt] = *(const float4*)(bias
                        + ((size_t)h * NSEQ + qbase + 16*m + lm) * NSEQ
                        + j0 + 32 + jt*16 + lg*4);
            mkn = mask[(size_t)b * NSEQ + j0 + 32 + (lane & 31)];
            STAGE(cur ^ 1)
            if (t + 2 < NT) A_ISSUE(j0 + 64)
        }
        unsigned long long bal = __ballot(mk != 0);

        f32x4 sac[2][2];
        #pragma unroll
        for (int m = 0; m < 2; ++m)
            #pragma unroll
            for (int jt = 0; jt < 2; ++jt) sac[m][jt] = (f32x4){0.f,0.f,0.f,0.f};
        __builtin_amdgcn_s_setprio(1);
        #pragma unroll
        for (int jt = 0; jt < 2; ++jt)
            #pragma unroll
            for (int ks = 0; ks < 2; ++ks) {
                short8 kbh = *(const short8*)(&KsH[cur][jt*16 + lm][ks*32 + lg*8]);
                short8 kbl = *(const short8*)(&KsL[cur][jt*16 + lm][ks*32 + lg*8]);
                #pragma unroll
                for (int m = 0; m < 2; ++m) {
                    sac[m][jt] = __builtin_amdgcn_mfma_f32_16x16x32_bf16(kbh, qfh[m][ks], sac[m][jt], 0, 0, 0);
                    sac[m][jt] = __builtin_amdgcn_mfma_f32_16x16x32_bf16(kbh, qfl[m][ks], sac[m][jt], 0, 0, 0);
                    sac[m][jt] = __builtin_amdgcn_mfma_f32_16x16x32_bf16(kbl, qfh[m][ks], sac[m][jt], 0, 0, 0);
                }
            }
        __builtin_amdgcn_s_setprio(0);

        short8 pah[2], pal[2];
        #pragma unroll
        for (int m = 0; m < 2; ++m) {
            float sv[2][4];
            #pragma unroll
            for (int jt = 0; jt < 2; ++jt) {
                unsigned int nib = (unsigned int)(bal >> (jt*16 + lg*4)) & 0xFu;
                #pragma unroll
                for (int r = 0; r < 4; ++r) {
                    bool dead = rowm[m] || ((nib >> r) & 1u);
                    float bv = (r == 0) ? bb[m][jt].x : (r == 1) ? bb[m][jt].y
                             : (r == 2) ? bb[m][jt].z : bb[m][jt].w;
                    sv[jt][r] = dead ? -FLT_MAX : fmaf(sac[m][jt][r], temp, bv);
                }
            }
            float pmax = fmaxf(fmaxf(fmaxf(sv[0][0], sv[0][1]), fmaxf(sv[0][2], sv[0][3])),
                               fmaxf(fmaxf(sv[1][0], sv[1][1]), fmaxf(sv[1][2], sv[1][3])));
            pmax = fmaxf(pmax, __shfl_xor(pmax, 16));
            pmax = fmaxf(pmax, __shfl_xor(pmax, 32));
            if (!__all(pmax <= m_r[m] + 8.f)) {
                float mn = fmaxf(m_r[m], pmax);
                float sc = __expf(m_r[m] - mn);
                m_r[m] = mn;
                l_r[m] *= sc;
                #pragma unroll
                for (int r = 0; r < 4; ++r) {
                    float sq = __shfl(sc, lg*4 + r);
                    #pragma unroll
                    for (int dt = 0; dt < 4; ++dt) oa[m][dt][r] *= sq;
                }
            }
            float rs = 0.f;
            #pragma unroll
            for (int jt = 0; jt < 2; ++jt)
                #pragma unroll
                for (int r = 0; r < 4; ++r) {
                    float pf = __expf(sv[jt][r] - m_r[m]);
                    rs += pf;
                    unsigned short hi = f2bf(pf);
                    pah[m][jt*4 + r] = (short)hi;
                    pal[m][jt*4 + r] = (short)f2bf(pf - bf2f(hi));
                }
            rs += __shfl_xor(rs, 16);
            rs += __shfl_xor(rs, 32);
            l_r[m] += rs;
        }

        __builtin_amdgcn_s_setprio(1);
        #pragma unroll
        for (int dt = 0; dt < 4; ++dt) {
            short8 vbh = *(const short8*)(&VsH[cur][dt*16 + lm][lg*8]);
            short8 vbl = *(const short8*)(&VsL[cur][dt*16 + lm][lg*8]);
            #pragma unroll
            for (int m = 0; m < 2; ++m) {
                oa[m][dt] = __builtin_amdgcn_mfma_f32_16x16x32_bf16(pah[m], vbh, oa[m][dt], 0, 0, 0);
                oa[m][dt] = __builtin_amdgcn_mfma_f32_16x16x32_bf16(pah[m], vbl, oa[m][dt], 0, 0, 0);
                oa[m][dt] = __builtin_amdgcn_mfma_f32_16x16x32_bf16(pal[m], vbh, oa[m][dt], 0, 0, 0);
            }
        }
        __builtin_amdgcn_s_setprio(0);
        __syncthreads();
        #pragma unroll
        for (int m = 0; m < 2; ++m)
            #pragma unroll
            for (int jt = 0; jt < 2; ++jt) bb[m][jt] = bbn[m][jt];
        mk = mkn;
    }
    #undef A_ISSUE
    #undef STAGE

    #pragma unroll
    for (int m = 0; m < 2; ++m)
        #pragma unroll
        for (int dt = 0; dt < 4; ++dt)
            #pragma unroll
            for (int r = 0; r < 4; ++r)
                Opart[((size_t)(js*16 + bh) * NSEQ + qbase + 16*m + lg*4 + r) * 64
                      + dt*16 + lm] = oa[m][dt][r];
    if (lane < 16) {
        #pragma unroll
        for (int m = 0; m < 2; ++m) {
            size_t mi = ((size_t)(js*16 + bh) * NSEQ + qbase + 16*m + lm) * 2;
            Ml[mi]     = m_r[m];
            Ml[mi + 1] = l_r[m];
        }
    }
}

extern "C" void kernel_launch(void* const* d_in, const int* in_sizes, int n_in,
                              void* d_out, int out_size, void* d_ws, size_t ws_size,
                              hipStream_t stream)
{
    const float*   x        = (const float*)d_in[0];
    const float*   w_qkv    = (const float*)d_in[1];
    const float*   w_out    = (const float*)d_in[2];
    const float*   pos_bias = (const float*)d_in[3];
    const float*   temp     = (const float*)d_in[4];
    const uint8_t* mask     = (const uint8_t*)d_in[5];
    float* out = (float*)d_out;

    const int M = BATCH * NSEQ;                        // 4096
    const size_t NE = (size_t)BATCH * HEADS * NSEQ * DIM;
    const int ns = 3;                                  // 3 j-splits: grid 768 = 3 blocks/CU exactly
    const int base = 64 / ns, rem = 64 % ns;

    char* ws = (char*)d_ws;
    // region 0 (25.2 MB): qkv_lin f32; exactly reused by the 3-split f32 Opart
    float* qkv_lin = (float*)ws;
    float* OpartP  = (float*)ws;    // 3*16*2048*64*4 B == M*QKV3*4 B exactly
    size_t off = (size_t)M * QKV3 * 4;
    // region 1: transposed/split weights + Ml
    ushort_t* WqkvTh = (ushort_t*)(ws + off); off += (size_t)QKV3 * CIN * 2;
    ushort_t* WqkvTl = (ushort_t*)(ws + off); off += (size_t)QKV3 * CIN * 2;
    ushort_t* WoutTh = (ushort_t*)(ws + off); off += (size_t)HD * CIN * 2;
    ushort_t* WoutTl = (ushort_t*)(ws + off); off += (size_t)HD * CIN * 2;
    float*    MlP    = (float*)(ws + off);    off += (size_t)ns * 16 * NSEQ * 2 * 4;
    // region 2 (25.2 MB): Q/K/Vt bf16 hi/lo
    char* reg2 = ws + off;
    ushort_t* Qh  = (ushort_t*)reg2;
    ushort_t* Ql  = Qh + NE;
    ushort_t* Kh  = Ql + NE;
    ushort_t* Kl  = Kh + NE;
    ushort_t* Vth = Kl + NE;
    ushort_t* Vtl = Vth + NE;

    // 1. both weight splits in one launch
    split_wT_kernel<<<dim3(32, CIN/64), 256, 0, stream>>>(
        w_qkv, w_out, WqkvTh, WqkvTl, WoutTh, WoutTl);
    // 2. qkv projection (f32-A LDS, 52KB -> 3 blocks/CU)
    gemm_f32A_kernel<<<dim3(QKV3/64, M/128), 256, 0, stream>>>(
        x, WqkvTh, WqkvTl, qkv_lin, M, QKV3, CIN);
    // 3. fused l2norm/split + V transpose
    qkv_prep_kernel<<<dim3(BATCH * HEADS * (NSEQ/64)), 256, 0, stream>>>(
        qkv_lin, Qh, Ql, Kh, Kl, Vth, Vtl);
    // 4. attention (j-split 3; Opart overwrites qkv_lin)
    attn_mfma_kernel<<<dim3(256 * ns), 256, 0, stream>>>(
        Qh, Ql, Kh, Kl, Vth, Vtl, pos_bias, temp, mask, OpartP, MlP,
        ns, base, rem);
    // 5. out projection with fused 3-way merge (reads Opart+Ml directly)
    gemm_merge_kernel<<<dim3(CIN/64, M/64), 256, 0, stream>>>(
        OpartP, MlP, WoutTh, WoutTl, out);
}

// Round 11
// 201.723 us; speedup vs baseline: 1.1655x; 1.1655x over previous
//
#include <hip/hip_runtime.h>
#include <cfloat>
#include <cstdint>

#define BATCH 2
#define NSEQ 2048
#define CIN 512
#define HEADS 8
#define DIM 64
#define HD 512
#define QKV3 1536

typedef short short8 __attribute__((ext_vector_type(8)));
typedef float f32x4 __attribute__((ext_vector_type(4)));
typedef unsigned short ushort_t;

__device__ __forceinline__ unsigned short f2bf(float f) {
    return (unsigned short)(__float_as_uint(f) >> 16);
}
__device__ __forceinline__ float bf2f(unsigned short h) {
    return __uint_as_float(((unsigned int)h) << 16);
}

// ---------- split + transpose BOTH weights in one launch ------------------
__global__ __launch_bounds__(256) void split_wT_kernel(
    const float* __restrict__ Wq, const float* __restrict__ Wo,
    ushort_t* __restrict__ WqTh, ushort_t* __restrict__ WqTl,
    ushort_t* __restrict__ WoTh, ushort_t* __restrict__ WoTl)
{
    __shared__ float T[64][65];
    const int bx = blockIdx.x;
    const float* W; ushort_t *WTh, *WTl; int N, n0;
    if (bx < 24) { W = Wq; WTh = WqTh; WTl = WqTl; N = QKV3; n0 = bx * 64; }
    else         { W = Wo; WTh = WoTh; WTl = WoTl; N = HD;   n0 = (bx - 24) * 64; }
    const int K = CIN;
    const int k0 = blockIdx.y * 64;
    const int tid = threadIdx.x;
    #pragma unroll
    for (int i = 0; i < 4; ++i) {
        int c = tid + i * 256;
        int row = c >> 4, c4 = c & 15;
        *(float4*)&T[row][c4*4] = *(const float4*)(W + (size_t)(k0 + row) * N + n0 + c4*4);
    }
    __syncthreads();
    const int n = tid >> 2, kseg = tid & 3;
    short8 hh0, ll0, hh1, ll1;
    #pragma unroll
    for (int e = 0; e < 8; ++e) {
        float x0 = T[kseg*16 + e][n];
        unsigned short h0 = f2bf(x0);
        hh0[e] = (short)h0; ll0[e] = (short)f2bf(x0 - bf2f(h0));
        float x1 = T[kseg*16 + 8 + e][n];
        unsigned short h1 = f2bf(x1);
        hh1[e] = (short)h1; ll1[e] = (short)f2bf(x1 - bf2f(h1));
    }
    size_t o = (size_t)(n0 + n) * K + k0 + kseg * 16;
    *(short8*)(WTh + o)     = hh0;
    *(short8*)(WTh + o + 8) = hh1;
    *(short8*)(WTl + o)     = ll0;
    *(short8*)(WTl + o + 8) = ll1;
}

// ---------- split-bf16 MFMA GEMM: C[M][N] = A[M][K](f32) @ BT[N][K](bf16 h/l) --
// BM=128 BN=64 BK=64; stage-time A conversion  [R7-proven path]
__global__ __launch_bounds__(256, 2) void gemm_split_kernel(
    const float* __restrict__ A, const ushort_t* __restrict__ BTh,
    const ushort_t* __restrict__ BTl, float* __restrict__ C,
    int M, int N, int K)
{
    __shared__ ushort_t Ash[128][72], Asl[128][72];
    __shared__ ushort_t Bsh[64][72],  Bsl[64][72];
    const int bm = blockIdx.y * 128, bn = blockIdx.x * 64;
    const int tid = threadIdx.x;
    const int wave = tid >> 6, lane = tid & 63;
    const int lg = lane >> 4, lm = lane & 15;
    const int wm = wave >> 1, wn = wave & 1;
    const int arow = tid >> 3, aseg = tid & 7;

    f32x4 acc[4][2];
    #pragma unroll
    for (int mf = 0; mf < 4; ++mf)
        #pragma unroll
        for (int nf = 0; nf < 2; ++nf) acc[mf][nf] = (f32x4){0.f,0.f,0.f,0.f};

    float4 ar[8];
    uint4 brh[2], brl[2];
    const int nkt = K >> 6;

    #define G_ISSUE(K0)                                                          \
        { _Pragma("unroll")                                                      \
          for (int i = 0; i < 4; ++i) {                                          \
            const float* ap = A + (size_t)(bm + arow + 32*i) * K + (K0) + aseg*8;\
            ar[2*i]   = *(const float4*)ap;                                      \
            ar[2*i+1] = *(const float4*)(ap + 4);                                \
          }                                                                      \
          _Pragma("unroll")                                                      \
          for (int i = 0; i < 2; ++i) {                                          \
            size_t bo = (size_t)(bn + arow + 32*i) * K + (K0) + aseg*8;          \
            brh[i] = *(const uint4*)(BTh + bo);                                  \
            brl[i] = *(const uint4*)(BTl + bo);                                  \
          } }

    G_ISSUE(0)
    for (int kt = 0; kt < nkt; ++kt) {
        __syncthreads();
        #pragma unroll
        for (int i = 0; i < 4; ++i) {
            float av[8];
            *(float4*)&av[0] = ar[2*i];
            *(float4*)&av[4] = ar[2*i+1];
            short8 hh, ll;
            #pragma unroll
            for (int e = 0; e < 8; ++e) {
                unsigned short hi = f2bf(av[e]);
                hh[e] = (short)hi;
                ll[e] = (short)f2bf(av[e] - bf2f(hi));
            }
            *(short8*)&Ash[arow + 32*i][aseg*8] = hh;
            *(short8*)&Asl[arow + 32*i][aseg*8] = ll;
        }
        #pragma unroll
        for (int i = 0; i < 2; ++i) {
            *(uint4*)&Bsh[arow + 32*i][aseg*8] = brh[i];
            *(uint4*)&Bsl[arow + 32*i][aseg*8] = brl[i];
        }
        if (kt + 1 < nkt) G_ISSUE((kt + 1) * 64)
        __syncthreads();
        #pragma unroll
        for (int ks = 0; ks < 2; ++ks) {
            short8 afh[4], afl[4], bfh[2], bfl[2];
            #pragma unroll
            for (int mf = 0; mf < 4; ++mf) {
                afh[mf] = *(const short8*)&Ash[wm*64 + mf*16 + lm][ks*32 + lg*8];
                afl[mf] = *(const short8*)&Asl[wm*64 + mf*16 + lm][ks*32 + lg*8];
            }
            #pragma unroll
            for (int nf = 0; nf < 2; ++nf) {
                bfh[nf] = *(const short8*)&Bsh[wn*32 + nf*16 + lm][ks*32 + lg*8];
                bfl[nf] = *(const short8*)&Bsl[wn*32 + nf*16 + lm][ks*32 + lg*8];
            }
            #pragma unroll
            for (int mf = 0; mf < 4; ++mf)
                #pragma unroll
                for (int nf = 0; nf < 2; ++nf) {
                    acc[mf][nf] = __builtin_amdgcn_mfma_f32_16x16x32_bf16(afh[mf], bfh[nf], acc[mf][nf], 0, 0, 0);
                    acc[mf][nf] = __builtin_amdgcn_mfma_f32_16x16x32_bf16(afh[mf], bfl[nf], acc[mf][nf], 0, 0, 0);
                    acc[mf][nf] = __builtin_amdgcn_mfma_f32_16x16x32_bf16(afl[mf], bfh[nf], acc[mf][nf], 0, 0, 0);
                }
        }
    }
    #pragma unroll
    for (int mf = 0; mf < 4; ++mf)
        #pragma unroll
        for (int nf = 0; nf < 2; ++nf)
            #pragma unroll
            for (int r = 0; r < 4; ++r)
                C[(size_t)(bm + wm*64 + mf*16 + lg*4 + r) * N + bn + wn*32 + nf*16 + lm]
                    = acc[mf][nf][r];
    #undef G_ISSUE
}

// ---------- out-proj GEMM with FUSED 3-way merge; stage-time conversion ---
// out[M][512] = merge(Opart,Ml) @ WoutT;  BM=64 BN=64 BK=64 (h = kt)
__global__ __launch_bounds__(256, 2) void gemm_merge_kernel(
    const float* __restrict__ Opart, const float* __restrict__ Ml,
    const ushort_t* __restrict__ BTh, const ushort_t* __restrict__ BTl,
    float* __restrict__ C)
{
    __shared__ ushort_t Ash[64][72], Asl[64][72];  // 18,432 B
    __shared__ ushort_t Bsh[64][72], Bsl[64][72];  // 18,432 B
    const int bm = blockIdx.y * 64, bn = blockIdx.x * 64;
    const int tid = threadIdx.x;
    const int wave = tid >> 6, lane = tid & 63;
    const int lg = lane >> 4, lm = lane & 15;
    const int wm = wave >> 1, wn = wave & 1;
    const int srow = tid >> 2, sseg = tid & 3;    // stage: 64 rows x 4 segs of 16

    f32x4 acc[2][2];
    #pragma unroll
    for (int mf = 0; mf < 2; ++mf)
        #pragma unroll
        for (int nf = 0; nf < 2; ++nf) acc[mf][nf] = (f32x4){0.f,0.f,0.f,0.f};

    float4 ar[4];
    uint4 brh[2], brl[2];

    #define GM_ISSUE(KT) {                                                      \
        const int h_ = (KT);                                                    \
        const int mrow = bm + srow;                                             \
        const int b_ = mrow >> 11, n_ = mrow & (NSEQ - 1);                      \
        float mv0, mv1, mv2, lv0, lv1, lv2;                                     \
        { size_t mi = ((size_t)(b_*8 + h_) * NSEQ + n_) * 2;                    \
          mv0 = Ml[mi]; lv0 = Ml[mi+1];                                         \
          mi = ((size_t)(16 + b_*8 + h_) * NSEQ + n_) * 2;                      \
          mv1 = Ml[mi]; lv1 = Ml[mi+1];                                         \
          mi = ((size_t)(32 + b_*8 + h_) * NSEQ + n_) * 2;                      \
          mv2 = Ml[mi]; lv2 = Ml[mi+1]; }                                       \
        float mm = fmaxf(fmaxf(mv0, mv1), mv2);                                 \
        float w0 = __expf(mv0 - mm), w1 = __expf(mv1 - mm), w2 = __expf(mv2 - mm);\
        float inv = 1.f / (lv0*w0 + lv1*w1 + lv2*w2);                           \
        size_t o0 = ((size_t)(b_*8 + h_) * NSEQ + n_) * 64 + sseg*16;           \
        size_t o1 = ((size_t)(16 + b_*8 + h_) * NSEQ + n_) * 64 + sseg*16;      \
        size_t o2 = ((size_t)(32 + b_*8 + h_) * NSEQ + n_) * 64 + sseg*16;      \
        _Pragma("unroll")                                                       \
        for (int c = 0; c < 4; ++c) {                                           \
            float4 v0 = *(const float4*)(Opart + o0 + c*4);                     \
            float4 v1 = *(const float4*)(Opart + o1 + c*4);                     \
            float4 v2 = *(const float4*)(Opart + o2 + c*4);                     \
            ar[c].x = (v0.x*w0 + v1.x*w1 + v2.x*w2) * inv;                      \
            ar[c].y = (v0.y*w0 + v1.y*w1 + v2.y*w2) * inv;                      \
            ar[c].z = (v0.z*w0 + v1.z*w1 + v2.z*w2) * inv;                      \
            ar[c].w = (v0.w*w0 + v1.w*w1 + v2.w*w2) * inv;                      \
        }                                                                       \
        size_t bo = (size_t)(bn + srow) * CIN + (KT)*64 + sseg*16;              \
        brh[0] = *(const uint4*)(BTh + bo);                                     \
        brh[1] = *(const uint4*)(BTh + bo + 8);                                 \
        brl[0] = *(const uint4*)(BTl + bo);                                     \
        brl[1] = *(const uint4*)(BTl + bo + 8); }

    GM_ISSUE(0)
    for (int kt = 0; kt < 8; ++kt) {
        __syncthreads();
        {   // stage-time f32 -> bf16 hi/lo (proven gemm_split pattern)
            short8 hh0, ll0, hh1, ll1;
            float av[16];
            *(float4*)&av[0]  = ar[0];
            *(float4*)&av[4]  = ar[1];
            *(float4*)&av[8]  = ar[2];
            *(float4*)&av[12] = ar[3];
            #pragma unroll
            for (int e = 0; e < 8; ++e) {
                unsigned short h0 = f2bf(av[e]);
                hh0[e] = (short)h0; ll0[e] = (short)f2bf(av[e] - bf2f(h0));
                unsigned short h1 = f2bf(av[e + 8]);
                hh1[e] = (short)h1; ll1[e] = (short)f2bf(av[e + 8] - bf2f(h1));
            }
            *(short8*)&Ash[srow][sseg*16]     = hh0;
            *(short8*)&Ash[srow][sseg*16 + 8] = hh1;
            *(short8*)&Asl[srow][sseg*16]     = ll0;
            *(short8*)&Asl[srow][sseg*16 + 8] = ll1;
        }
        *(uint4*)&Bsh[srow][sseg*16]     = brh[0];
        *(uint4*)&Bsh[srow][sseg*16 + 8] = brh[1];
        *(uint4*)&Bsl[srow][sseg*16]     = brl[0];
        *(uint4*)&Bsl[srow][sseg*16 + 8] = brl[1];
        if (kt + 1 < 8) GM_ISSUE(kt + 1)
        __syncthreads();
        #pragma unroll
        for (int ks = 0; ks < 2; ++ks) {
            short8 afh[2], afl[2], bfh[2], bfl[2];
            #pragma unroll
            for (int mf = 0; mf < 2; ++mf) {
                afh[mf] = *(const short8*)&Ash[wm*32 + mf*16 + lm][ks*32 + lg*8];
                afl[mf] = *(const short8*)&Asl[wm*32 + mf*16 + lm][ks*32 + lg*8];
            }
            #pragma unroll
            for (int nf = 0; nf < 2; ++nf) {
                bfh[nf] = *(const short8*)&Bsh[wn*32 + nf*16 + lm][ks*32 + lg*8];
                bfl[nf] = *(const short8*)&Bsl[wn*32 + nf*16 + lm][ks*32 + lg*8];
            }
            #pragma unroll
            for (int mf = 0; mf < 2; ++mf)
                #pragma unroll
                for (int nf = 0; nf < 2; ++nf) {
                    acc[mf][nf] = __builtin_amdgcn_mfma_f32_16x16x32_bf16(afh[mf], bfh[nf], acc[mf][nf], 0, 0, 0);
                    acc[mf][nf] = __builtin_amdgcn_mfma_f32_16x16x32_bf16(afh[mf], bfl[nf], acc[mf][nf], 0, 0, 0);
                    acc[mf][nf] = __builtin_amdgcn_mfma_f32_16x16x32_bf16(afl[mf], bfh[nf], acc[mf][nf], 0, 0, 0);
                }
        }
    }
    #pragma unroll
    for (int mf = 0; mf < 2; ++mf)
        #pragma unroll
        for (int nf = 0; nf < 2; ++nf)
            #pragma unroll
            for (int r = 0; r < 4; ++r)
                C[(size_t)(bm + wm*32 + mf*16 + lg*4 + r) * CIN + bn + wn*32 + nf*16 + lm]
                    = acc[mf][nf][r];
    #undef GM_ISSUE
}

// ------- fused qkv prep: l2norm+split Q,K  and  transposed/permuted V ----
__global__ __launch_bounds__(256) void qkv_prep_kernel(
    const float* __restrict__ qkv,
    ushort_t* __restrict__ Qh, ushort_t* __restrict__ Ql,
    ushort_t* __restrict__ Kh, ushort_t* __restrict__ Kl,
    ushort_t* __restrict__ Vth, ushort_t* __restrict__ Vtl)
{
    __shared__ float Vf[64][65];
    const int id = blockIdx.x;
    const int bh = id >> 5, nt = id & 31;
    const int b = bh >> 3, h = bh & 7;
    const int n0 = nt * 64;
    const int tid = threadIdx.x;
    {
        const int row = tid >> 2, dseg = tid & 3;
        const float* src = qkv + ((size_t)(b * NSEQ + n0 + row)) * QKV3
                         + h * 192 + dseg * 48;
        float f[48];
        #pragma unroll
        for (int i = 0; i < 12; ++i)
            *(float4*)&f[i*4] = *(const float4*)(src + i*4);
        float nq = 0.f, nk = 0.f;
        #pragma unroll
        for (int e = 0; e < 16; ++e) {
            nq = fmaf(f[3*e], f[3*e], nq);
            nk = fmaf(f[3*e+1], f[3*e+1], nk);
        }
        nq += __shfl_xor(nq, 1); nq += __shfl_xor(nq, 2);
        nk += __shfl_xor(nk, 1); nk += __shfl_xor(nk, 2);
        float rq = 1.f / fmaxf(sqrtf(nq), 1e-12f);
        float rk = 1.f / fmaxf(sqrtf(nk), 1e-12f);
        short8 qh8[2], ql8[2], kh8[2], kl8[2];
        #pragma unroll
        for (int e = 0; e < 16; ++e) {
            float q = f[3*e] * rq, k = f[3*e+1] * rk;
            unsigned short qhi = f2bf(q), khi = f2bf(k);
            qh8[e>>3][e&7] = (short)qhi;
            ql8[e>>3][e&7] = (short)f2bf(q - bf2f(qhi));
            kh8[e>>3][e&7] = (short)khi;
            kl8[e>>3][e&7] = (short)f2bf(k - bf2f(khi));
            Vf[dseg*16 + e][row] = f[3*e+2];
        }
        size_t o = ((size_t)bh * NSEQ + n0 + row) * DIM + dseg * 16;
        *(short8*)(Qh + o) = qh8[0]; *(short8*)(Qh + o + 8) = qh8[1];
        *(short8*)(Ql + o) = ql8[0]; *(short8*)(Ql + o + 8) = ql8[1];
        *(short8*)(Kh + o) = kh8[0]; *(short8*)(Kh + o + 8) = kh8[1];
        *(short8*)(Kl + o) = kl8[0]; *(short8*)(Kl + o + 8) = kl8[1];
    }
    __syncthreads();
    {   // Vt[bh][d][n] with the PV fragment j-permutation (within 32-blocks)
        const int d = tid >> 2, seg = tid & 3;
        ushort_t th[16], tl[16];
        #pragma unroll
        for (int t = 0; t < 16; ++t) {
            int p = seg * 16 + t;
            int s = (p & 35) | ((p & 4) << 2) | ((p >> 1) & 12);
            float v = Vf[d][s];
            unsigned short hi = f2bf(v);
            th[t] = hi;
            tl[t] = f2bf(v - bf2f(hi));
        }
        size_t o = ((size_t)bh * DIM + d) * NSEQ + n0 + seg * 16;
        *(uint4*)(Vth + o)     = *(uint4*)&th[0];
        *(uint4*)(Vth + o + 8) = *(uint4*)&th[8];
        *(uint4*)(Vtl + o)     = *(uint4*)&tl[0];
        *(uint4*)(Vtl + o + 8) = *(uint4*)&tl[8];
    }
}

// ---------------- MFMA flash attention (R7-proven, j-split 3) ------------
__global__ __launch_bounds__(256, 3) void attn_mfma_kernel(
    const ushort_t* __restrict__ Qh, const ushort_t* __restrict__ Ql,
    const ushort_t* __restrict__ Kh, const ushort_t* __restrict__ Kl,
    const ushort_t* __restrict__ Vth, const ushort_t* __restrict__ Vtl,
    const float* __restrict__ bias, const float* __restrict__ temp_p,
    const uint8_t* __restrict__ mask,
    float* __restrict__ Opart, float* __restrict__ Ml,
    int ns, int base, int rem)
{
    __shared__ ushort_t KsH[2][32][72], KsL[2][32][72];   // [buf][j][d]
    __shared__ ushort_t VsH[2][64][36], VsL[2][64][36];   // [buf][d][j-perm]

    const int id = blockIdx.x;
    const int h = id & 7;                  // XCD-grouped
    const int rest = id >> 3;
    const int per_b = 16 * ns;
    const int b = rest / per_b;
    const int r2 = rest - b * per_b;
    const int js = r2 >> 4;
    const int qt = r2 & 15;
    const int bh = b * 8 + h;
    const int i0 = qt * 128;
    const int tid = threadIdx.x;
    const int wave = tid >> 6, lane = tid & 63;
    const int lg = lane >> 4, lm = lane & 15;
    const int qbase = i0 + wave * 32;
    const float temp = *temp_p;
    const int krow = tid >> 3, kseg = tid & 7;
    const int vrow = tid >> 2, vseg = tid & 3;

    short8 qfh[2][2], qfl[2][2];
    #pragma unroll
    for (int m = 0; m < 2; ++m) {
        size_t qo = ((size_t)(bh * NSEQ + qbase + 16*m + lm)) * DIM + lg * 8;
        qfh[m][0] = *(const short8*)(Qh + qo);
        qfh[m][1] = *(const short8*)(Qh + qo + 32);
        qfl[m][0] = *(const short8*)(Ql + qo);
        qfl[m][1] = *(const short8*)(Ql + qo + 32);
    }
    bool rowm[2];
    rowm[0] = mask[(size_t)b * NSEQ + qbase + lm] != 0;
    rowm[1] = mask[(size_t)b * NSEQ + qbase + 16 + lm] != 0;

    float m_r[2] = {-FLT_MAX, -FLT_MAX};
    float l_r[2] = {0.f, 0.f};
    f32x4 oa[2][4];
    #pragma unroll
    for (int m = 0; m < 2; ++m)
        #pragma unroll
        for (int dt = 0; dt < 4; ++dt) oa[m][dt] = (f32x4){0.f,0.f,0.f,0.f};

    const int NT = base + (js < rem ? 1 : 0);
    const int tstart = js * base + (js < rem ? js : rem);
    const int jbase = tstart * 32;
    uint4 skh, skl, svh, svl;

    #define A_ISSUE(J0) {                                                      \
        size_t gk = ((size_t)(bh * NSEQ) + (J0) + krow) * DIM + kseg*8;        \
        size_t gv = ((size_t)(bh * DIM) + vrow) * NSEQ + (J0) + vseg*8;        \
        skh = *(const uint4*)(Kh  + gk);                                       \
        skl = *(const uint4*)(Kl  + gk);                                       \
        svh = *(const uint4*)(Vth + gv);                                       \
        svl = *(const uint4*)(Vtl + gv); }
    #define STAGE(BUF) {                                                       \
        *(uint4*)&KsH[BUF][krow][kseg*8] = skh;                                \
        *(uint4*)&KsL[BUF][krow][kseg*8] = skl;                                \
        *(uint4*)&VsH[BUF][vrow][vseg*8] = svh;                                \
        *(uint4*)&VsL[BUF][vrow][vseg*8] = svl; }

    A_ISSUE(jbase)
    STAGE(0)
    A_ISSUE(jbase + 32)
    float4 bb[2][2];
    #pragma unroll
    for (int m = 0; m < 2; ++m)
        #pragma unroll
        for (int jt = 0; jt < 2; ++jt)
            bb[m][jt] = *(const float4*)(bias
                + ((size_t)h * NSEQ + qbase + 16*m + lm) * NSEQ
                + jbase + jt*16 + lg*4);
    uint8_t mk = mask[(size_t)b * NSEQ + jbase + (lane & 31)];
    __syncthreads();

    #pragma unroll 2
    for (int t = 0; t < NT; ++t) {
        const int cur = t & 1;
        const int j0 = jbase + t * 32;

        float4 bbn[2][2];
        uint8_t mkn = 0;
        if (t + 1 < NT) {
            #pragma unroll
            for (int m = 0; m < 2; ++m)
                #pragma unroll
                for (int jt = 0; jt < 2; ++jt)
                    bbn[m][jt] = *(const float4*)(bias
                        + ((size_t)h * NSEQ + qbase + 16*m + lm) * NSEQ
                        + j0 + 32 + jt*16 + lg*4);
            mkn = mask[(size_t)b * NSEQ + j0 + 32 + (lane & 31)];
            STAGE(cur ^ 1)
            if (t + 2 < NT) A_ISSUE(j0 + 64)
        }
        unsigned long long bal = __ballot(mk != 0);

        f32x4 sac[2][2];
        #pragma unroll
        for (int m = 0; m < 2; ++m)
            #pragma unroll
            for (int jt = 0; jt < 2; ++jt) sac[m][jt] = (f32x4){0.f,0.f,0.f,0.f};
        __builtin_amdgcn_s_setprio(1);
        #pragma unroll
        for (int jt = 0; jt < 2; ++jt)
            #pragma unroll
            for (int ks = 0; ks < 2; ++ks) {
                short8 kbh = *(const short8*)(&KsH[cur][jt*16 + lm][ks*32 + lg*8]);
                short8 kbl = *(const short8*)(&KsL[cur][jt*16 + lm][ks*32 + lg*8]);
                #pragma unroll
                for (int m = 0; m < 2; ++m) {
                    sac[m][jt] = __builtin_amdgcn_mfma_f32_16x16x32_bf16(kbh, qfh[m][ks], sac[m][jt], 0, 0, 0);
                    sac[m][jt] = __builtin_amdgcn_mfma_f32_16x16x32_bf16(kbh, qfl[m][ks], sac[m][jt], 0, 0, 0);
                    sac[m][jt] = __builtin_amdgcn_mfma_f32_16x16x32_bf16(kbl, qfh[m][ks], sac[m][jt], 0, 0, 0);
                }
            }
        __builtin_amdgcn_s_setprio(0);

        short8 pah[2], pal[2];
        #pragma unroll
        for (int m = 0; m < 2; ++m) {
            float sv[2][4];
            #pragma unroll
            for (int jt = 0; jt < 2; ++jt) {
                unsigned int nib = (unsigned int)(bal >> (jt*16 + lg*4)) & 0xFu;
                #pragma unroll
                for (int r = 0; r < 4; ++r) {
                    bool dead = rowm[m] || ((nib >> r) & 1u);
                    float bv = (r == 0) ? bb[m][jt].x : (r == 1) ? bb[m][jt].y
                             : (r == 2) ? bb[m][jt].z : bb[m][jt].w;
                    sv[jt][r] = dead ? -FLT_MAX : fmaf(sac[m][jt][r], temp, bv);
                }
            }
            float pmax = fmaxf(fmaxf(fmaxf(sv[0][0], sv[0][1]), fmaxf(sv[0][2], sv[0][3])),
                               fmaxf(fmaxf(sv[1][0], sv[1][1]), fmaxf(sv[1][2], sv[1][3])));
            pmax = fmaxf(pmax, __shfl_xor(pmax, 16));
            pmax = fmaxf(pmax, __shfl_xor(pmax, 32));
            if (!__all(pmax <= m_r[m] + 8.f)) {
                float mn = fmaxf(m_r[m], pmax);
                float sc = __expf(m_r[m] - mn);
                m_r[m] = mn;
                l_r[m] *= sc;
                #pragma unroll
                for (int r = 0; r < 4; ++r) {
                    float sq = __shfl(sc, lg*4 + r);
                    #pragma unroll
                    for (int dt = 0; dt < 4; ++dt) oa[m][dt][r] *= sq;
                }
            }
            float rs = 0.f;
            #pragma unroll
            for (int jt = 0; jt < 2; ++jt)
                #pragma unroll
                for (int r = 0; r < 4; ++r) {
                    float pf = __expf(sv[jt][r] - m_r[m]);
                    rs += pf;
                    unsigned short hi = f2bf(pf);
                    pah[m][jt*4 + r] = (short)hi;
                    pal[m][jt*4 + r] = (short)f2bf(pf - bf2f(hi));
                }
            rs += __shfl_xor(rs, 16);
            rs += __shfl_xor(rs, 32);
            l_r[m] += rs;
        }

        __builtin_amdgcn_s_setprio(1);
        #pragma unroll
        for (int dt = 0; dt < 4; ++dt) {
            short8 vbh = *(const short8*)(&VsH[cur][dt*16 + lm][lg*8]);
            short8 vbl = *(const short8*)(&VsL[cur][dt*16 + lm][lg*8]);
            #pragma unroll
            for (int m = 0; m < 2; ++m) {
                oa[m][dt] = __builtin_amdgcn_mfma_f32_16x16x32_bf16(pah[m], vbh, oa[m][dt], 0, 0, 0);
                oa[m][dt] = __builtin_amdgcn_mfma_f32_16x16x32_bf16(pah[m], vbl, oa[m][dt], 0, 0, 0);
                oa[m][dt] = __builtin_amdgcn_mfma_f32_16x16x32_bf16(pal[m], vbh, oa[m][dt], 0, 0, 0);
            }
        }
        __builtin_amdgcn_s_setprio(0);
        __syncthreads();
        #pragma unroll
        for (int m = 0; m < 2; ++m)
            #pragma unroll
            for (int jt = 0; jt < 2; ++jt) bb[m][jt] = bbn[m][jt];
        mk = mkn;
    }
    #undef A_ISSUE
    #undef STAGE

    #pragma unroll
    for (int m = 0; m < 2; ++m)
        #pragma unroll
        for (int dt = 0; dt < 4; ++dt)
            #pragma unroll
            for (int r = 0; r < 4; ++r)
                Opart[((size_t)(js*16 + bh) * NSEQ + qbase + 16*m + lg*4 + r) * 64
                      + dt*16 + lm] = oa[m][dt][r];
    if (lane < 16) {
        #pragma unroll
        for (int m = 0; m < 2; ++m) {
            size_t mi = ((size_t)(js*16 + bh) * NSEQ + qbase + 16*m + lm) * 2;
            Ml[mi]     = m_r[m];
            Ml[mi + 1] = l_r[m];
        }
    }
}

extern "C" void kernel_launch(void* const* d_in, const int* in_sizes, int n_in,
                              void* d_out, int out_size, void* d_ws, size_t ws_size,
                              hipStream_t stream)
{
    const float*   x        = (const float*)d_in[0];
    const float*   w_qkv    = (const float*)d_in[1];
    const float*   w_out    = (const float*)d_in[2];
    const float*   pos_bias = (const float*)d_in[3];
    const float*   temp     = (const float*)d_in[4];
    const uint8_t* mask     = (const uint8_t*)d_in[5];
    float* out = (float*)d_out;

    const int M = BATCH * NSEQ;                        // 4096
    const size_t NE = (size_t)BATCH * HEADS * NSEQ * DIM;
    const int ns = 3;                                  // grid 768 = 3 blocks/CU exactly
    const int base = 64 / ns, rem = 64 % ns;

    char* ws = (char*)d_ws;
    // region 0 (25.2 MB): qkv_lin f32; exactly reused by the 3-split f32 Opart
    float* qkv_lin = (float*)ws;
    float* OpartP  = (float*)ws;    // 3*16*2048*64*4 B == M*QKV3*4 B exactly
    size_t off = (size_t)M * QKV3 * 4;
    // region 1: transposed/split weights + Ml
    ushort_t* WqkvTh = (ushort_t*)(ws + off); off += (size_t)QKV3 * CIN * 2;
    ushort_t* WqkvTl = (ushort_t*)(ws + off); off += (size_t)QKV3 * CIN * 2;
    ushort_t* WoutTh = (ushort_t*)(ws + off); off += (size_t)HD * CIN * 2;
    ushort_t* WoutTl = (ushort_t*)(ws + off); off += (size_t)HD * CIN * 2;
    float*    MlP    = (float*)(ws + off);    off += (size_t)ns * 16 * NSEQ * 2 * 4;
    // region 2 (25.2 MB): Q/K/Vt bf16 hi/lo
    char* reg2 = ws + off;
    ushort_t* Qh  = (ushort_t*)reg2;
    ushort_t* Ql  = Qh + NE;
    ushort_t* Kh  = Ql + NE;
    ushort_t* Kl  = Kh + NE;
    ushort_t* Vth = Kl + NE;
    ushort_t* Vtl = Vth + NE;

    // 1. both weight splits in one launch
    split_wT_kernel<<<dim3(32, CIN/64), 256, 0, stream>>>(
        w_qkv, w_out, WqkvTh, WqkvTl, WoutTh, WoutTl);
    // 2. qkv projection (R7-proven stage-time-convert GEMM)
    gemm_split_kernel<<<dim3(QKV3/64, M/128), 256, 0, stream>>>(
        x, WqkvTh, WqkvTl, qkv_lin, M, QKV3, CIN);
    // 3. fused l2norm/split + V transpose
    qkv_prep_kernel<<<dim3(BATCH * HEADS * (NSEQ/64)), 256, 0, stream>>>(
        qkv_lin, Qh, Ql, Kh, Kl, Vth, Vtl);
    // 4. attention (j-split 3; Opart overwrites qkv_lin)
    attn_mfma_kernel<<<dim3(256 * ns), 256, 0, stream>>>(
        Qh, Ql, Kh, Kl, Vth, Vtl, pos_bias, temp, mask, OpartP, MlP,
        ns, base, rem);
    // 5. out projection with fused 3-way merge (reads Opart+Ml directly)
    gemm_merge_kernel<<<dim3(CIN/64, M/64), 256, 0, stream>>>(
        OpartP, MlP, WoutTh, WoutTl, out);
}

// Round 12
// 176.708 us; speedup vs baseline: 1.3305x; 1.1416x over previous
//
#include <hip/hip_runtime.h>
#include <cfloat>
#include <cstdint>

#define BATCH 2
#define NSEQ 2048
#define CIN 512
#define HEADS 8
#define DIM 64
#define HD 512
#define QKV3 1536

typedef short short8 __attribute__((ext_vector_type(8)));
typedef float f32x4 __attribute__((ext_vector_type(4)));
typedef unsigned short ushort_t;

__device__ __forceinline__ unsigned short f2bf(float f) {
    return (unsigned short)(__float_as_uint(f) >> 16);
}
__device__ __forceinline__ float bf2f(unsigned short h) {
    return __uint_as_float(((unsigned int)h) << 16);
}
// T2 XOR swizzle (ushort-index units): toggles the 8-ushort (16B) slot
// within a 64-ushort (128B) row; bank set then depends only on slot.
#define SWZ(row, col) ((col) ^ (((row) & 7) << 3))

// ---------- split + transpose BOTH weights in one launch ------------------
__global__ __launch_bounds__(256) void split_wT_kernel(
    const float* __restrict__ Wq, const float* __restrict__ Wo,
    ushort_t* __restrict__ WqTh, ushort_t* __restrict__ WqTl,
    ushort_t* __restrict__ WoTh, ushort_t* __restrict__ WoTl)
{
    __shared__ float T[64][65];
    const int bx = blockIdx.x;
    const float* W; ushort_t *WTh, *WTl; int N, n0;
    if (bx < 24) { W = Wq; WTh = WqTh; WTl = WqTl; N = QKV3; n0 = bx * 64; }
    else         { W = Wo; WTh = WoTh; WTl = WoTl; N = HD;   n0 = (bx - 24) * 64; }
    const int K = CIN;
    const int k0 = blockIdx.y * 64;
    const int tid = threadIdx.x;
    #pragma unroll
    for (int i = 0; i < 4; ++i) {
        int c = tid + i * 256;
        int row = c >> 4, c4 = c & 15;
        *(float4*)&T[row][c4*4] = *(const float4*)(W + (size_t)(k0 + row) * N + n0 + c4*4);
    }
    __syncthreads();
    const int n = tid >> 2, kseg = tid & 3;
    short8 hh0, ll0, hh1, ll1;
    #pragma unroll
    for (int e = 0; e < 8; ++e) {
        float x0 = T[kseg*16 + e][n];
        unsigned short h0 = f2bf(x0);
        hh0[e] = (short)h0; ll0[e] = (short)f2bf(x0 - bf2f(h0));
        float x1 = T[kseg*16 + 8 + e][n];
        unsigned short h1 = f2bf(x1);
        hh1[e] = (short)h1; ll1[e] = (short)f2bf(x1 - bf2f(h1));
    }
    size_t o = (size_t)(n0 + n) * K + k0 + kseg * 16;
    *(short8*)(WTh + o)     = hh0;
    *(short8*)(WTh + o + 8) = hh1;
    *(short8*)(WTl + o)     = ll0;
    *(short8*)(WTl + o + 8) = ll1;
}

// ---------- split-bf16 MFMA GEMM: C[M][N] = A[M][K](f32) @ BT[N][K](bf16 h/l) --
// BM=128 BN=64 BK=64; stage-time A conversion; XOR-swizzled LDS (48KB -> 3 blk/CU)
__global__ __launch_bounds__(256, 2) void gemm_split_kernel(
    const float* __restrict__ A, const ushort_t* __restrict__ BTh,
    const ushort_t* __restrict__ BTl, float* __restrict__ C,
    int M, int N, int K)
{
    __shared__ ushort_t Ash[128][64], Asl[128][64];   // 32,768 B
    __shared__ ushort_t Bsh[64][64],  Bsl[64][64];    // 16,384 B
    const int bm = blockIdx.y * 128, bn = blockIdx.x * 64;
    const int tid = threadIdx.x;
    const int wave = tid >> 6, lane = tid & 63;
    const int lg = lane >> 4, lm = lane & 15;
    const int wm = wave >> 1, wn = wave & 1;
    const int arow = tid >> 3, aseg = tid & 7;
    const int scol = SWZ(arow, aseg * 8);   // stage col (row&7 invariant over +32i)

    f32x4 acc[4][2];
    #pragma unroll
    for (int mf = 0; mf < 4; ++mf)
        #pragma unroll
        for (int nf = 0; nf < 2; ++nf) acc[mf][nf] = (f32x4){0.f,0.f,0.f,0.f};

    float4 ar[8];
    uint4 brh[2], brl[2];
    const int nkt = K >> 6;

    #define G_ISSUE(K0)                                                          \
        { _Pragma("unroll")                                                      \
          for (int i = 0; i < 4; ++i) {                                          \
            const float* ap = A + (size_t)(bm + arow + 32*i) * K + (K0) + aseg*8;\
            ar[2*i]   = *(const float4*)ap;                                      \
            ar[2*i+1] = *(const float4*)(ap + 4);                                \
          }                                                                      \
          _Pragma("unroll")                                                      \
          for (int i = 0; i < 2; ++i) {                                          \
            size_t bo = (size_t)(bn + arow + 32*i) * K + (K0) + aseg*8;          \
            brh[i] = *(const uint4*)(BTh + bo);                                  \
            brl[i] = *(const uint4*)(BTl + bo);                                  \
          } }

    G_ISSUE(0)
    for (int kt = 0; kt < nkt; ++kt) {
        __syncthreads();
        #pragma unroll
        for (int i = 0; i < 4; ++i) {
            float av[8];
            *(float4*)&av[0] = ar[2*i];
            *(float4*)&av[4] = ar[2*i+1];
            short8 hh, ll;
            #pragma unroll
            for (int e = 0; e < 8; ++e) {
                unsigned short hi = f2bf(av[e]);
                hh[e] = (short)hi;
                ll[e] = (short)f2bf(av[e] - bf2f(hi));
            }
            *(short8*)&Ash[arow + 32*i][scol] = hh;
            *(short8*)&Asl[arow + 32*i][scol] = ll;
        }
        #pragma unroll
        for (int i = 0; i < 2; ++i) {
            *(uint4*)&Bsh[arow + 32*i][scol] = brh[i];
            *(uint4*)&Bsl[arow + 32*i][scol] = brl[i];
        }
        if (kt + 1 < nkt) G_ISSUE((kt + 1) * 64)
        __syncthreads();
        #pragma unroll
        for (int ks = 0; ks < 2; ++ks) {
            const int rcol = SWZ(lm, ks*32 + lg*8);   // read col (row&7 == lm&7)
            short8 afh[4], afl[4], bfh[2], bfl[2];
            #pragma unroll
            for (int mf = 0; mf < 4; ++mf) {
                afh[mf] = *(const short8*)&Ash[wm*64 + mf*16 + lm][rcol];
                afl[mf] = *(const short8*)&Asl[wm*64 + mf*16 + lm][rcol];
            }
            #pragma unroll
            for (int nf = 0; nf < 2; ++nf) {
                bfh[nf] = *(const short8*)&Bsh[wn*32 + nf*16 + lm][rcol];
                bfl[nf] = *(const short8*)&Bsl[wn*32 + nf*16 + lm][rcol];
            }
            #pragma unroll
            for (int mf = 0; mf < 4; ++mf)
                #pragma unroll
                for (int nf = 0; nf < 2; ++nf) {
                    acc[mf][nf] = __builtin_amdgcn_mfma_f32_16x16x32_bf16(afh[mf], bfh[nf], acc[mf][nf], 0, 0, 0);
                    acc[mf][nf] = __builtin_amdgcn_mfma_f32_16x16x32_bf16(afh[mf], bfl[nf], acc[mf][nf], 0, 0, 0);
                    acc[mf][nf] = __builtin_amdgcn_mfma_f32_16x16x32_bf16(afl[mf], bfh[nf], acc[mf][nf], 0, 0, 0);
                }
        }
    }
    #pragma unroll
    for (int mf = 0; mf < 4; ++mf)
        #pragma unroll
        for (int nf = 0; nf < 2; ++nf)
            #pragma unroll
            for (int r = 0; r < 4; ++r)
                C[(size_t)(bm + wm*64 + mf*16 + lg*4 + r) * N + bn + wn*32 + nf*16 + lm]
                    = acc[mf][nf][r];
    #undef G_ISSUE
}

// ---------- out-proj GEMM with FUSED 3-way merge; swizzled LDS (32KB) -----
// out[M][512] = merge(Opart,Ml) @ WoutT;  BM=64 BN=64 BK=64 (h = kt)
__global__ __launch_bounds__(256, 2) void gemm_merge_kernel(
    const float* __restrict__ Opart, const float* __restrict__ Ml,
    const ushort_t* __restrict__ BTh, const ushort_t* __restrict__ BTl,
    float* __restrict__ C)
{
    __shared__ ushort_t Ash[64][64], Asl[64][64];  // 16,384 B
    __shared__ ushort_t Bsh[64][64], Bsl[64][64];  // 16,384 B
    const int bm = blockIdx.y * 64, bn = blockIdx.x * 64;
    const int tid = threadIdx.x;
    const int wave = tid >> 6, lane = tid & 63;
    const int lg = lane >> 4, lm = lane & 15;
    const int wm = wave >> 1, wn = wave & 1;
    const int srow = tid >> 2, sseg = tid & 3;    // stage: 64 rows x 4 segs of 16
    const int sc0 = SWZ(srow, sseg * 16);
    const int sc1 = SWZ(srow, sseg * 16 + 8);

    f32x4 acc[2][2];
    #pragma unroll
    for (int mf = 0; mf < 2; ++mf)
        #pragma unroll
        for (int nf = 0; nf < 2; ++nf) acc[mf][nf] = (f32x4){0.f,0.f,0.f,0.f};

    float4 ar[4];
    uint4 brh[2], brl[2];

    #define GM_ISSUE(KT) {                                                      \
        const int h_ = (KT);                                                    \
        const int mrow = bm + srow;                                             \
        const int b_ = mrow >> 11, n_ = mrow & (NSEQ - 1);                      \
        float mv0, mv1, mv2, lv0, lv1, lv2;                                     \
        { size_t mi = ((size_t)(b_*8 + h_) * NSEQ + n_) * 2;                    \
          mv0 = Ml[mi]; lv0 = Ml[mi+1];                                         \
          mi = ((size_t)(16 + b_*8 + h_) * NSEQ + n_) * 2;                      \
          mv1 = Ml[mi]; lv1 = Ml[mi+1];                                         \
          mi = ((size_t)(32 + b_*8 + h_) * NSEQ + n_) * 2;                      \
          mv2 = Ml[mi]; lv2 = Ml[mi+1]; }                                       \
        float mm = fmaxf(fmaxf(mv0, mv1), mv2);                                 \
        float w0 = __expf(mv0 - mm), w1 = __expf(mv1 - mm), w2 = __expf(mv2 - mm);\
        float inv = 1.f / (lv0*w0 + lv1*w1 + lv2*w2);                           \
        size_t o0 = ((size_t)(b_*8 + h_) * NSEQ + n_) * 64 + sseg*16;           \
        size_t o1 = ((size_t)(16 + b_*8 + h_) * NSEQ + n_) * 64 + sseg*16;      \
        size_t o2 = ((size_t)(32 + b_*8 + h_) * NSEQ + n_) * 64 + sseg*16;      \
        _Pragma("unroll")                                                       \
        for (int c = 0; c < 4; ++c) {                                           \
            float4 v0 = *(const float4*)(Opart + o0 + c*4);                     \
            float4 v1 = *(const float4*)(Opart + o1 + c*4);                     \
            float4 v2 = *(const float4*)(Opart + o2 + c*4);                     \
            ar[c].x = (v0.x*w0 + v1.x*w1 + v2.x*w2) * inv;                      \
            ar[c].y = (v0.y*w0 + v1.y*w1 + v2.y*w2) * inv;                      \
            ar[c].z = (v0.z*w0 + v1.z*w1 + v2.z*w2) * inv;                      \
            ar[c].w = (v0.w*w0 + v1.w*w1 + v2.w*w2) * inv;                      \
        }                                                                       \
        size_t bo = (size_t)(bn + srow) * CIN + (KT)*64 + sseg*16;              \
        brh[0] = *(const uint4*)(BTh + bo);                                     \
        brh[1] = *(const uint4*)(BTh + bo + 8);                                 \
        brl[0] = *(const uint4*)(BTl + bo);                                     \
        brl[1] = *(const uint4*)(BTl + bo + 8); }

    GM_ISSUE(0)
    for (int kt = 0; kt < 8; ++kt) {
        __syncthreads();
        {   // stage-time f32 -> bf16 hi/lo (proven gemm_split pattern)
            short8 hh0, ll0, hh1, ll1;
            float av[16];
            *(float4*)&av[0]  = ar[0];
            *(float4*)&av[4]  = ar[1];
            *(float4*)&av[8]  = ar[2];
            *(float4*)&av[12] = ar[3];
            #pragma unroll
            for (int e = 0; e < 8; ++e) {
                unsigned short h0 = f2bf(av[e]);
                hh0[e] = (short)h0; ll0[e] = (short)f2bf(av[e] - bf2f(h0));
                unsigned short h1 = f2bf(av[e + 8]);
                hh1[e] = (short)h1; ll1[e] = (short)f2bf(av[e + 8] - bf2f(h1));
            }
            *(short8*)&Ash[srow][sc0] = hh0;
            *(short8*)&Ash[srow][sc1] = hh1;
            *(short8*)&Asl[srow][sc0] = ll0;
            *(short8*)&Asl[srow][sc1] = ll1;
        }
        *(uint4*)&Bsh[srow][sc0] = brh[0];
        *(uint4*)&Bsh[srow][sc1] = brh[1];
        *(uint4*)&Bsl[srow][sc0] = brl[0];
        *(uint4*)&Bsl[srow][sc1] = brl[1];
        if (kt + 1 < 8) GM_ISSUE(kt + 1)
        __syncthreads();
        #pragma unroll
        for (int ks = 0; ks < 2; ++ks) {
            const int rcol = SWZ(lm, ks*32 + lg*8);
            short8 afh[2], afl[2], bfh[2], bfl[2];
            #pragma unroll
            for (int mf = 0; mf < 2; ++mf) {
                afh[mf] = *(const short8*)&Ash[wm*32 + mf*16 + lm][rcol];
                afl[mf] = *(const short8*)&Asl[wm*32 + mf*16 + lm][rcol];
            }
            #pragma unroll
            for (int nf = 0; nf < 2; ++nf) {
                bfh[nf] = *(const short8*)&Bsh[wn*32 + nf*16 + lm][rcol];
                bfl[nf] = *(const short8*)&Bsl[wn*32 + nf*16 + lm][rcol];
            }
            #pragma unroll
            for (int mf = 0; mf < 2; ++mf)
                #pragma unroll
                for (int nf = 0; nf < 2; ++nf) {
                    acc[mf][nf] = __builtin_amdgcn_mfma_f32_16x16x32_bf16(afh[mf], bfh[nf], acc[mf][nf], 0, 0, 0);
                    acc[mf][nf] = __builtin_amdgcn_mfma_f32_16x16x32_bf16(afh[mf], bfl[nf], acc[mf][nf], 0, 0, 0);
                    acc[mf][nf] = __builtin_amdgcn_mfma_f32_16x16x32_bf16(afl[mf], bfh[nf], acc[mf][nf], 0, 0, 0);
                }
        }
    }
    #pragma unroll
    for (int mf = 0; mf < 2; ++mf)
        #pragma unroll
        for (int nf = 0; nf < 2; ++nf)
            #pragma unroll
            for (int r = 0; r < 4; ++r)
                C[(size_t)(bm + wm*32 + mf*16 + lg*4 + r) * CIN + bn + wn*32 + nf*16 + lm]
                    = acc[mf][nf][r];
    #undef GM_ISSUE
}

// ------- fused qkv prep: l2norm+split Q,K  and  transposed/permuted V ----
__global__ __launch_bounds__(256) void qkv_prep_kernel(
    const float* __restrict__ qkv,
    ushort_t* __restrict__ Qh, ushort_t* __restrict__ Ql,
    ushort_t* __restrict__ Kh, ushort_t* __restrict__ Kl,
    ushort_t* __restrict__ Vth, ushort_t* __restrict__ Vtl)
{
    __shared__ float Vf[64][65];
    const int id = blockIdx.x;
    const int bh = id >> 5, nt = id & 31;
    const int b = bh >> 3, h = bh & 7;
    const int n0 = nt * 64;
    const int tid = threadIdx.x;
    {
        const int row = tid >> 2, dseg = tid & 3;
        const float* src = qkv + ((size_t)(b * NSEQ + n0 + row)) * QKV3
                         + h * 192 + dseg * 48;
        float f[48];
        #pragma unroll
        for (int i = 0; i < 12; ++i)
            *(float4*)&f[i*4] = *(const float4*)(src + i*4);
        float nq = 0.f, nk = 0.f;
        #pragma unroll
        for (int e = 0; e < 16; ++e) {
            nq = fmaf(f[3*e], f[3*e], nq);
            nk = fmaf(f[3*e+1], f[3*e+1], nk);
        }
        nq += __shfl_xor(nq, 1); nq += __shfl_xor(nq, 2);
        nk += __shfl_xor(nk, 1); nk += __shfl_xor(nk, 2);
        float rq = 1.f / fmaxf(sqrtf(nq), 1e-12f);
        float rk = 1.f / fmaxf(sqrtf(nk), 1e-12f);
        short8 qh8[2], ql8[2], kh8[2], kl8[2];
        #pragma unroll
        for (int e = 0; e < 16; ++e) {
            float q = f[3*e] * rq, k = f[3*e+1] * rk;
            unsigned short qhi = f2bf(q), khi = f2bf(k);
            qh8[e>>3][e&7] = (short)qhi;
            ql8[e>>3][e&7] = (short)f2bf(q - bf2f(qhi));
            kh8[e>>3][e&7] = (short)khi;
            kl8[e>>3][e&7] = (short)f2bf(k - bf2f(khi));
            Vf[dseg*16 + e][row] = f[3*e+2];
        }
        size_t o = ((size_t)bh * NSEQ + n0 + row) * DIM + dseg * 16;
        *(short8*)(Qh + o) = qh8[0]; *(short8*)(Qh + o + 8) = qh8[1];
        *(short8*)(Ql + o) = ql8[0]; *(short8*)(Ql + o + 8) = ql8[1];
        *(short8*)(Kh + o) = kh8[0]; *(short8*)(Kh + o + 8) = kh8[1];
        *(short8*)(Kl + o) = kl8[0]; *(short8*)(Kl + o + 8) = kl8[1];
    }
    __syncthreads();
    {   // Vt[bh][d][n] with the PV fragment j-permutation (within 32-blocks)
        const int d = tid >> 2, seg = tid & 3;
        ushort_t th[16], tl[16];
        #pragma unroll
        for (int t = 0; t < 16; ++t) {
            int p = seg * 16 + t;
            int s = (p & 35) | ((p & 4) << 2) | ((p >> 1) & 12);
            float v = Vf[d][s];
            unsigned short hi = f2bf(v);
            th[t] = hi;
            tl[t] = f2bf(v - bf2f(hi));
        }
        size_t o = ((size_t)bh * DIM + d) * NSEQ + n0 + seg * 16;
        *(uint4*)(Vth + o)     = *(uint4*)&th[0];
        *(uint4*)(Vth + o + 8) = *(uint4*)&th[8];
        *(uint4*)(Vtl + o)     = *(uint4*)&tl[0];
        *(uint4*)(Vtl + o + 8) = *(uint4*)&tl[8];
    }
}

// ---------------- MFMA flash attention (R7-proven, j-split 3) ------------
__global__ __launch_bounds__(256, 3) void attn_mfma_kernel(
    const ushort_t* __restrict__ Qh, const ushort_t* __restrict__ Ql,
    const ushort_t* __restrict__ Kh, const ushort_t* __restrict__ Kl,
    const ushort_t* __restrict__ Vth, const ushort_t* __restrict__ Vtl,
    const float* __restrict__ bias, const float* __restrict__ temp_p,
    const uint8_t* __restrict__ mask,
    float* __restrict__ Opart, float* __restrict__ Ml,
    int ns, int base, int rem)
{
    __shared__ ushort_t KsH[2][32][72], KsL[2][32][72];   // [buf][j][d]
    __shared__ ushort_t VsH[2][64][36], VsL[2][64][36];   // [buf][d][j-perm]

    const int id = blockIdx.x;
    const int h = id & 7;                  // XCD-grouped
    const int rest = id >> 3;
    const int per_b = 16 * ns;
    const int b = rest / per_b;
    const int r2 = rest - b * per_b;
    const int js = r2 >> 4;
    const int qt = r2 & 15;
    const int bh = b * 8 + h;
    const int i0 = qt * 128;
    const int tid = threadIdx.x;
    const int wave = tid >> 6, lane = tid & 63;
    const int lg = lane >> 4, lm = lane & 15;
    const int qbase = i0 + wave * 32;
    const float temp = *temp_p;
    const int krow = tid >> 3, kseg = tid & 7;
    const int vrow = tid >> 2, vseg = tid & 3;

    short8 qfh[2][2], qfl[2][2];
    #pragma unroll
    for (int m = 0; m < 2; ++m) {
        size_t qo = ((size_t)(bh * NSEQ + qbase + 16*m + lm)) * DIM + lg * 8;
        qfh[m][0] = *(const short8*)(Qh + qo);
        qfh[m][1] = *(const short8*)(Qh + qo + 32);
        qfl[m][0] = *(const short8*)(Ql + qo);
        qfl[m][1] = *(const short8*)(Ql + qo + 32);
    }
    bool rowm[2];
    rowm[0] = mask[(size_t)b * NSEQ + qbase + lm] != 0;
    rowm[1] = mask[(size_t)b * NSEQ + qbase + 16 + lm] != 0;

    float m_r[2] = {-FLT_MAX, -FLT_MAX};
    float l_r[2] = {0.f, 0.f};
    f32x4 oa[2][4];
    #pragma unroll
    for (int m = 0; m < 2; ++m)
        #pragma unroll
        for (int dt = 0; dt < 4; ++dt) oa[m][dt] = (f32x4){0.f,0.f,0.f,0.f};

    const int NT = base + (js < rem ? 1 : 0);
    const int tstart = js * base + (js < rem ? js : rem);
    const int jbase = tstart * 32;
    uint4 skh, skl, svh, svl;

    #define A_ISSUE(J0) {                                                      \
        size_t gk = ((size_t)(bh * NSEQ) + (J0) + krow) * DIM + kseg*8;        \
        size_t gv = ((size_t)(bh * DIM) + vrow) * NSEQ + (J0) + vseg*8;        \
        skh = *(const uint4*)(Kh  + gk);                                       \
        skl = *(const uint4*)(Kl  + gk);                                       \
        svh = *(const uint4*)(Vth + gv);                                       \
        svl = *(const uint4*)(Vtl + gv); }
    #define STAGE(BUF) {                                                       \
        *(uint4*)&KsH[BUF][krow][kseg*8] = skh;                                \
        *(uint4*)&KsL[BUF][krow][kseg*8] = skl;                                \
        *(uint4*)&VsH[BUF][vrow][vseg*8] = svh;                                \
        *(uint4*)&VsL[BUF][vrow][vseg*8] = svl; }

    A_ISSUE(jbase)
    STAGE(0)
    A_ISSUE(jbase + 32)
    float4 bb[2][2];
    #pragma unroll
    for (int m = 0; m < 2; ++m)
        #pragma unroll
        for (int jt = 0; jt < 2; ++jt)
            bb[m][jt] = *(const float4*)(bias
                + ((size_t)h * NSEQ + qbase + 16*m + lm) * NSEQ
                + jbase + jt*16 + lg*4);
    uint8_t mk = mask[(size_t)b * NSEQ + jbase + (lane & 31)];
    __syncthreads();

    #pragma unroll 2
    for (int t = 0; t < NT; ++t) {
        const int cur = t & 1;
        const int j0 = jbase + t * 32;

        float4 bbn[2][2];
        uint8_t mkn = 0;
        if (t + 1 < NT) {
            #pragma unroll
            for (int m = 0; m < 2; ++m)
                #pragma unroll
                for (int jt = 0; jt < 2; ++jt)
                    bbn[m][jt] = *(const float4*)(bias
                        + ((size_t)h * NSEQ + qbase + 16*m + lm) * NSEQ
                        + j0 + 32 + jt*16 + lg*4);
            mkn = mask[(size_t)b * NSEQ + j0 + 32 + (lane & 31)];
            STAGE(cur ^ 1)
            if (t + 2 < NT) A_ISSUE(j0 + 64)
        }
        unsigned long long bal = __ballot(mk != 0);

        f32x4 sac[2][2];
        #pragma unroll
        for (int m = 0; m < 2; ++m)
            #pragma unroll
            for (int jt = 0; jt < 2; ++jt) sac[m][jt] = (f32x4){0.f,0.f,0.f,0.f};
        __builtin_amdgcn_s_setprio(1);
        #pragma unroll
        for (int jt = 0; jt < 2; ++jt)
            #pragma unroll
            for (int ks = 0; ks < 2; ++ks) {
                short8 kbh = *(const short8*)(&KsH[cur][jt*16 + lm][ks*32 + lg*8]);
                short8 kbl = *(const short8*)(&KsL[cur][jt*16 + lm][ks*32 + lg*8]);
                #pragma unroll
                for (int m = 0; m < 2; ++m) {
                    sac[m][jt] = __builtin_amdgcn_mfma_f32_16x16x32_bf16(kbh, qfh[m][ks], sac[m][jt], 0, 0, 0);
                    sac[m][jt] = __builtin_amdgcn_mfma_f32_16x16x32_bf16(kbh, qfl[m][ks], sac[m][jt], 0, 0, 0);
                    sac[m][jt] = __builtin_amdgcn_mfma_f32_16x16x32_bf16(kbl, qfh[m][ks], sac[m][jt], 0, 0, 0);
                }
            }
        __builtin_amdgcn_s_setprio(0);

        short8 pah[2], pal[2];
        #pragma unroll
        for (int m = 0; m < 2; ++m) {
            float sv[2][4];
            #pragma unroll
            for (int jt = 0; jt < 2; ++jt) {
                unsigned int nib = (unsigned int)(bal >> (jt*16 + lg*4)) & 0xFu;
                #pragma unroll
                for (int r = 0; r < 4; ++r) {
                    bool dead = rowm[m] || ((nib >> r) & 1u);
                    float bv = (r == 0) ? bb[m][jt].x : (r == 1) ? bb[m][jt].y
                             : (r == 2) ? bb[m][jt].z : bb[m][jt].w;
                    sv[jt][r] = dead ? -FLT_MAX : fmaf(sac[m][jt][r], temp, bv);
                }
            }
            float pmax = fmaxf(fmaxf(fmaxf(sv[0][0], sv[0][1]), fmaxf(sv[0][2], sv[0][3])),
                               fmaxf(fmaxf(sv[1][0], sv[1][1]), fmaxf(sv[1][2], sv[1][3])));
            pmax = fmaxf(pmax, __shfl_xor(pmax, 16));
            pmax = fmaxf(pmax, __shfl_xor(pmax, 32));
            if (!__all(pmax <= m_r[m] + 8.f)) {
                float mn = fmaxf(m_r[m], pmax);
                float sc = __expf(m_r[m] - mn);
                m_r[m] = mn;
                l_r[m] *= sc;
                #pragma unroll
                for (int r = 0; r < 4; ++r) {
                    float sq = __shfl(sc, lg*4 + r);
                    #pragma unroll
                    for (int dt = 0; dt < 4; ++dt) oa[m][dt][r] *= sq;
                }
            }
            float rs = 0.f;
            #pragma unroll
            for (int jt = 0; jt < 2; ++jt)
                #pragma unroll
                for (int r = 0; r < 4; ++r) {
                    float pf = __expf(sv[jt][r] - m_r[m]);
                    rs += pf;
                    unsigned short hi = f2bf(pf);
                    pah[m][jt*4 + r] = (short)hi;
                    pal[m][jt*4 + r] = (short)f2bf(pf - bf2f(hi));
                }
            rs += __shfl_xor(rs, 16);
            rs += __shfl_xor(rs, 32);
            l_r[m] += rs;
        }

        __builtin_amdgcn_s_setprio(1);
        #pragma unroll
        for (int dt = 0; dt < 4; ++dt) {
            short8 vbh = *(const short8*)(&VsH[cur][dt*16 + lm][lg*8]);
            short8 vbl = *(const short8*)(&VsL[cur][dt*16 + lm][lg*8]);
            #pragma unroll
            for (int m = 0; m < 2; ++m) {
                oa[m][dt] = __builtin_amdgcn_mfma_f32_16x16x32_bf16(pah[m], vbh, oa[m][dt], 0, 0, 0);
                oa[m][dt] = __builtin_amdgcn_mfma_f32_16x16x32_bf16(pah[m], vbl, oa[m][dt], 0, 0, 0);
                oa[m][dt] = __builtin_amdgcn_mfma_f32_16x16x32_bf16(pal[m], vbh, oa[m][dt], 0, 0, 0);
            }
        }
        __builtin_amdgcn_s_setprio(0);
        __syncthreads();
        #pragma unroll
        for (int m = 0; m < 2; ++m)
            #pragma unroll
            for (int jt = 0; jt < 2; ++jt) bb[m][jt] = bbn[m][jt];
        mk = mkn;
    }
    #undef A_ISSUE
    #undef STAGE

    #pragma unroll
    for (int m = 0; m < 2; ++m)
        #pragma unroll
        for (int dt = 0; dt < 4; ++dt)
            #pragma unroll
            for (int r = 0; r < 4; ++r)
                Opart[((size_t)(js*16 + bh) * NSEQ + qbase + 16*m + lg*4 + r) * 64
                      + dt*16 + lm] = oa[m][dt][r];
    if (lane < 16) {
        #pragma unroll
        for (int m = 0; m < 2; ++m) {
            size_t mi = ((size_t)(js*16 + bh) * NSEQ + qbase + 16*m + lm) * 2;
            Ml[mi]     = m_r[m];
            Ml[mi + 1] = l_r[m];
        }
    }
}

extern "C" void kernel_launch(void* const* d_in, const int* in_sizes, int n_in,
                              void* d_out, int out_size, void* d_ws, size_t ws_size,
                              hipStream_t stream)
{
    const float*   x        = (const float*)d_in[0];
    const float*   w_qkv    = (const float*)d_in[1];
    const float*   w_out    = (const float*)d_in[2];
    const float*   pos_bias = (const float*)d_in[3];
    const float*   temp     = (const float*)d_in[4];
    const uint8_t* mask     = (const uint8_t*)d_in[5];
    float* out = (float*)d_out;

    const int M = BATCH * NSEQ;                        // 4096
    const size_t NE = (size_t)BATCH * HEADS * NSEQ * DIM;
    const int ns = 3;                                  // grid 768 = 3 blocks/CU exactly
    const int base = 64 / ns, rem = 64 % ns;

    char* ws = (char*)d_ws;
    // region 0 (25.2 MB): qkv_lin f32; exactly reused by the 3-split f32 Opart
    float* qkv_lin = (float*)ws;
    float* OpartP  = (float*)ws;    // 3*16*2048*64*4 B == M*QKV3*4 B exactly
    size_t off = (size_t)M * QKV3 * 4;
    // region 1: transposed/split weights + Ml
    ushort_t* WqkvTh = (ushort_t*)(ws + off); off += (size_t)QKV3 * CIN * 2;
    ushort_t* WqkvTl = (ushort_t*)(ws + off); off += (size_t)QKV3 * CIN * 2;
    ushort_t* WoutTh = (ushort_t*)(ws + off); off += (size_t)HD * CIN * 2;
    ushort_t* WoutTl = (ushort_t*)(ws + off); off += (size_t)HD * CIN * 2;
    float*    MlP    = (float*)(ws + off);    off += (size_t)ns * 16 * NSEQ * 2 * 4;
    // region 2 (25.2 MB): Q/K/Vt bf16 hi/lo
    char* reg2 = ws + off;
    ushort_t* Qh  = (ushort_t*)reg2;
    ushort_t* Ql  = Qh + NE;
    ushort_t* Kh  = Ql + NE;
    ushort_t* Kl  = Kh + NE;
    ushort_t* Vth = Kl + NE;
    ushort_t* Vtl = Vth + NE;

    // 1. both weight splits in one launch
    split_wT_kernel<<<dim3(32, CIN/64), 256, 0, stream>>>(
        w_qkv, w_out, WqkvTh, WqkvTl, WoutTh, WoutTl);
    // 2. qkv projection (swizzled-LDS GEMM, 48KB -> 3 blocks/CU)
    gemm_split_kernel<<<dim3(QKV3/64, M/128), 256, 0, stream>>>(
        x, WqkvTh, WqkvTl, qkv_lin, M, QKV3, CIN);
    // 3. fused l2norm/split + V transpose
    qkv_prep_kernel<<<dim3(BATCH * HEADS * (NSEQ/64)), 256, 0, stream>>>(
        qkv_lin, Qh, Ql, Kh, Kl, Vth, Vtl);
    // 4. attention (j-split 3; Opart overwrites qkv_lin)
    attn_mfma_kernel<<<dim3(256 * ns), 256, 0, stream>>>(
        Qh, Ql, Kh, Kl, Vth, Vtl, pos_bias, temp, mask, OpartP, MlP,
        ns, base, rem);
    // 5. out projection with fused 3-way merge (reads Opart+Ml directly)
    gemm_merge_kernel<<<dim3(CIN/64, M/64), 256, 0, stream>>>(
        OpartP, MlP, WoutTh, WoutTl, out);
}

// Round 13
// 171.839 us; speedup vs baseline: 1.3682x; 1.0283x over previous
//
#include <hip/hip_runtime.h>
#include <cfloat>
#include <cstdint>

#define BATCH 2
#define NSEQ 2048
#define CIN 512
#define HEADS 8
#define DIM 64
#define HD 512
#define QKV3 1536

typedef short short8 __attribute__((ext_vector_type(8)));
typedef float f32x4 __attribute__((ext_vector_type(4)));
typedef unsigned short ushort_t;

__device__ __forceinline__ unsigned short f2bf(float f) {
    return (unsigned short)(__float_as_uint(f) >> 16);
}
__device__ __forceinline__ float bf2f(unsigned short h) {
    return __uint_as_float(((unsigned int)h) << 16);
}
__device__ __forceinline__ float bftrunc(float f) {   // bf2f(f2bf(f)), 1 AND
    return __uint_as_float(__float_as_uint(f) & 0xffff0000u);
}
// T2 XOR swizzle (ushort-index units): toggles the 8-ushort (16B) slot
// within a 64-ushort (128B) row; bank set then depends only on slot.
#define SWZ(row, col) ((col) ^ (((row) & 7) << 3))

// ---------- split + transpose BOTH weights in one launch ------------------
__global__ __launch_bounds__(256) void split_wT_kernel(
    const float* __restrict__ Wq, const float* __restrict__ Wo,
    ushort_t* __restrict__ WqTh, ushort_t* __restrict__ WqTl,
    ushort_t* __restrict__ WoTh, ushort_t* __restrict__ WoTl)
{
    __shared__ float T[64][65];
    const int bx = blockIdx.x;
    const float* W; ushort_t *WTh, *WTl; int N, n0;
    if (bx < 24) { W = Wq; WTh = WqTh; WTl = WqTl; N = QKV3; n0 = bx * 64; }
    else         { W = Wo; WTh = WoTh; WTl = WoTl; N = HD;   n0 = (bx - 24) * 64; }
    const int K = CIN;
    const int k0 = blockIdx.y * 64;
    const int tid = threadIdx.x;
    #pragma unroll
    for (int i = 0; i < 4; ++i) {
        int c = tid + i * 256;
        int row = c >> 4, c4 = c & 15;
        *(float4*)&T[row][c4*4] = *(const float4*)(W + (size_t)(k0 + row) * N + n0 + c4*4);
    }
    __syncthreads();
    const int n = tid >> 2, kseg = tid & 3;
    short8 hh0, ll0, hh1, ll1;
    #pragma unroll
    for (int e = 0; e < 8; ++e) {
        float x0 = T[kseg*16 + e][n];
        unsigned short h0 = f2bf(x0);
        hh0[e] = (short)h0; ll0[e] = (short)f2bf(x0 - bf2f(h0));
        float x1 = T[kseg*16 + 8 + e][n];
        unsigned short h1 = f2bf(x1);
        hh1[e] = (short)h1; ll1[e] = (short)f2bf(x1 - bf2f(h1));
    }
    size_t o = (size_t)(n0 + n) * K + k0 + kseg * 16;
    *(short8*)(WTh + o)     = hh0;
    *(short8*)(WTh + o + 8) = hh1;
    *(short8*)(WTl + o)     = ll0;
    *(short8*)(WTl + o + 8) = ll1;
}

// ---------- split-bf16 MFMA GEMM: C[M][N] = A[M][K](f32) @ BT[N][K](bf16 h/l) --
// BM=128 BN=64 BK=64; stage-time A conversion; XOR-swizzled LDS (48KB -> 3 blk/CU)
__global__ __launch_bounds__(256, 2) void gemm_split_kernel(
    const float* __restrict__ A, const ushort_t* __restrict__ BTh,
    const ushort_t* __restrict__ BTl, float* __restrict__ C,
    int M, int N, int K)
{
    __shared__ ushort_t Ash[128][64], Asl[128][64];   // 32,768 B
    __shared__ ushort_t Bsh[64][64],  Bsl[64][64];    // 16,384 B
    const int bm = blockIdx.y * 128, bn = blockIdx.x * 64;
    const int tid = threadIdx.x;
    const int wave = tid >> 6, lane = tid & 63;
    const int lg = lane >> 4, lm = lane & 15;
    const int wm = wave >> 1, wn = wave & 1;
    const int arow = tid >> 3, aseg = tid & 7;
    const int scol = SWZ(arow, aseg * 8);   // stage col (row&7 invariant over +32i)

    f32x4 acc[4][2];
    #pragma unroll
    for (int mf = 0; mf < 4; ++mf)
        #pragma unroll
        for (int nf = 0; nf < 2; ++nf) acc[mf][nf] = (f32x4){0.f,0.f,0.f,0.f};

    float4 ar[8];
    uint4 brh[2], brl[2];
    const int nkt = K >> 6;

    #define G_ISSUE(K0)                                                          \
        { _Pragma("unroll")                                                      \
          for (int i = 0; i < 4; ++i) {                                          \
            const float* ap = A + (size_t)(bm + arow + 32*i) * K + (K0) + aseg*8;\
            ar[2*i]   = *(const float4*)ap;                                      \
            ar[2*i+1] = *(const float4*)(ap + 4);                                \
          }                                                                      \
          _Pragma("unroll")                                                      \
          for (int i = 0; i < 2; ++i) {                                          \
            size_t bo = (size_t)(bn + arow + 32*i) * K + (K0) + aseg*8;          \
            brh[i] = *(const uint4*)(BTh + bo);                                  \
            brl[i] = *(const uint4*)(BTl + bo);                                  \
          } }

    G_ISSUE(0)
    for (int kt = 0; kt < nkt; ++kt) {
        __syncthreads();
        #pragma unroll
        for (int i = 0; i < 4; ++i) {
            float av[8];
            *(float4*)&av[0] = ar[2*i];
            *(float4*)&av[4] = ar[2*i+1];
            short8 hh, ll;
            #pragma unroll
            for (int e = 0; e < 8; ++e) {
                unsigned short hi = f2bf(av[e]);
                hh[e] = (short)hi;
                ll[e] = (short)f2bf(av[e] - bf2f(hi));
            }
            *(short8*)&Ash[arow + 32*i][scol] = hh;
            *(short8*)&Asl[arow + 32*i][scol] = ll;
        }
        #pragma unroll
        for (int i = 0; i < 2; ++i) {
            *(uint4*)&Bsh[arow + 32*i][scol] = brh[i];
            *(uint4*)&Bsl[arow + 32*i][scol] = brl[i];
        }
        if (kt + 1 < nkt) G_ISSUE((kt + 1) * 64)
        __syncthreads();
        #pragma unroll
        for (int ks = 0; ks < 2; ++ks) {
            const int rcol = SWZ(lm, ks*32 + lg*8);   // read col (row&7 == lm&7)
            short8 afh[4], afl[4], bfh[2], bfl[2];
            #pragma unroll
            for (int mf = 0; mf < 4; ++mf) {
                afh[mf] = *(const short8*)&Ash[wm*64 + mf*16 + lm][rcol];
                afl[mf] = *(const short8*)&Asl[wm*64 + mf*16 + lm][rcol];
            }
            #pragma unroll
            for (int nf = 0; nf < 2; ++nf) {
                bfh[nf] = *(const short8*)&Bsh[wn*32 + nf*16 + lm][rcol];
                bfl[nf] = *(const short8*)&Bsl[wn*32 + nf*16 + lm][rcol];
            }
            #pragma unroll
            for (int mf = 0; mf < 4; ++mf)
                #pragma unroll
                for (int nf = 0; nf < 2; ++nf) {
                    acc[mf][nf] = __builtin_amdgcn_mfma_f32_16x16x32_bf16(afh[mf], bfh[nf], acc[mf][nf], 0, 0, 0);
                    acc[mf][nf] = __builtin_amdgcn_mfma_f32_16x16x32_bf16(afh[mf], bfl[nf], acc[mf][nf], 0, 0, 0);
                    acc[mf][nf] = __builtin_amdgcn_mfma_f32_16x16x32_bf16(afl[mf], bfh[nf], acc[mf][nf], 0, 0, 0);
                }
        }
    }
    #pragma unroll
    for (int mf = 0; mf < 4; ++mf)
        #pragma unroll
        for (int nf = 0; nf < 2; ++nf)
            #pragma unroll
            for (int r = 0; r < 4; ++r)
                C[(size_t)(bm + wm*64 + mf*16 + lg*4 + r) * N + bn + wn*32 + nf*16 + lm]
                    = acc[mf][nf][r];
    #undef G_ISSUE
}

// ---------- out-proj GEMM with FUSED 3-way merge; swizzled LDS (32KB) -----
// out[M][512] = merge(Opart,Ml) @ WoutT;  BM=64 BN=64 BK=64 (h = kt)
__global__ __launch_bounds__(256, 2) void gemm_merge_kernel(
    const float* __restrict__ Opart, const float* __restrict__ Ml,
    const ushort_t* __restrict__ BTh, const ushort_t* __restrict__ BTl,
    float* __restrict__ C)
{
    __shared__ ushort_t Ash[64][64], Asl[64][64];  // 16,384 B
    __shared__ ushort_t Bsh[64][64], Bsl[64][64];  // 16,384 B
    const int bm = blockIdx.y * 64, bn = blockIdx.x * 64;
    const int tid = threadIdx.x;
    const int wave = tid >> 6, lane = tid & 63;
    const int lg = lane >> 4, lm = lane & 15;
    const int wm = wave >> 1, wn = wave & 1;
    const int srow = tid >> 2, sseg = tid & 3;    // stage: 64 rows x 4 segs of 16
    const int sc0 = SWZ(srow, sseg * 16);
    const int sc1 = SWZ(srow, sseg * 16 + 8);

    f32x4 acc[2][2];
    #pragma unroll
    for (int mf = 0; mf < 2; ++mf)
        #pragma unroll
        for (int nf = 0; nf < 2; ++nf) acc[mf][nf] = (f32x4){0.f,0.f,0.f,0.f};

    float4 ar[4];
    uint4 brh[2], brl[2];

    #define GM_ISSUE(KT) {                                                      \
        const int h_ = (KT);                                                    \
        const int mrow = bm + srow;                                             \
        const int b_ = mrow >> 11, n_ = mrow & (NSEQ - 1);                      \
        float mv0, mv1, mv2, lv0, lv1, lv2;                                     \
        { size_t mi = ((size_t)(b_*8 + h_) * NSEQ + n_) * 2;                    \
          mv0 = Ml[mi]; lv0 = Ml[mi+1];                                         \
          mi = ((size_t)(16 + b_*8 + h_) * NSEQ + n_) * 2;                      \
          mv1 = Ml[mi]; lv1 = Ml[mi+1];                                         \
          mi = ((size_t)(32 + b_*8 + h_) * NSEQ + n_) * 2;                      \
          mv2 = Ml[mi]; lv2 = Ml[mi+1]; }                                       \
        float mm = fmaxf(fmaxf(mv0, mv1), mv2);                                 \
        float w0 = __expf(mv0 - mm), w1 = __expf(mv1 - mm), w2 = __expf(mv2 - mm);\
        float inv = 1.f / (lv0*w0 + lv1*w1 + lv2*w2);                           \
        size_t o0 = ((size_t)(b_*8 + h_) * NSEQ + n_) * 64 + sseg*16;           \
        size_t o1 = ((size_t)(16 + b_*8 + h_) * NSEQ + n_) * 64 + sseg*16;      \
        size_t o2 = ((size_t)(32 + b_*8 + h_) * NSEQ + n_) * 64 + sseg*16;      \
        _Pragma("unroll")                                                       \
        for (int c = 0; c < 4; ++c) {                                           \
            float4 v0 = *(const float4*)(Opart + o0 + c*4);                     \
            float4 v1 = *(const float4*)(Opart + o1 + c*4);                     \
            float4 v2 = *(const float4*)(Opart + o2 + c*4);                     \
            ar[c].x = (v0.x*w0 + v1.x*w1 + v2.x*w2) * inv;                      \
            ar[c].y = (v0.y*w0 + v1.y*w1 + v2.y*w2) * inv;                      \
            ar[c].z = (v0.z*w0 + v1.z*w1 + v2.z*w2) * inv;                      \
            ar[c].w = (v0.w*w0 + v1.w*w1 + v2.w*w2) * inv;                      \
        }                                                                       \
        size_t bo = (size_t)(bn + srow) * CIN + (KT)*64 + sseg*16;              \
        brh[0] = *(const uint4*)(BTh + bo);                                     \
        brh[1] = *(const uint4*)(BTh + bo + 8);                                 \
        brl[0] = *(const uint4*)(BTl + bo);                                     \
        brl[1] = *(const uint4*)(BTl + bo + 8); }

    GM_ISSUE(0)
    for (int kt = 0; kt < 8; ++kt) {
        __syncthreads();
        {   // stage-time f32 -> bf16 hi/lo (proven gemm_split pattern)
            short8 hh0, ll0, hh1, ll1;
            float av[16];
            *(float4*)&av[0]  = ar[0];
            *(float4*)&av[4]  = ar[1];
            *(float4*)&av[8]  = ar[2];
            *(float4*)&av[12] = ar[3];
            #pragma unroll
            for (int e = 0; e < 8; ++e) {
                unsigned short h0 = f2bf(av[e]);
                hh0[e] = (short)h0; ll0[e] = (short)f2bf(av[e] - bf2f(h0));
                unsigned short h1 = f2bf(av[e + 8]);
                hh1[e] = (short)h1; ll1[e] = (short)f2bf(av[e + 8] - bf2f(h1));
            }
            *(short8*)&Ash[srow][sc0] = hh0;
            *(short8*)&Ash[srow][sc1] = hh1;
            *(short8*)&Asl[srow][sc0] = ll0;
            *(short8*)&Asl[srow][sc1] = ll1;
        }
        *(uint4*)&Bsh[srow][sc0] = brh[0];
        *(uint4*)&Bsh[srow][sc1] = brh[1];
        *(uint4*)&Bsl[srow][sc0] = brl[0];
        *(uint4*)&Bsl[srow][sc1] = brl[1];
        if (kt + 1 < 8) GM_ISSUE(kt + 1)
        __syncthreads();
        #pragma unroll
        for (int ks = 0; ks < 2; ++ks) {
            const int rcol = SWZ(lm, ks*32 + lg*8);
            short8 afh[2], afl[2], bfh[2], bfl[2];
            #pragma unroll
            for (int mf = 0; mf < 2; ++mf) {
                afh[mf] = *(const short8*)&Ash[wm*32 + mf*16 + lm][rcol];
                afl[mf] = *(const short8*)&Asl[wm*32 + mf*16 + lm][rcol];
            }
            #pragma unroll
            for (int nf = 0; nf < 2; ++nf) {
                bfh[nf] = *(const short8*)&Bsh[wn*32 + nf*16 + lm][rcol];
                bfl[nf] = *(const short8*)&Bsl[wn*32 + nf*16 + lm][rcol];
            }
            #pragma unroll
            for (int mf = 0; mf < 2; ++mf)
                #pragma unroll
                for (int nf = 0; nf < 2; ++nf) {
                    acc[mf][nf] = __builtin_amdgcn_mfma_f32_16x16x32_bf16(afh[mf], bfh[nf], acc[mf][nf], 0, 0, 0);
                    acc[mf][nf] = __builtin_amdgcn_mfma_f32_16x16x32_bf16(afh[mf], bfl[nf], acc[mf][nf], 0, 0, 0);
                    acc[mf][nf] = __builtin_amdgcn_mfma_f32_16x16x32_bf16(afl[mf], bfh[nf], acc[mf][nf], 0, 0, 0);
                }
        }
    }
    #pragma unroll
    for (int mf = 0; mf < 2; ++mf)
        #pragma unroll
        for (int nf = 0; nf < 2; ++nf)
            #pragma unroll
            for (int r = 0; r < 4; ++r)
                C[(size_t)(bm + wm*32 + mf*16 + lg*4 + r) * CIN + bn + wn*32 + nf*16 + lm]
                    = acc[mf][nf][r];
    #undef GM_ISSUE
}

// ------- fused qkv prep: l2norm+split Q,K  and  transposed/permuted V ----
__global__ __launch_bounds__(256) void qkv_prep_kernel(
    const float* __restrict__ qkv,
    ushort_t* __restrict__ Qh, ushort_t* __restrict__ Ql,
    ushort_t* __restrict__ Kh, ushort_t* __restrict__ Kl,
    ushort_t* __restrict__ Vth, ushort_t* __restrict__ Vtl)
{
    __shared__ float Vf[64][65];
    const int id = blockIdx.x;
    const int bh = id >> 5, nt = id & 31;
    const int b = bh >> 3, h = bh & 7;
    const int n0 = nt * 64;
    const int tid = threadIdx.x;
    {
        const int row = tid >> 2, dseg = tid & 3;
        const float* src = qkv + ((size_t)(b * NSEQ + n0 + row)) * QKV3
                         + h * 192 + dseg * 48;
        float f[48];
        #pragma unroll
        for (int i = 0; i < 12; ++i)
            *(float4*)&f[i*4] = *(const float4*)(src + i*4);
        float nq = 0.f, nk = 0.f;
        #pragma unroll
        for (int e = 0; e < 16; ++e) {
            nq = fmaf(f[3*e], f[3*e], nq);
            nk = fmaf(f[3*e+1], f[3*e+1], nk);
        }
        nq += __shfl_xor(nq, 1); nq += __shfl_xor(nq, 2);
        nk += __shfl_xor(nk, 1); nk += __shfl_xor(nk, 2);
        float rq = 1.f / fmaxf(sqrtf(nq), 1e-12f);
        float rk = 1.f / fmaxf(sqrtf(nk), 1e-12f);
        short8 qh8[2], ql8[2], kh8[2], kl8[2];
        #pragma unroll
        for (int e = 0; e < 16; ++e) {
            float q = f[3*e] * rq, k = f[3*e+1] * rk;
            unsigned short qhi = f2bf(q), khi = f2bf(k);
            qh8[e>>3][e&7] = (short)qhi;
            ql8[e>>3][e&7] = (short)f2bf(q - bf2f(qhi));
            kh8[e>>3][e&7] = (short)khi;
            kl8[e>>3][e&7] = (short)f2bf(k - bf2f(khi));
            Vf[dseg*16 + e][row] = f[3*e+2];
        }
        size_t o = ((size_t)bh * NSEQ + n0 + row) * DIM + dseg * 16;
        *(short8*)(Qh + o) = qh8[0]; *(short8*)(Qh + o + 8) = qh8[1];
        *(short8*)(Ql + o) = ql8[0]; *(short8*)(Ql + o + 8) = ql8[1];
        *(short8*)(Kh + o) = kh8[0]; *(short8*)(Kh + o + 8) = kh8[1];
        *(short8*)(Kl + o) = kl8[0]; *(short8*)(Kl + o + 8) = kl8[1];
    }
    __syncthreads();
    {   // Vt[bh][d][n] with the PV fragment j-permutation (within 32-blocks)
        const int d = tid >> 2, seg = tid & 3;
        ushort_t th[16], tl[16];
        #pragma unroll
        for (int t = 0; t < 16; ++t) {
            int p = seg * 16 + t;
            int s = (p & 35) | ((p & 4) << 2) | ((p >> 1) & 12);
            float v = Vf[d][s];
            unsigned short hi = f2bf(v);
            th[t] = hi;
            tl[t] = f2bf(v - bf2f(hi));
        }
        size_t o = ((size_t)bh * DIM + d) * NSEQ + n0 + seg * 16;
        *(uint4*)(Vth + o)     = *(uint4*)&th[0];
        *(uint4*)(Vth + o + 8) = *(uint4*)&th[8];
        *(uint4*)(Vtl + o)     = *(uint4*)&tl[0];
        *(uint4*)(Vtl + o + 8) = *(uint4*)&tl[8];
    }
}

// ---------------- MFMA flash attention v8: truncated-P softmax ------------
// PV = Ph*(Vh+Vl) with l = sum(bf-truncated P) -> exact softmax in weights Ph
__global__ __launch_bounds__(256, 3) void attn_mfma_kernel(
    const ushort_t* __restrict__ Qh, const ushort_t* __restrict__ Ql,
    const ushort_t* __restrict__ Kh, const ushort_t* __restrict__ Kl,
    const ushort_t* __restrict__ Vth, const ushort_t* __restrict__ Vtl,
    const float* __restrict__ bias, const float* __restrict__ temp_p,
    const uint8_t* __restrict__ mask,
    float* __restrict__ Opart, float* __restrict__ Ml,
    int ns, int base, int rem)
{
    __shared__ ushort_t KsH[2][32][72], KsL[2][32][72];   // [buf][j][d]
    __shared__ ushort_t VsH[2][64][36], VsL[2][64][36];   // [buf][d][j-perm]

    const int id = blockIdx.x;
    const int h = id & 7;                  // XCD-grouped
    const int rest = id >> 3;
    const int per_b = 16 * ns;
    const int b = rest / per_b;
    const int r2 = rest - b * per_b;
    const int js = r2 >> 4;
    const int qt = r2 & 15;
    const int bh = b * 8 + h;
    const int i0 = qt * 128;
    const int tid = threadIdx.x;
    const int wave = tid >> 6, lane = tid & 63;
    const int lg = lane >> 4, lm = lane & 15;
    const int qbase = i0 + wave * 32;
    const float temp = *temp_p;
    const int krow = tid >> 3, kseg = tid & 7;
    const int vrow = tid >> 2, vseg = tid & 3;

    short8 qfh[2][2], qfl[2][2];
    #pragma unroll
    for (int m = 0; m < 2; ++m) {
        size_t qo = ((size_t)(bh * NSEQ + qbase + 16*m + lm)) * DIM + lg * 8;
        qfh[m][0] = *(const short8*)(Qh + qo);
        qfh[m][1] = *(const short8*)(Qh + qo + 32);
        qfl[m][0] = *(const short8*)(Ql + qo);
        qfl[m][1] = *(const short8*)(Ql + qo + 32);
    }
    bool rowm[2];
    rowm[0] = mask[(size_t)b * NSEQ + qbase + lm] != 0;
    rowm[1] = mask[(size_t)b * NSEQ + qbase + 16 + lm] != 0;

    float m_r[2] = {-FLT_MAX, -FLT_MAX};
    float l_r[2] = {0.f, 0.f};
    f32x4 oa[2][4];
    #pragma unroll
    for (int m = 0; m < 2; ++m)
        #pragma unroll
        for (int dt = 0; dt < 4; ++dt) oa[m][dt] = (f32x4){0.f,0.f,0.f,0.f};

    const int NT = base + (js < rem ? 1 : 0);
    const int tstart = js * base + (js < rem ? js : rem);
    const int jbase = tstart * 32;
    uint4 skh, skl, svh, svl;

    #define A_ISSUE(J0) {                                                      \
        size_t gk = ((size_t)(bh * NSEQ) + (J0) + krow) * DIM + kseg*8;        \
        size_t gv = ((size_t)(bh * DIM) + vrow) * NSEQ + (J0) + vseg*8;        \
        skh = *(const uint4*)(Kh  + gk);                                       \
        skl = *(const uint4*)(Kl  + gk);                                       \
        svh = *(const uint4*)(Vth + gv);                                       \
        svl = *(const uint4*)(Vtl + gv); }
    #define STAGE(BUF) {                                                       \
        *(uint4*)&KsH[BUF][krow][kseg*8] = skh;                                \
        *(uint4*)&KsL[BUF][krow][kseg*8] = skl;                                \
        *(uint4*)&VsH[BUF][vrow][vseg*8] = svh;                                \
        *(uint4*)&VsL[BUF][vrow][vseg*8] = svl; }

    A_ISSUE(jbase)
    STAGE(0)
    A_ISSUE(jbase + 32)
    float4 bb[2][2];
    #pragma unroll
    for (int m = 0; m < 2; ++m)
        #pragma unroll
        for (int jt = 0; jt < 2; ++jt)
            bb[m][jt] = *(const float4*)(bias
                + ((size_t)h * NSEQ + qbase + 16*m + lm) * NSEQ
                + jbase + jt*16 + lg*4);
    uint8_t mk = mask[(size_t)b * NSEQ + jbase + (lane & 31)];
    __syncthreads();

    #pragma unroll 2
    for (int t = 0; t < NT; ++t) {
        const int cur = t & 1;
        const int j0 = jbase + t * 32;

        float4 bbn[2][2];
        uint8_t mkn = 0;
        if (t + 1 < NT) {
            #pragma unroll
            for (int m = 0; m < 2; ++m)
                #pragma unroll
                for (int jt = 0; jt < 2; ++jt)
                    bbn[m][jt] = *(const float4*)(bias
                        + ((size_t)h * NSEQ + qbase + 16*m + lm) * NSEQ
                        + j0 + 32 + jt*16 + lg*4);
            mkn = mask[(size_t)b * NSEQ + j0 + 32 + (lane & 31)];
            STAGE(cur ^ 1)
            if (t + 2 < NT) A_ISSUE(j0 + 64)
        }
        unsigned long long bal = __ballot(mk != 0);

        f32x4 sac[2][2];
        #pragma unroll
        for (int m = 0; m < 2; ++m)
            #pragma unroll
            for (int jt = 0; jt < 2; ++jt) sac[m][jt] = (f32x4){0.f,0.f,0.f,0.f};
        __builtin_amdgcn_s_setprio(1);
        #pragma unroll
        for (int jt = 0; jt < 2; ++jt)
            #pragma unroll
            for (int ks = 0; ks < 2; ++ks) {
                short8 kbh = *(const short8*)(&KsH[cur][jt*16 + lm][ks*32 + lg*8]);
                short8 kbl = *(const short8*)(&KsL[cur][jt*16 + lm][ks*32 + lg*8]);
                #pragma unroll
                for (int m = 0; m < 2; ++m) {
                    sac[m][jt] = __builtin_amdgcn_mfma_f32_16x16x32_bf16(kbh, qfh[m][ks], sac[m][jt], 0, 0, 0);
                    sac[m][jt] = __builtin_amdgcn_mfma_f32_16x16x32_bf16(kbh, qfl[m][ks], sac[m][jt], 0, 0, 0);
                    sac[m][jt] = __builtin_amdgcn_mfma_f32_16x16x32_bf16(kbl, qfh[m][ks], sac[m][jt], 0, 0, 0);
                }
            }
        __builtin_amdgcn_s_setprio(0);

        short8 pah[2];
        #pragma unroll
        for (int m = 0; m < 2; ++m) {
            float sv[2][4];
            #pragma unroll
            for (int jt = 0; jt < 2; ++jt) {
                unsigned int nib = (unsigned int)(bal >> (jt*16 + lg*4)) & 0xFu;
                #pragma unroll
                for (int r = 0; r < 4; ++r) {
                    bool dead = rowm[m] || ((nib >> r) & 1u);
                    float bv = (r == 0) ? bb[m][jt].x : (r == 1) ? bb[m][jt].y
                             : (r == 2) ? bb[m][jt].z : bb[m][jt].w;
                    sv[jt][r] = dead ? -FLT_MAX : fmaf(sac[m][jt][r], temp, bv);
                }
            }
            float pmax = fmaxf(fmaxf(fmaxf(sv[0][0], sv[0][1]), fmaxf(sv[0][2], sv[0][3])),
                               fmaxf(fmaxf(sv[1][0], sv[1][1]), fmaxf(sv[1][2], sv[1][3])));
            pmax = fmaxf(pmax, __shfl_xor(pmax, 16));
            pmax = fmaxf(pmax, __shfl_xor(pmax, 32));
            if (!__all(pmax <= m_r[m] + 8.f)) {
                float mn = fmaxf(m_r[m], pmax);
                float sc = __expf(m_r[m] - mn);
                m_r[m] = mn;
                l_r[m] *= sc;
                #pragma unroll
                for (int r = 0; r < 4; ++r) {
                    float sq = __shfl(sc, lg*4 + r);
                    #pragma unroll
                    for (int dt = 0; dt < 4; ++dt) oa[m][dt][r] *= sq;
                }
            }
            float rs = 0.f;
            #pragma unroll
            for (int jt = 0; jt < 2; ++jt)
                #pragma unroll
                for (int r = 0; r < 4; ++r) {
                    float pf = __expf(sv[jt][r] - m_r[m]);
                    // truncated weight: O uses Ph, so l must sum Ph too
                    rs += bftrunc(pf);
                    pah[m][jt*4 + r] = (short)f2bf(pf);
                }
            rs += __shfl_xor(rs, 16);
            rs += __shfl_xor(rs, 32);
            l_r[m] += rs;
        }

        // ---- O += Ph.V  (Ph*Vh + Ph*Vl; Pl term dropped, l consistent) ----
        __builtin_amdgcn_s_setprio(1);
        #pragma unroll
        for (int dt = 0; dt < 4; ++dt) {
            short8 vbh = *(const short8*)(&VsH[cur][dt*16 + lm][lg*8]);
            short8 vbl = *(const short8*)(&VsL[cur][dt*16 + lm][lg*8]);
            #pragma unroll
            for (int m = 0; m < 2; ++m) {
                oa[m][dt] = __builtin_amdgcn_mfma_f32_16x16x32_bf16(pah[m], vbh, oa[m][dt], 0, 0, 0);
                oa[m][dt] = __builtin_amdgcn_mfma_f32_16x16x32_bf16(pah[m], vbl, oa[m][dt], 0, 0, 0);
            }
        }
        __builtin_amdgcn_s_setprio(0);
        __syncthreads();
        #pragma unroll
        for (int m = 0; m < 2; ++m)
            #pragma unroll
            for (int jt = 0; jt < 2; ++jt) bb[m][jt] = bbn[m][jt];
        mk = mkn;
    }
    #undef A_ISSUE
    #undef STAGE

    #pragma unroll
    for (int m = 0; m < 2; ++m)
        #pragma unroll
        for (int dt = 0; dt < 4; ++dt)
            #pragma unroll
            for (int r = 0; r < 4; ++r)
                Opart[((size_t)(js*16 + bh) * NSEQ + qbase + 16*m + lg*4 + r) * 64
                      + dt*16 + lm] = oa[m][dt][r];
    if (lane < 16) {
        #pragma unroll
        for (int m = 0; m < 2; ++m) {
            size_t mi = ((size_t)(js*16 + bh) * NSEQ + qbase + 16*m + lm) * 2;
            Ml[mi]     = m_r[m];
            Ml[mi + 1] = l_r[m];
        }
    }
}

extern "C" void kernel_launch(void* const* d_in, const int* in_sizes, int n_in,
                              void* d_out, int out_size, void* d_ws, size_t ws_size,
                              hipStream_t stream)
{
    const float*   x        = (const float*)d_in[0];
    const float*   w_qkv    = (const float*)d_in[1];
    const float*   w_out    = (const float*)d_in[2];
    const float*   pos_bias = (const float*)d_in[3];
    const float*   temp     = (const float*)d_in[4];
    const uint8_t* mask     = (const uint8_t*)d_in[5];
    float* out = (float*)d_out;

    const int M = BATCH * NSEQ;                        // 4096
    const size_t NE = (size_t)BATCH * HEADS * NSEQ * DIM;
    const int ns = 3;                                  // grid 768 = 3 blocks/CU exactly
    const int base = 64 / ns, rem = 64 % ns;

    char* ws = (char*)d_ws;
    // region 0 (25.2 MB): qkv_lin f32; exactly reused by the 3-split f32 Opart
    float* qkv_lin = (float*)ws;
    float* OpartP  = (float*)ws;    // 3*16*2048*64*4 B == M*QKV3*4 B exactly
    size_t off = (size_t)M * QKV3 * 4;
    // region 1: transposed/split weights + Ml
    ushort_t* WqkvTh = (ushort_t*)(ws + off); off += (size_t)QKV3 * CIN * 2;
    ushort_t* WqkvTl = (ushort_t*)(ws + off); off += (size_t)QKV3 * CIN * 2;
    ushort_t* WoutTh = (ushort_t*)(ws + off); off += (size_t)HD * CIN * 2;
    ushort_t* WoutTl = (ushort_t*)(ws + off); off += (size_t)HD * CIN * 2;
    float*    MlP    = (float*)(ws + off);    off += (size_t)ns * 16 * NSEQ * 2 * 4;
    // region 2 (25.2 MB): Q/K/Vt bf16 hi/lo
    char* reg2 = ws + off;
    ushort_t* Qh  = (ushort_t*)reg2;
    ushort_t* Ql  = Qh + NE;
    ushort_t* Kh  = Ql + NE;
    ushort_t* Kl  = Kh + NE;
    ushort_t* Vth = Kl + NE;
    ushort_t* Vtl = Vth + NE;

    // 1. both weight splits in one launch
    split_wT_kernel<<<dim3(32, CIN/64), 256, 0, stream>>>(
        w_qkv, w_out, WqkvTh, WqkvTl, WoutTh, WoutTl);
    // 2. qkv projection (swizzled-LDS GEMM, 48KB -> 3 blocks/CU)
    gemm_split_kernel<<<dim3(QKV3/64, M/128), 256, 0, stream>>>(
        x, WqkvTh, WqkvTl, qkv_lin, M, QKV3, CIN);
    // 3. fused l2norm/split + V transpose
    qkv_prep_kernel<<<dim3(BATCH * HEADS * (NSEQ/64)), 256, 0, stream>>>(
        qkv_lin, Qh, Ql, Kh, Kl, Vth, Vtl);
    // 4. attention (j-split 3; Opart overwrites qkv_lin)
    attn_mfma_kernel<<<dim3(256 * ns), 256, 0, stream>>>(
        Qh, Ql, Kh, Kl, Vth, Vtl, pos_bias, temp, mask, OpartP, MlP,
        ns, base, rem);
    // 5. out projection with fused 3-way merge (reads Opart+Ml directly)
    gemm_merge_kernel<<<dim3(CIN/64, M/64), 256, 0, stream>>>(
        OpartP, MlP, WoutTh, WoutTl, out);
}

// Round 14
// 152.016 us; speedup vs baseline: 1.5466x; 1.1304x over previous
//
#include <hip/hip_runtime.h>
#include <cfloat>
#include <cstdint>

#define BATCH 2
#define NSEQ 2048
#define CIN 512
#define HEADS 8
#define DIM 64
#define HD 512
#define QKV3 1536

typedef short short8 __attribute__((ext_vector_type(8)));
typedef _Float16 half8 __attribute__((ext_vector_type(8)));
typedef float f32x4 __attribute__((ext_vector_type(4)));
typedef unsigned short ushort_t;

__device__ __forceinline__ unsigned short f2bf(float f) {
    return (unsigned short)(__float_as_uint(f) >> 16);
}
__device__ __forceinline__ float bf2f(unsigned short h) {
    return __uint_as_float(((unsigned int)h) << 16);
}
// T2 XOR swizzle (ushort-index units): toggles the 8-ushort (16B) slot
// within a 64-ushort (128B) row; bank set then depends only on slot.
#define SWZ(row, col) ((col) ^ (((row) & 7) << 3))

// ---------- split + transpose BOTH weights in one launch ------------------
__global__ __launch_bounds__(256) void split_wT_kernel(
    const float* __restrict__ Wq, const float* __restrict__ Wo,
    ushort_t* __restrict__ WqTh, ushort_t* __restrict__ WqTl,
    ushort_t* __restrict__ WoTh, ushort_t* __restrict__ WoTl)
{
    __shared__ float T[64][65];
    const int bx = blockIdx.x;
    const float* W; ushort_t *WTh, *WTl; int N, n0;
    if (bx < 24) { W = Wq; WTh = WqTh; WTl = WqTl; N = QKV3; n0 = bx * 64; }
    else         { W = Wo; WTh = WoTh; WTl = WoTl; N = HD;   n0 = (bx - 24) * 64; }
    const int K = CIN;
    const int k0 = blockIdx.y * 64;
    const int tid = threadIdx.x;
    #pragma unroll
    for (int i = 0; i < 4; ++i) {
        int c = tid + i * 256;
        int row = c >> 4, c4 = c & 15;
        *(float4*)&T[row][c4*4] = *(const float4*)(W + (size_t)(k0 + row) * N + n0 + c4*4);
    }
    __syncthreads();
    const int n = tid >> 2, kseg = tid & 3;
    short8 hh0, ll0, hh1, ll1;
    #pragma unroll
    for (int e = 0; e < 8; ++e) {
        float x0 = T[kseg*16 + e][n];
        unsigned short h0 = f2bf(x0);
        hh0[e] = (short)h0; ll0[e] = (short)f2bf(x0 - bf2f(h0));
        float x1 = T[kseg*16 + 8 + e][n];
        unsigned short h1 = f2bf(x1);
        hh1[e] = (short)h1; ll1[e] = (short)f2bf(x1 - bf2f(h1));
    }
    size_t o = (size_t)(n0 + n) * K + k0 + kseg * 16;
    *(short8*)(WTh + o)     = hh0;
    *(short8*)(WTh + o + 8) = hh1;
    *(short8*)(WTl + o)     = ll0;
    *(short8*)(WTl + o + 8) = ll1;
}

// ---------- split-bf16 MFMA GEMM: C[M][N] = A[M][K](f32) @ BT[N][K](bf16 h/l) --
// BM=128 BN=64 BK=64; stage-time A conversion; XOR-swizzled LDS (48KB)
__global__ __launch_bounds__(256, 2) void gemm_split_kernel(
    const float* __restrict__ A, const ushort_t* __restrict__ BTh,
    const ushort_t* __restrict__ BTl, float* __restrict__ C,
    int M, int N, int K)
{
    __shared__ ushort_t Ash[128][64], Asl[128][64];   // 32,768 B
    __shared__ ushort_t Bsh[64][64],  Bsl[64][64];    // 16,384 B
    const int bm = blockIdx.y * 128, bn = blockIdx.x * 64;
    const int tid = threadIdx.x;
    const int wave = tid >> 6, lane = tid & 63;
    const int lg = lane >> 4, lm = lane & 15;
    const int wm = wave >> 1, wn = wave & 1;
    const int arow = tid >> 3, aseg = tid & 7;
    const int scol = SWZ(arow, aseg * 8);

    f32x4 acc[4][2];
    #pragma unroll
    for (int mf = 0; mf < 4; ++mf)
        #pragma unroll
        for (int nf = 0; nf < 2; ++nf) acc[mf][nf] = (f32x4){0.f,0.f,0.f,0.f};

    float4 ar[8];
    uint4 brh[2], brl[2];
    const int nkt = K >> 6;

    #define G_ISSUE(K0)                                                          \
        { _Pragma("unroll")                                                      \
          for (int i = 0; i < 4; ++i) {                                          \
            const float* ap = A + (size_t)(bm + arow + 32*i) * K + (K0) + aseg*8;\
            ar[2*i]   = *(const float4*)ap;                                      \
            ar[2*i+1] = *(const float4*)(ap + 4);                                \
          }                                                                      \
          _Pragma("unroll")                                                      \
          for (int i = 0; i < 2; ++i) {                                          \
            size_t bo = (size_t)(bn + arow + 32*i) * K + (K0) + aseg*8;          \
            brh[i] = *(const uint4*)(BTh + bo);                                  \
            brl[i] = *(const uint4*)(BTl + bo);                                  \
          } }

    G_ISSUE(0)
    for (int kt = 0; kt < nkt; ++kt) {
        __syncthreads();
        #pragma unroll
        for (int i = 0; i < 4; ++i) {
            float av[8];
            *(float4*)&av[0] = ar[2*i];
            *(float4*)&av[4] = ar[2*i+1];
            short8 hh, ll;
            #pragma unroll
            for (int e = 0; e < 8; ++e) {
                unsigned short hi = f2bf(av[e]);
                hh[e] = (short)hi;
                ll[e] = (short)f2bf(av[e] - bf2f(hi));
            }
            *(short8*)&Ash[arow + 32*i][scol] = hh;
            *(short8*)&Asl[arow + 32*i][scol] = ll;
        }
        #pragma unroll
        for (int i = 0; i < 2; ++i) {
            *(uint4*)&Bsh[arow + 32*i][scol] = brh[i];
            *(uint4*)&Bsl[arow + 32*i][scol] = brl[i];
        }
        if (kt + 1 < nkt) G_ISSUE((kt + 1) * 64)
        __syncthreads();
        #pragma unroll
        for (int ks = 0; ks < 2; ++ks) {
            const int rcol = SWZ(lm, ks*32 + lg*8);
            short8 afh[4], afl[4], bfh[2], bfl[2];
            #pragma unroll
            for (int mf = 0; mf < 4; ++mf) {
                afh[mf] = *(const short8*)&Ash[wm*64 + mf*16 + lm][rcol];
                afl[mf] = *(const short8*)&Asl[wm*64 + mf*16 + lm][rcol];
            }
            #pragma unroll
            for (int nf = 0; nf < 2; ++nf) {
                bfh[nf] = *(const short8*)&Bsh[wn*32 + nf*16 + lm][rcol];
                bfl[nf] = *(const short8*)&Bsl[wn*32 + nf*16 + lm][rcol];
            }
            #pragma unroll
            for (int mf = 0; mf < 4; ++mf)
                #pragma unroll
                for (int nf = 0; nf < 2; ++nf) {
                    acc[mf][nf] = __builtin_amdgcn_mfma_f32_16x16x32_bf16(afh[mf], bfh[nf], acc[mf][nf], 0, 0, 0);
                    acc[mf][nf] = __builtin_amdgcn_mfma_f32_16x16x32_bf16(afh[mf], bfl[nf], acc[mf][nf], 0, 0, 0);
                    acc[mf][nf] = __builtin_amdgcn_mfma_f32_16x16x32_bf16(afl[mf], bfh[nf], acc[mf][nf], 0, 0, 0);
                }
        }
    }
    #pragma unroll
    for (int mf = 0; mf < 4; ++mf)
        #pragma unroll
        for (int nf = 0; nf < 2; ++nf)
            #pragma unroll
            for (int r = 0; r < 4; ++r)
                C[(size_t)(bm + wm*64 + mf*16 + lg*4 + r) * N + bn + wn*32 + nf*16 + lm]
                    = acc[mf][nf][r];
    #undef G_ISSUE
}

// ---------- out-proj GEMM with FUSED 3-way merge; swizzled LDS (32KB) -----
__global__ __launch_bounds__(256, 2) void gemm_merge_kernel(
    const float* __restrict__ Opart, const float* __restrict__ Ml,
    const ushort_t* __restrict__ BTh, const ushort_t* __restrict__ BTl,
    float* __restrict__ C)
{
    __shared__ ushort_t Ash[64][64], Asl[64][64];
    __shared__ ushort_t Bsh[64][64], Bsl[64][64];
    const int bm = blockIdx.y * 64, bn = blockIdx.x * 64;
    const int tid = threadIdx.x;
    const int wave = tid >> 6, lane = tid & 63;
    const int lg = lane >> 4, lm = lane & 15;
    const int wm = wave >> 1, wn = wave & 1;
    const int srow = tid >> 2, sseg = tid & 3;
    const int sc0 = SWZ(srow, sseg * 16);
    const int sc1 = SWZ(srow, sseg * 16 + 8);

    f32x4 acc[2][2];
    #pragma unroll
    for (int mf = 0; mf < 2; ++mf)
        #pragma unroll
        for (int nf = 0; nf < 2; ++nf) acc[mf][nf] = (f32x4){0.f,0.f,0.f,0.f};

    float4 ar[4];
    uint4 brh[2], brl[2];

    #define GM_ISSUE(KT) {                                                      \
        const int h_ = (KT);                                                    \
        const int mrow = bm + srow;                                             \
        const int b_ = mrow >> 11, n_ = mrow & (NSEQ - 1);                      \
        float mv0, mv1, mv2, lv0, lv1, lv2;                                     \
        { size_t mi = ((size_t)(b_*8 + h_) * NSEQ + n_) * 2;                    \
          mv0 = Ml[mi]; lv0 = Ml[mi+1];                                         \
          mi = ((size_t)(16 + b_*8 + h_) * NSEQ + n_) * 2;                      \
          mv1 = Ml[mi]; lv1 = Ml[mi+1];                                         \
          mi = ((size_t)(32 + b_*8 + h_) * NSEQ + n_) * 2;                      \
          mv2 = Ml[mi]; lv2 = Ml[mi+1]; }                                       \
        float mm = fmaxf(fmaxf(mv0, mv1), mv2);                                 \
        float w0 = __expf(mv0 - mm), w1 = __expf(mv1 - mm), w2 = __expf(mv2 - mm);\
        float inv = 1.f / (lv0*w0 + lv1*w1 + lv2*w2);                           \
        size_t o0 = ((size_t)(b_*8 + h_) * NSEQ + n_) * 64 + sseg*16;           \
        size_t o1 = ((size_t)(16 + b_*8 + h_) * NSEQ + n_) * 64 + sseg*16;      \
        size_t o2 = ((size_t)(32 + b_*8 + h_) * NSEQ + n_) * 64 + sseg*16;      \
        _Pragma("unroll")                                                       \
        for (int c = 0; c < 4; ++c) {                                           \
            float4 v0 = *(const float4*)(Opart + o0 + c*4);                     \
            float4 v1 = *(const float4*)(Opart + o1 + c*4);                     \
            float4 v2 = *(const float4*)(Opart + o2 + c*4);                     \
            ar[c].x = (v0.x*w0 + v1.x*w1 + v2.x*w2) * inv;                      \
            ar[c].y = (v0.y*w0 + v1.y*w1 + v2.y*w2) * inv;                      \
            ar[c].z = (v0.z*w0 + v1.z*w1 + v2.z*w2) * inv;                      \
            ar[c].w = (v0.w*w0 + v1.w*w1 + v2.w*w2) * inv;                      \
        }                                                                       \
        size_t bo = (size_t)(bn + srow) * CIN + (KT)*64 + sseg*16;              \
        brh[0] = *(const uint4*)(BTh + bo);                                     \
        brh[1] = *(const uint4*)(BTh + bo + 8);                                 \
        brl[0] = *(const uint4*)(BTl + bo);                                     \
        brl[1] = *(const uint4*)(BTl + bo + 8); }

    GM_ISSUE(0)
    for (int kt = 0; kt < 8; ++kt) {
        __syncthreads();
        {
            short8 hh0, ll0, hh1, ll1;
            float av[16];
            *(float4*)&av[0]  = ar[0];
            *(float4*)&av[4]  = ar[1];
            *(float4*)&av[8]  = ar[2];
            *(float4*)&av[12] = ar[3];
            #pragma unroll
            for (int e = 0; e < 8; ++e) {
                unsigned short h0 = f2bf(av[e]);
                hh0[e] = (short)h0; ll0[e] = (short)f2bf(av[e] - bf2f(h0));
                unsigned short h1 = f2bf(av[e + 8]);
                hh1[e] = (short)h1; ll1[e] = (short)f2bf(av[e + 8] - bf2f(h1));
            }
            *(short8*)&Ash[srow][sc0] = hh0;
            *(short8*)&Ash[srow][sc1] = hh1;
            *(short8*)&Asl[srow][sc0] = ll0;
            *(short8*)&Asl[srow][sc1] = ll1;
        }
        *(uint4*)&Bsh[srow][sc0] = brh[0];
        *(uint4*)&Bsh[srow][sc1] = brh[1];
        *(uint4*)&Bsl[srow][sc0] = brl[0];
        *(uint4*)&Bsl[srow][sc1] = brl[1];
        if (kt + 1 < 8) GM_ISSUE(kt + 1)
        __syncthreads();
        #pragma unroll
        for (int ks = 0; ks < 2; ++ks) {
            const int rcol = SWZ(lm, ks*32 + lg*8);
            short8 afh[2], afl[2], bfh[2], bfl[2];
            #pragma unroll
            for (int mf = 0; mf < 2; ++mf) {
                afh[mf] = *(const short8*)&Ash[wm*32 + mf*16 + lm][rcol];
                afl[mf] = *(const short8*)&Asl[wm*32 + mf*16 + lm][rcol];
            }
            #pragma unroll
            for (int nf = 0; nf < 2; ++nf) {
                bfh[nf] = *(const short8*)&Bsh[wn*32 + nf*16 + lm][rcol];
                bfl[nf] = *(const short8*)&Bsl[wn*32 + nf*16 + lm][rcol];
            }
            #pragma unroll
            for (int mf = 0; mf < 2; ++mf)
                #pragma unroll
                for (int nf = 0; nf < 2; ++nf) {
                    acc[mf][nf] = __builtin_amdgcn_mfma_f32_16x16x32_bf16(afh[mf], bfh[nf], acc[mf][nf], 0, 0, 0);
                    acc[mf][nf] = __builtin_amdgcn_mfma_f32_16x16x32_bf16(afh[mf], bfl[nf], acc[mf][nf], 0, 0, 0);
                    acc[mf][nf] = __builtin_amdgcn_mfma_f32_16x16x32_bf16(afl[mf], bfh[nf], acc[mf][nf], 0, 0, 0);
                }
        }
    }
    #pragma unroll
    for (int mf = 0; mf < 2; ++mf)
        #pragma unroll
        for (int nf = 0; nf < 2; ++nf)
            #pragma unroll
            for (int r = 0; r < 4; ++r)
                C[(size_t)(bm + wm*32 + mf*16 + lg*4 + r) * CIN + bn + wn*32 + nf*16 + lm]
                    = acc[mf][nf][r];
    #undef GM_ISSUE
}

// ------- fused qkv prep (fp16): l2norm Q,K -> fp16; V transposed+perm fp16 -
__global__ __launch_bounds__(256) void qkv_prep_kernel(
    const float* __restrict__ qkv,
    _Float16* __restrict__ Q16, _Float16* __restrict__ K16,
    _Float16* __restrict__ Vt16)
{
    __shared__ float Vf[64][65];
    const int id = blockIdx.x;
    const int bh = id >> 5, nt = id & 31;
    const int b = bh >> 3, h = bh & 7;
    const int n0 = nt * 64;
    const int tid = threadIdx.x;
    {
        const int row = tid >> 2, dseg = tid & 3;
        const float* src = qkv + ((size_t)(b * NSEQ + n0 + row)) * QKV3
                         + h * 192 + dseg * 48;
        float f[48];
        #pragma unroll
        for (int i = 0; i < 12; ++i)
            *(float4*)&f[i*4] = *(const float4*)(src + i*4);
        float nq = 0.f, nk = 0.f;
        #pragma unroll
        for (int e = 0; e < 16; ++e) {
            nq = fmaf(f[3*e], f[3*e], nq);
            nk = fmaf(f[3*e+1], f[3*e+1], nk);
        }
        nq += __shfl_xor(nq, 1); nq += __shfl_xor(nq, 2);
        nk += __shfl_xor(nk, 1); nk += __shfl_xor(nk, 2);
        float rq = 1.f / fmaxf(sqrtf(nq), 1e-12f);
        float rk = 1.f / fmaxf(sqrtf(nk), 1e-12f);
        _Float16 q16[16], k16[16];
        #pragma unroll
        for (int e = 0; e < 16; ++e) {
            q16[e] = (_Float16)(f[3*e] * rq);
            k16[e] = (_Float16)(f[3*e+1] * rk);
            Vf[dseg*16 + e][row] = f[3*e+2];
        }
        size_t o = ((size_t)bh * NSEQ + n0 + row) * DIM + dseg * 16;
        *(uint4*)(Q16 + o)     = *(uint4*)&q16[0];
        *(uint4*)(Q16 + o + 8) = *(uint4*)&q16[8];
        *(uint4*)(K16 + o)     = *(uint4*)&k16[0];
        *(uint4*)(K16 + o + 8) = *(uint4*)&k16[8];
    }
    __syncthreads();
    {   // Vt[bh][d][n] with the PV fragment j-permutation (within 32-blocks)
        const int d = tid >> 2, seg = tid & 3;
        _Float16 tv[16];
        #pragma unroll
        for (int t = 0; t < 16; ++t) {
            int p = seg * 16 + t;
            int s = (p & 35) | ((p & 4) << 2) | ((p >> 1) & 12);
            tv[t] = (_Float16)Vf[d][s];
        }
        size_t o = ((size_t)bh * DIM + d) * NSEQ + n0 + seg * 16;
        *(uint4*)(Vt16 + o)     = *(uint4*)&tv[0];
        *(uint4*)(Vt16 + o + 8) = *(uint4*)&tv[8];
    }
}

// ---------------- MFMA flash attention v9: single-term fp16 ---------------
// QK^T = K16.Q16 (1 MFMA/frag); PV = P16.V16 with l = sum(fp16-rounded P)
__global__ __launch_bounds__(256, 3) void attn_mfma_kernel(
    const _Float16* __restrict__ Q16, const _Float16* __restrict__ K16,
    const _Float16* __restrict__ Vt16,
    const float* __restrict__ bias, const float* __restrict__ temp_p,
    const uint8_t* __restrict__ mask,
    float* __restrict__ Opart, float* __restrict__ Ml,
    int ns, int base, int rem)
{
    __shared__ _Float16 Ks[2][32][72];   // [buf][j][d]   9,216 B
    __shared__ _Float16 Vs[2][64][36];   // [buf][d][j']  9,216 B

    const int id = blockIdx.x;
    const int h = id & 7;                  // XCD-grouped
    const int rest = id >> 3;
    const int per_b = 16 * ns;
    const int b = rest / per_b;
    const int r2 = rest - b * per_b;
    const int js = r2 >> 4;
    const int qt = r2 & 15;
    const int bh = b * 8 + h;
    const int i0 = qt * 128;
    const int tid = threadIdx.x;
    const int wave = tid >> 6, lane = tid & 63;
    const int lg = lane >> 4, lm = lane & 15;
    const int qbase = i0 + wave * 32;
    const float temp = *temp_p;
    const int krow = tid >> 3, kseg = tid & 7;
    const int vrow = tid >> 2, vseg = tid & 3;

    half8 qf[2][2];
    #pragma unroll
    for (int m = 0; m < 2; ++m) {
        size_t qo = ((size_t)(bh * NSEQ + qbase + 16*m + lm)) * DIM + lg * 8;
        qf[m][0] = *(const half8*)(Q16 + qo);
        qf[m][1] = *(const half8*)(Q16 + qo + 32);
    }
    bool rowm[2];
    rowm[0] = mask[(size_t)b * NSEQ + qbase + lm] != 0;
    rowm[1] = mask[(size_t)b * NSEQ + qbase + 16 + lm] != 0;
    const bool nomaskrow = __all(!rowm[0] && !rowm[1]);

    // hoisted bias row pointers (per m)
    const float* bp0 = bias + ((size_t)h * NSEQ + qbase + lm) * NSEQ;
    const float* bp1 = bp0 + (size_t)16 * NSEQ;
    const int lgo = lg * 4;

    float m_r[2] = {-FLT_MAX, -FLT_MAX};
    float l_r[2] = {0.f, 0.f};
    f32x4 oa[2][4];
    #pragma unroll
    for (int m = 0; m < 2; ++m)
        #pragma unroll
        for (int dt = 0; dt < 4; ++dt) oa[m][dt] = (f32x4){0.f,0.f,0.f,0.f};

    const int NT = base + (js < rem ? 1 : 0);
    const int tstart = js * base + (js < rem ? js : rem);
    const int jbase = tstart * 32;
    uint4 skh, svh;

    #define A_ISSUE(J0) {                                                      \
        size_t gk = ((size_t)(bh * NSEQ) + (J0) + krow) * DIM + kseg*8;        \
        size_t gv = ((size_t)(bh * DIM) + vrow) * NSEQ + (J0) + vseg*8;        \
        skh = *(const uint4*)(K16  + gk);                                      \
        svh = *(const uint4*)(Vt16 + gv); }
    #define STAGE(BUF) {                                                       \
        *(uint4*)&Ks[BUF][krow][kseg*8] = skh;                                 \
        *(uint4*)&Vs[BUF][vrow][vseg*8] = svh; }

    A_ISSUE(jbase)
    STAGE(0)
    A_ISSUE(jbase + 32)
    float4 bb[2][2];
    #pragma unroll
    for (int jt = 0; jt < 2; ++jt) {
        bb[0][jt] = *(const float4*)(bp0 + jbase + jt*16 + lgo);
        bb[1][jt] = *(const float4*)(bp1 + jbase + jt*16 + lgo);
    }
    uint8_t mk = mask[(size_t)b * NSEQ + jbase + (lane & 31)];
    __syncthreads();

    #pragma unroll 2
    for (int t = 0; t < NT; ++t) {
        const int cur = t & 1;
        const int j0 = jbase + t * 32;

        float4 bbn[2][2];
        uint8_t mkn = 0;
        if (t + 1 < NT) {
            #pragma unroll
            for (int jt = 0; jt < 2; ++jt) {
                bbn[0][jt] = *(const float4*)(bp0 + j0 + 32 + jt*16 + lgo);
                bbn[1][jt] = *(const float4*)(bp1 + j0 + 32 + jt*16 + lgo);
            }
            mkn = mask[(size_t)b * NSEQ + j0 + 32 + (lane & 31)];
            STAGE(cur ^ 1)
            if (t + 2 < NT) A_ISSUE(j0 + 64)
        }
        unsigned long long bal = __ballot(mk != 0);

        // ---- S^T = K.Q (swapped), single fp16 MFMA per fragment ----
        f32x4 sac[2][2];
        #pragma unroll
        for (int m = 0; m < 2; ++m)
            #pragma unroll
            for (int jt = 0; jt < 2; ++jt) sac[m][jt] = (f32x4){0.f,0.f,0.f,0.f};
        __builtin_amdgcn_s_setprio(1);
        #pragma unroll
        for (int jt = 0; jt < 2; ++jt)
            #pragma unroll
            for (int ks = 0; ks < 2; ++ks) {
                half8 kb = *(const half8*)(&Ks[cur][jt*16 + lm][ks*32 + lg*8]);
                #pragma unroll
                for (int m = 0; m < 2; ++m)
                    sac[m][jt] = __builtin_amdgcn_mfma_f32_16x16x32_f16(kb, qf[m][ks], sac[m][jt], 0, 0, 0);
            }
        __builtin_amdgcn_s_setprio(0);

        // ---- in-register online softmax with defer-max ----
        half8 pah[2];
        #pragma unroll
        for (int m = 0; m < 2; ++m) {
            const float4* bbm = bb[m];
            float sv[2][4];
            if (nomaskrow && bal == 0) {        // wave-uniform fast path
                #pragma unroll
                for (int jt = 0; jt < 2; ++jt) {
                    sv[jt][0] = fmaf(sac[m][jt][0], temp, bbm[jt].x);
                    sv[jt][1] = fmaf(sac[m][jt][1], temp, bbm[jt].y);
                    sv[jt][2] = fmaf(sac[m][jt][2], temp, bbm[jt].z);
                    sv[jt][3] = fmaf(sac[m][jt][3], temp, bbm[jt].w);
                }
            } else {                             // masked path (proven logic)
                #pragma unroll
                for (int jt = 0; jt < 2; ++jt) {
                    unsigned int nib = (unsigned int)(bal >> (jt*16 + lg*4)) & 0xFu;
                    #pragma unroll
                    for (int r = 0; r < 4; ++r) {
                        bool dead = rowm[m] || ((nib >> r) & 1u);
                        float bv = (r == 0) ? bbm[jt].x : (r == 1) ? bbm[jt].y
                                 : (r == 2) ? bbm[jt].z : bbm[jt].w;
                        sv[jt][r] = dead ? -FLT_MAX : fmaf(sac[m][jt][r], temp, bv);
                    }
                }
            }
            float pmax = fmaxf(fmaxf(fmaxf(sv[0][0], sv[0][1]), fmaxf(sv[0][2], sv[0][3])),
                               fmaxf(fmaxf(sv[1][0], sv[1][1]), fmaxf(sv[1][2], sv[1][3])));
            pmax = fmaxf(pmax, __shfl_xor(pmax, 16));
            pmax = fmaxf(pmax, __shfl_xor(pmax, 32));
            if (!__all(pmax <= m_r[m] + 8.f)) {
                float mn = fmaxf(m_r[m], pmax);
                float sc = __expf(m_r[m] - mn);
                m_r[m] = mn;
                l_r[m] *= sc;
                #pragma unroll
                for (int r = 0; r < 4; ++r) {
                    float sq = __shfl(sc, lg*4 + r);
                    #pragma unroll
                    for (int dt = 0; dt < 4; ++dt) oa[m][dt][r] *= sq;
                }
            }
            float rs = 0.f;
            #pragma unroll
            for (int jt = 0; jt < 2; ++jt)
                #pragma unroll
                for (int r = 0; r < 4; ++r) {
                    float pf = __expf(sv[jt][r] - m_r[m]);
                    _Float16 p16 = (_Float16)pf;
                    rs += (float)p16;            // l consistent with fp16 P
                    pah[m][jt*4 + r] = p16;
                }
            rs += __shfl_xor(rs, 16);
            rs += __shfl_xor(rs, 32);
            l_r[m] += rs;
        }

        // ---- O += P16.V16 (single fp16 MFMA per fragment) ----
        __builtin_amdgcn_s_setprio(1);
        #pragma unroll
        for (int dt = 0; dt < 4; ++dt) {
            half8 vb = *(const half8*)(&Vs[cur][dt*16 + lm][lg*8]);
            #pragma unroll
            for (int m = 0; m < 2; ++m)
                oa[m][dt] = __builtin_amdgcn_mfma_f32_16x16x32_f16(pah[m], vb, oa[m][dt], 0, 0, 0);
        }
        __builtin_amdgcn_s_setprio(0);
        __syncthreads();
        #pragma unroll
        for (int m = 0; m < 2; ++m)
            #pragma unroll
            for (int jt = 0; jt < 2; ++jt) bb[m][jt] = bbn[m][jt];
        mk = mkn;
    }
    #undef A_ISSUE
    #undef STAGE

    #pragma unroll
    for (int m = 0; m < 2; ++m)
        #pragma unroll
        for (int dt = 0; dt < 4; ++dt)
            #pragma unroll
            for (int r = 0; r < 4; ++r)
                Opart[((size_t)(js*16 + bh) * NSEQ + qbase + 16*m + lg*4 + r) * 64
                      + dt*16 + lm] = oa[m][dt][r];
    if (lane < 16) {
        #pragma unroll
        for (int m = 0; m < 2; ++m) {
            size_t mi = ((size_t)(js*16 + bh) * NSEQ + qbase + 16*m + lm) * 2;
            Ml[mi]     = m_r[m];
            Ml[mi + 1] = l_r[m];
        }
    }
}

extern "C" void kernel_launch(void* const* d_in, const int* in_sizes, int n_in,
                              void* d_out, int out_size, void* d_ws, size_t ws_size,
                              hipStream_t stream)
{
    const float*   x        = (const float*)d_in[0];
    const float*   w_qkv    = (const float*)d_in[1];
    const float*   w_out    = (const float*)d_in[2];
    const float*   pos_bias = (const float*)d_in[3];
    const float*   temp     = (const float*)d_in[4];
    const uint8_t* mask     = (const uint8_t*)d_in[5];
    float* out = (float*)d_out;

    const int M = BATCH * NSEQ;                        // 4096
    const size_t NE = (size_t)BATCH * HEADS * NSEQ * DIM;
    const int ns = 3;                                  // grid 768 = 3 blocks/CU exactly
    const int base = 64 / ns, rem = 64 % ns;

    char* ws = (char*)d_ws;
    // region 0 (25.2 MB): qkv_lin f32; exactly reused by the 3-split f32 Opart
    float* qkv_lin = (float*)ws;
    float* OpartP  = (float*)ws;    // 3*16*2048*64*4 B == M*QKV3*4 B exactly
    size_t off = (size_t)M * QKV3 * 4;
    // region 1: transposed/split weights + Ml
    ushort_t* WqkvTh = (ushort_t*)(ws + off); off += (size_t)QKV3 * CIN * 2;
    ushort_t* WqkvTl = (ushort_t*)(ws + off); off += (size_t)QKV3 * CIN * 2;
    ushort_t* WoutTh = (ushort_t*)(ws + off); off += (size_t)HD * CIN * 2;
    ushort_t* WoutTl = (ushort_t*)(ws + off); off += (size_t)HD * CIN * 2;
    float*    MlP    = (float*)(ws + off);    off += (size_t)ns * 16 * NSEQ * 2 * 4;
    // region 2 (12.6 MB): Q16/K16/Vt16 fp16
    char* reg2 = ws + off;
    _Float16* Q16  = (_Float16*)reg2;
    _Float16* K16  = Q16 + NE;
    _Float16* Vt16 = K16 + NE;

    // 1. both weight splits in one launch
    split_wT_kernel<<<dim3(32, CIN/64), 256, 0, stream>>>(
        w_qkv, w_out, WqkvTh, WqkvTl, WoutTh, WoutTl);
    // 2. qkv projection (swizzled-LDS bf16-split GEMM)
    gemm_split_kernel<<<dim3(QKV3/64, M/128), 256, 0, stream>>>(
        x, WqkvTh, WqkvTl, qkv_lin, M, QKV3, CIN);
    // 3. fused l2norm + V transpose -> fp16
    qkv_prep_kernel<<<dim3(BATCH * HEADS * (NSEQ/64)), 256, 0, stream>>>(
        qkv_lin, Q16, K16, Vt16);
    // 4. attention (fp16 single-term; Opart overwrites qkv_lin)
    attn_mfma_kernel<<<dim3(256 * ns), 256, 0, stream>>>(
        Q16, K16, Vt16, pos_bias, temp, mask, OpartP, MlP, ns, base, rem);
    // 5. out projection with fused 3-way merge
    gemm_merge_kernel<<<dim3(CIN/64, M/64), 256, 0, stream>>>(
        OpartP, MlP, WoutTh, WoutTl, out);
}

// Round 15
// 125.442 us; speedup vs baseline: 1.8743x; 1.2118x over previous
//
#include <hip/hip_runtime.h>
#include <cfloat>
#include <cstdint>

#define BATCH 2
#define NSEQ 2048
#define CIN 512
#define HEADS 8
#define DIM 64
#define HD 512
#define QKV3 1536

typedef short short8 __attribute__((ext_vector_type(8)));
typedef _Float16 half8 __attribute__((ext_vector_type(8)));
typedef float f32x4 __attribute__((ext_vector_type(4)));
typedef unsigned short ushort_t;

// T2 XOR swizzle (halfword-index units): toggles the 8-half (16B) slot
// within a 64-half (128B) row; bank set then depends only on slot.
#define SWZ(row, col) ((col) ^ (((row) & 7) << 3))

// ---------- convert + transpose BOTH weights to fp16 in one launch --------
__global__ __launch_bounds__(256) void cvt_wT_kernel(
    const float* __restrict__ Wq, const float* __restrict__ Wo,
    _Float16* __restrict__ WqT, _Float16* __restrict__ WoT)
{
    __shared__ float T[64][65];
    const int bx = blockIdx.x;
    const float* W; _Float16* WT; int N, n0;
    if (bx < 24) { W = Wq; WT = WqT; N = QKV3; n0 = bx * 64; }
    else         { W = Wo; WT = WoT; N = HD;   n0 = (bx - 24) * 64; }
    const int K = CIN;
    const int k0 = blockIdx.y * 64;
    const int tid = threadIdx.x;
    #pragma unroll
    for (int i = 0; i < 4; ++i) {
        int c = tid + i * 256;
        int row = c >> 4, c4 = c & 15;
        *(float4*)&T[row][c4*4] = *(const float4*)(W + (size_t)(k0 + row) * N + n0 + c4*4);
    }
    __syncthreads();
    const int n = tid >> 2, kseg = tid & 3;
    _Float16 hv[16];
    #pragma unroll
    for (int e = 0; e < 16; ++e)
        hv[e] = (_Float16)T[kseg*16 + e][n];
    size_t o = (size_t)(n0 + n) * K + k0 + kseg * 16;
    *(uint4*)(WT + o)     = *(uint4*)&hv[0];
    *(uint4*)(WT + o + 8) = *(uint4*)&hv[8];
}

// ---------- fp16 MFMA GEMM: C[M][N] = A[M][K](f32) @ BT[N][K](fp16) -------
// BM=128 BN=64 BK=64; stage-time A->fp16; XOR-swizzled LDS (24.5KB)
__global__ __launch_bounds__(256, 2) void gemm_f16_kernel(
    const float* __restrict__ A, const _Float16* __restrict__ BT,
    float* __restrict__ C, int M, int N, int K)
{
    __shared__ _Float16 As[128][64];   // 16,384 B
    __shared__ _Float16 Bs[64][64];    //  8,192 B
    const int bm = blockIdx.y * 128, bn = blockIdx.x * 64;
    const int tid = threadIdx.x;
    const int wave = tid >> 6, lane = tid & 63;
    const int lg = lane >> 4, lm = lane & 15;
    const int wm = wave >> 1, wn = wave & 1;
    const int arow = tid >> 3, aseg = tid & 7;
    const int scol = SWZ(arow, aseg * 8);

    f32x4 acc[4][2];
    #pragma unroll
    for (int mf = 0; mf < 4; ++mf)
        #pragma unroll
        for (int nf = 0; nf < 2; ++nf) acc[mf][nf] = (f32x4){0.f,0.f,0.f,0.f};

    float4 ar[8];
    uint4 br[2];
    const int nkt = K >> 6;

    #define G_ISSUE(K0)                                                          \
        { _Pragma("unroll")                                                      \
          for (int i = 0; i < 4; ++i) {                                          \
            const float* ap = A + (size_t)(bm + arow + 32*i) * K + (K0) + aseg*8;\
            ar[2*i]   = *(const float4*)ap;                                      \
            ar[2*i+1] = *(const float4*)(ap + 4);                                \
          }                                                                      \
          _Pragma("unroll")                                                      \
          for (int i = 0; i < 2; ++i) {                                          \
            size_t bo = (size_t)(bn + arow + 32*i) * K + (K0) + aseg*8;          \
            br[i] = *(const uint4*)(BT + bo);                                    \
          } }

    G_ISSUE(0)
    for (int kt = 0; kt < nkt; ++kt) {
        __syncthreads();
        #pragma unroll
        for (int i = 0; i < 4; ++i) {
            float av[8];
            *(float4*)&av[0] = ar[2*i];
            *(float4*)&av[4] = ar[2*i+1];
            half8 hh;
            #pragma unroll
            for (int e = 0; e < 8; ++e) hh[e] = (_Float16)av[e];
            *(half8*)&As[arow + 32*i][scol] = hh;
        }
        #pragma unroll
        for (int i = 0; i < 2; ++i)
            *(uint4*)&Bs[arow + 32*i][scol] = br[i];
        if (kt + 1 < nkt) G_ISSUE((kt + 1) * 64)
        __syncthreads();
        #pragma unroll
        for (int ks = 0; ks < 2; ++ks) {
            const int rcol = SWZ(lm, ks*32 + lg*8);
            half8 af[4], bf[2];
            #pragma unroll
            for (int mf = 0; mf < 4; ++mf)
                af[mf] = *(const half8*)&As[wm*64 + mf*16 + lm][rcol];
            #pragma unroll
            for (int nf = 0; nf < 2; ++nf)
                bf[nf] = *(const half8*)&Bs[wn*32 + nf*16 + lm][rcol];
            #pragma unroll
            for (int mf = 0; mf < 4; ++mf)
                #pragma unroll
                for (int nf = 0; nf < 2; ++nf)
                    acc[mf][nf] = __builtin_amdgcn_mfma_f32_16x16x32_f16(af[mf], bf[nf], acc[mf][nf], 0, 0, 0);
        }
    }
    #pragma unroll
    for (int mf = 0; mf < 4; ++mf)
        #pragma unroll
        for (int nf = 0; nf < 2; ++nf)
            #pragma unroll
            for (int r = 0; r < 4; ++r)
                C[(size_t)(bm + wm*64 + mf*16 + lg*4 + r) * N + bn + wn*32 + nf*16 + lm]
                    = acc[mf][nf][r];
    #undef G_ISSUE
}

// ---------- out-proj fp16 GEMM with FUSED 3-way merge (16KB LDS) ----------
// out[M][512] = merge(Opart,Ml) @ WoT;  BM=64 BN=64 BK=64 (h = kt)
__global__ __launch_bounds__(256, 2) void gemm_merge_kernel(
    const float* __restrict__ Opart, const float* __restrict__ Ml,
    const _Float16* __restrict__ BT, float* __restrict__ C)
{
    __shared__ _Float16 As[64][64];   // 8,192 B
    __shared__ _Float16 Bs[64][64];   // 8,192 B
    const int bm = blockIdx.y * 64, bn = blockIdx.x * 64;
    const int tid = threadIdx.x;
    const int wave = tid >> 6, lane = tid & 63;
    const int lg = lane >> 4, lm = lane & 15;
    const int wm = wave >> 1, wn = wave & 1;
    const int srow = tid >> 2, sseg = tid & 3;    // stage: 64 rows x 4 segs of 16
    const int sc0 = SWZ(srow, sseg * 16);
    const int sc1 = SWZ(srow, sseg * 16 + 8);

    f32x4 acc[2][2];
    #pragma unroll
    for (int mf = 0; mf < 2; ++mf)
        #pragma unroll
        for (int nf = 0; nf < 2; ++nf) acc[mf][nf] = (f32x4){0.f,0.f,0.f,0.f};

    float4 ar[4];
    uint4 br[2];

    #define GM_ISSUE(KT) {                                                      \
        const int h_ = (KT);                                                    \
        const int mrow = bm + srow;                                             \
        const int b_ = mrow >> 11, n_ = mrow & (NSEQ - 1);                      \
        float mv0, mv1, mv2, lv0, lv1, lv2;                                     \
        { size_t mi = ((size_t)(b_*8 + h_) * NSEQ + n_) * 2;                    \
          mv0 = Ml[mi]; lv0 = Ml[mi+1];                                         \
          mi = ((size_t)(16 + b_*8 + h_) * NSEQ + n_) * 2;                      \
          mv1 = Ml[mi]; lv1 = Ml[mi+1];                                         \
          mi = ((size_t)(32 + b_*8 + h_) * NSEQ + n_) * 2;                      \
          mv2 = Ml[mi]; lv2 = Ml[mi+1]; }                                       \
        float mm = fmaxf(fmaxf(mv0, mv1), mv2);                                 \
        float w0 = __expf(mv0 - mm), w1 = __expf(mv1 - mm), w2 = __expf(mv2 - mm);\
        float inv = 1.f / (lv0*w0 + lv1*w1 + lv2*w2);                           \
        size_t o0 = ((size_t)(b_*8 + h_) * NSEQ + n_) * 64 + sseg*16;           \
        size_t o1 = ((size_t)(16 + b_*8 + h_) * NSEQ + n_) * 64 + sseg*16;      \
        size_t o2 = ((size_t)(32 + b_*8 + h_) * NSEQ + n_) * 64 + sseg*16;      \
        _Pragma("unroll")                                                       \
        for (int c = 0; c < 4; ++c) {                                           \
            float4 v0 = *(const float4*)(Opart + o0 + c*4);                     \
            float4 v1 = *(const float4*)(Opart + o1 + c*4);                     \
            float4 v2 = *(const float4*)(Opart + o2 + c*4);                     \
            ar[c].x = (v0.x*w0 + v1.x*w1 + v2.x*w2) * inv;                      \
            ar[c].y = (v0.y*w0 + v1.y*w1 + v2.y*w2) * inv;                      \
            ar[c].z = (v0.z*w0 + v1.z*w1 + v2.z*w2) * inv;                      \
            ar[c].w = (v0.w*w0 + v1.w*w1 + v2.w*w2) * inv;                      \
        }                                                                       \
        size_t bo = (size_t)(bn + srow) * CIN + (KT)*64 + sseg*16;              \
        br[0] = *(const uint4*)(BT + bo);                                       \
        br[1] = *(const uint4*)(BT + bo + 8); }

    GM_ISSUE(0)
    for (int kt = 0; kt < 8; ++kt) {
        __syncthreads();
        {   // stage-time f32 -> fp16 (proven stage-convert pattern)
            float av[16];
            *(float4*)&av[0]  = ar[0];
            *(float4*)&av[4]  = ar[1];
            *(float4*)&av[8]  = ar[2];
            *(float4*)&av[12] = ar[3];
            half8 h0, h1;
            #pragma unroll
            for (int e = 0; e < 8; ++e) {
                h0[e] = (_Float16)av[e];
                h1[e] = (_Float16)av[e + 8];
            }
            *(half8*)&As[srow][sc0] = h0;
            *(half8*)&As[srow][sc1] = h1;
        }
        *(uint4*)&Bs[srow][sc0] = br[0];
        *(uint4*)&Bs[srow][sc1] = br[1];
        if (kt + 1 < 8) GM_ISSUE(kt + 1)
        __syncthreads();
        #pragma unroll
        for (int ks = 0; ks < 2; ++ks) {
            const int rcol = SWZ(lm, ks*32 + lg*8);
            half8 af[2], bf[2];
            #pragma unroll
            for (int mf = 0; mf < 2; ++mf)
                af[mf] = *(const half8*)&As[wm*32 + mf*16 + lm][rcol];
            #pragma unroll
            for (int nf = 0; nf < 2; ++nf)
                bf[nf] = *(const half8*)&Bs[wn*32 + nf*16 + lm][rcol];
            #pragma unroll
            for (int mf = 0; mf < 2; ++mf)
                #pragma unroll
                for (int nf = 0; nf < 2; ++nf)
                    acc[mf][nf] = __builtin_amdgcn_mfma_f32_16x16x32_f16(af[mf], bf[nf], acc[mf][nf], 0, 0, 0);
        }
    }
    #pragma unroll
    for (int mf = 0; mf < 2; ++mf)
        #pragma unroll
        for (int nf = 0; nf < 2; ++nf)
            #pragma unroll
            for (int r = 0; r < 4; ++r)
                C[(size_t)(bm + wm*32 + mf*16 + lg*4 + r) * CIN + bn + wn*32 + nf*16 + lm]
                    = acc[mf][nf][r];
    #undef GM_ISSUE
}

// ------- fused qkv prep (fp16): l2norm Q,K -> fp16; V transposed+perm fp16 -
__global__ __launch_bounds__(256) void qkv_prep_kernel(
    const float* __restrict__ qkv,
    _Float16* __restrict__ Q16, _Float16* __restrict__ K16,
    _Float16* __restrict__ Vt16)
{
    __shared__ float Vf[64][65];
    const int id = blockIdx.x;
    const int bh = id >> 5, nt = id & 31;
    const int b = bh >> 3, h = bh & 7;
    const int n0 = nt * 64;
    const int tid = threadIdx.x;
    {
        const int row = tid >> 2, dseg = tid & 3;
        const float* src = qkv + ((size_t)(b * NSEQ + n0 + row)) * QKV3
                         + h * 192 + dseg * 48;
        float f[48];
        #pragma unroll
        for (int i = 0; i < 12; ++i)
            *(float4*)&f[i*4] = *(const float4*)(src + i*4);
        float nq = 0.f, nk = 0.f;
        #pragma unroll
        for (int e = 0; e < 16; ++e) {
            nq = fmaf(f[3*e], f[3*e], nq);
            nk = fmaf(f[3*e+1], f[3*e+1], nk);
        }
        nq += __shfl_xor(nq, 1); nq += __shfl_xor(nq, 2);
        nk += __shfl_xor(nk, 1); nk += __shfl_xor(nk, 2);
        float rq = 1.f / fmaxf(sqrtf(nq), 1e-12f);
        float rk = 1.f / fmaxf(sqrtf(nk), 1e-12f);
        _Float16 q16[16], k16[16];
        #pragma unroll
        for (int e = 0; e < 16; ++e) {
            q16[e] = (_Float16)(f[3*e] * rq);
            k16[e] = (_Float16)(f[3*e+1] * rk);
            Vf[dseg*16 + e][row] = f[3*e+2];
        }
        size_t o = ((size_t)bh * NSEQ + n0 + row) * DIM + dseg * 16;
        *(uint4*)(Q16 + o)     = *(uint4*)&q16[0];
        *(uint4*)(Q16 + o + 8) = *(uint4*)&q16[8];
        *(uint4*)(K16 + o)     = *(uint4*)&k16[0];
        *(uint4*)(K16 + o + 8) = *(uint4*)&k16[8];
    }
    __syncthreads();
    {   // Vt[bh][d][n] with the PV fragment j-permutation (within 32-blocks)
        const int d = tid >> 2, seg = tid & 3;
        _Float16 tv[16];
        #pragma unroll
        for (int t = 0; t < 16; ++t) {
            int p = seg * 16 + t;
            int s = (p & 35) | ((p & 4) << 2) | ((p >> 1) & 12);
            tv[t] = (_Float16)Vf[d][s];
        }
        size_t o = ((size_t)bh * DIM + d) * NSEQ + n0 + seg * 16;
        *(uint4*)(Vt16 + o)     = *(uint4*)&tv[0];
        *(uint4*)(Vt16 + o + 8) = *(uint4*)&tv[8];
    }
}

// ---------------- MFMA flash attention v9: single-term fp16 (R14-proven) --
__global__ __launch_bounds__(256, 3) void attn_mfma_kernel(
    const _Float16* __restrict__ Q16, const _Float16* __restrict__ K16,
    const _Float16* __restrict__ Vt16,
    const float* __restrict__ bias, const float* __restrict__ temp_p,
    const uint8_t* __restrict__ mask,
    float* __restrict__ Opart, float* __restrict__ Ml,
    int ns, int base, int rem)
{
    __shared__ _Float16 Ks[2][32][72];   // [buf][j][d]   9,216 B
    __shared__ _Float16 Vs[2][64][36];   // [buf][d][j']  9,216 B

    const int id = blockIdx.x;
    const int h = id & 7;                  // XCD-grouped
    const int rest = id >> 3;
    const int per_b = 16 * ns;
    const int b = rest / per_b;
    const int r2 = rest - b * per_b;
    const int js = r2 >> 4;
    const int qt = r2 & 15;
    const int bh = b * 8 + h;
    const int i0 = qt * 128;
    const int tid = threadIdx.x;
    const int wave = tid >> 6, lane = tid & 63;
    const int lg = lane >> 4, lm = lane & 15;
    const int qbase = i0 + wave * 32;
    const float temp = *temp_p;
    const int krow = tid >> 3, kseg = tid & 7;
    const int vrow = tid >> 2, vseg = tid & 3;

    half8 qf[2][2];
    #pragma unroll
    for (int m = 0; m < 2; ++m) {
        size_t qo = ((size_t)(bh * NSEQ + qbase + 16*m + lm)) * DIM + lg * 8;
        qf[m][0] = *(const half8*)(Q16 + qo);
        qf[m][1] = *(const half8*)(Q16 + qo + 32);
    }
    bool rowm[2];
    rowm[0] = mask[(size_t)b * NSEQ + qbase + lm] != 0;
    rowm[1] = mask[(size_t)b * NSEQ + qbase + 16 + lm] != 0;
    const bool nomaskrow = __all(!rowm[0] && !rowm[1]);

    const float* bp0 = bias + ((size_t)h * NSEQ + qbase + lm) * NSEQ;
    const float* bp1 = bp0 + (size_t)16 * NSEQ;
    const int lgo = lg * 4;

    float m_r[2] = {-FLT_MAX, -FLT_MAX};
    float l_r[2] = {0.f, 0.f};
    f32x4 oa[2][4];
    #pragma unroll
    for (int m = 0; m < 2; ++m)
        #pragma unroll
        for (int dt = 0; dt < 4; ++dt) oa[m][dt] = (f32x4){0.f,0.f,0.f,0.f};

    const int NT = base + (js < rem ? 1 : 0);
    const int tstart = js * base + (js < rem ? js : rem);
    const int jbase = tstart * 32;
    uint4 skh, svh;

    #define A_ISSUE(J0) {                                                      \
        size_t gk = ((size_t)(bh * NSEQ) + (J0) + krow) * DIM + kseg*8;        \
        size_t gv = ((size_t)(bh * DIM) + vrow) * NSEQ + (J0) + vseg*8;        \
        skh = *(const uint4*)(K16  + gk);                                      \
        svh = *(const uint4*)(Vt16 + gv); }
    #define STAGE(BUF) {                                                       \
        *(uint4*)&Ks[BUF][krow][kseg*8] = skh;                                 \
        *(uint4*)&Vs[BUF][vrow][vseg*8] = svh; }

    A_ISSUE(jbase)
    STAGE(0)
    A_ISSUE(jbase + 32)
    float4 bb[2][2];
    #pragma unroll
    for (int jt = 0; jt < 2; ++jt) {
        bb[0][jt] = *(const float4*)(bp0 + jbase + jt*16 + lgo);
        bb[1][jt] = *(const float4*)(bp1 + jbase + jt*16 + lgo);
    }
    uint8_t mk = mask[(size_t)b * NSEQ + jbase + (lane & 31)];
    __syncthreads();

    #pragma unroll 2
    for (int t = 0; t < NT; ++t) {
        const int cur = t & 1;
        const int j0 = jbase + t * 32;

        float4 bbn[2][2];
        uint8_t mkn = 0;
        if (t + 1 < NT) {
            #pragma unroll
            for (int jt = 0; jt < 2; ++jt) {
                bbn[0][jt] = *(const float4*)(bp0 + j0 + 32 + jt*16 + lgo);
                bbn[1][jt] = *(const float4*)(bp1 + j0 + 32 + jt*16 + lgo);
            }
            mkn = mask[(size_t)b * NSEQ + j0 + 32 + (lane & 31)];
            STAGE(cur ^ 1)
            if (t + 2 < NT) A_ISSUE(j0 + 64)
        }
        unsigned long long bal = __ballot(mk != 0);

        f32x4 sac[2][2];
        #pragma unroll
        for (int m = 0; m < 2; ++m)
            #pragma unroll
            for (int jt = 0; jt < 2; ++jt) sac[m][jt] = (f32x4){0.f,0.f,0.f,0.f};
        __builtin_amdgcn_s_setprio(1);
        #pragma unroll
        for (int jt = 0; jt < 2; ++jt)
            #pragma unroll
            for (int ks = 0; ks < 2; ++ks) {
                half8 kb = *(const half8*)(&Ks[cur][jt*16 + lm][ks*32 + lg*8]);
                #pragma unroll
                for (int m = 0; m < 2; ++m)
                    sac[m][jt] = __builtin_amdgcn_mfma_f32_16x16x32_f16(kb, qf[m][ks], sac[m][jt], 0, 0, 0);
            }
        __builtin_amdgcn_s_setprio(0);

        half8 pah[2];
        #pragma unroll
        for (int m = 0; m < 2; ++m) {
            const float4* bbm = bb[m];
            float sv[2][4];
            if (nomaskrow && bal == 0) {
                #pragma unroll
                for (int jt = 0; jt < 2; ++jt) {
                    sv[jt][0] = fmaf(sac[m][jt][0], temp, bbm[jt].x);
                    sv[jt][1] = fmaf(sac[m][jt][1], temp, bbm[jt].y);
                    sv[jt][2] = fmaf(sac[m][jt][2], temp, bbm[jt].z);
                    sv[jt][3] = fmaf(sac[m][jt][3], temp, bbm[jt].w);
                }
            } else {
                #pragma unroll
                for (int jt = 0; jt < 2; ++jt) {
                    unsigned int nib = (unsigned int)(bal >> (jt*16 + lg*4)) & 0xFu;
                    #pragma unroll
                    for (int r = 0; r < 4; ++r) {
                        bool dead = rowm[m] || ((nib >> r) & 1u);
                        float bv = (r == 0) ? bbm[jt].x : (r == 1) ? bbm[jt].y
                                 : (r == 2) ? bbm[jt].z : bbm[jt].w;
                        sv[jt][r] = dead ? -FLT_MAX : fmaf(sac[m][jt][r], temp, bv);
                    }
                }
            }
            float pmax = fmaxf(fmaxf(fmaxf(sv[0][0], sv[0][1]), fmaxf(sv[0][2], sv[0][3])),
                               fmaxf(fmaxf(sv[1][0], sv[1][1]), fmaxf(sv[1][2], sv[1][3])));
            pmax = fmaxf(pmax, __shfl_xor(pmax, 16));
            pmax = fmaxf(pmax, __shfl_xor(pmax, 32));
            if (!__all(pmax <= m_r[m] + 8.f)) {
                float mn = fmaxf(m_r[m], pmax);
                float sc = __expf(m_r[m] - mn);
                m_r[m] = mn;
                l_r[m] *= sc;
                #pragma unroll
                for (int r = 0; r < 4; ++r) {
                    float sq = __shfl(sc, lg*4 + r);
                    #pragma unroll
                    for (int dt = 0; dt < 4; ++dt) oa[m][dt][r] *= sq;
                }
            }
            float rs = 0.f;
            #pragma unroll
            for (int jt = 0; jt < 2; ++jt)
                #pragma unroll
                for (int r = 0; r < 4; ++r) {
                    float pf = __expf(sv[jt][r] - m_r[m]);
                    _Float16 p16 = (_Float16)pf;
                    rs += (float)p16;            // l consistent with fp16 P
                    pah[m][jt*4 + r] = p16;
                }
            rs += __shfl_xor(rs, 16);
            rs += __shfl_xor(rs, 32);
            l_r[m] += rs;
        }

        __builtin_amdgcn_s_setprio(1);
        #pragma unroll
        for (int dt = 0; dt < 4; ++dt) {
            half8 vb = *(const half8*)(&Vs[cur][dt*16 + lm][lg*8]);
            #pragma unroll
            for (int m = 0; m < 2; ++m)
                oa[m][dt] = __builtin_amdgcn_mfma_f32_16x16x32_f16(pah[m], vb, oa[m][dt], 0, 0, 0);
        }
        __builtin_amdgcn_s_setprio(0);
        __syncthreads();
        #pragma unroll
        for (int m = 0; m < 2; ++m)
            #pragma unroll
            for (int jt = 0; jt < 2; ++jt) bb[m][jt] = bbn[m][jt];
        mk = mkn;
    }
    #undef A_ISSUE
    #undef STAGE

    #pragma unroll
    for (int m = 0; m < 2; ++m)
        #pragma unroll
        for (int dt = 0; dt < 4; ++dt)
            #pragma unroll
            for (int r = 0; r < 4; ++r)
                Opart[((size_t)(js*16 + bh) * NSEQ + qbase + 16*m + lg*4 + r) * 64
                      + dt*16 + lm] = oa[m][dt][r];
    if (lane < 16) {
        #pragma unroll
        for (int m = 0; m < 2; ++m) {
            size_t mi = ((size_t)(js*16 + bh) * NSEQ + qbase + 16*m + lm) * 2;
            Ml[mi]     = m_r[m];
            Ml[mi + 1] = l_r[m];
        }
    }
}

extern "C" void kernel_launch(void* const* d_in, const int* in_sizes, int n_in,
                              void* d_out, int out_size, void* d_ws, size_t ws_size,
                              hipStream_t stream)
{
    const float*   x        = (const float*)d_in[0];
    const float*   w_qkv    = (const float*)d_in[1];
    const float*   w_out    = (const float*)d_in[2];
    const float*   pos_bias = (const float*)d_in[3];
    const float*   temp     = (const float*)d_in[4];
    const uint8_t* mask     = (const uint8_t*)d_in[5];
    float* out = (float*)d_out;

    const int M = BATCH * NSEQ;                        // 4096
    const size_t NE = (size_t)BATCH * HEADS * NSEQ * DIM;
    const int ns = 3;                                  // grid 768 = 3 blocks/CU exactly
    const int base = 64 / ns, rem = 64 % ns;

    char* ws = (char*)d_ws;
    // region 0 (25.2 MB): qkv_lin f32; exactly reused by the 3-split f32 Opart
    float* qkv_lin = (float*)ws;
    float* OpartP  = (float*)ws;    // 3*16*2048*64*4 B == M*QKV3*4 B exactly
    size_t off = (size_t)M * QKV3 * 4;
    // region 1: fp16 transposed weights + Ml
    _Float16* WqkvT = (_Float16*)(ws + off); off += (size_t)QKV3 * CIN * 2;
    _Float16* WoutT = (_Float16*)(ws + off); off += (size_t)HD * CIN * 2;
    float*    MlP   = (float*)(ws + off);    off += (size_t)ns * 16 * NSEQ * 2 * 4;
    // region 2 (12.6 MB): Q16/K16/Vt16 fp16
    char* reg2 = ws + off;
    _Float16* Q16  = (_Float16*)reg2;
    _Float16* K16  = Q16 + NE;
    _Float16* Vt16 = K16 + NE;

    // 1. both weight converts in one launch
    cvt_wT_kernel<<<dim3(32, CIN/64), 256, 0, stream>>>(
        w_qkv, w_out, WqkvT, WoutT);
    // 2. qkv projection (fp16 single-term GEMM)
    gemm_f16_kernel<<<dim3(QKV3/64, M/128), 256, 0, stream>>>(
        x, WqkvT, qkv_lin, M, QKV3, CIN);
    // 3. fused l2norm + V transpose -> fp16
    qkv_prep_kernel<<<dim3(BATCH * HEADS * (NSEQ/64)), 256, 0, stream>>>(
        qkv_lin, Q16, K16, Vt16);
    // 4. attention (fp16 single-term; Opart overwrites qkv_lin)
    attn_mfma_kernel<<<dim3(256 * ns), 256, 0, stream>>>(
        Q16, K16, Vt16, pos_bias, temp, mask, OpartP, MlP, ns, base, rem);
    // 5. out projection with fused 3-way merge (fp16)
    gemm_merge_kernel<<<dim3(CIN/64, M/64), 256, 0, stream>>>(
        OpartP, MlP, WoutT, out);
}

// Round 16
// 125.401 us; speedup vs baseline: 1.8749x; 1.0003x over previous
//
#include <hip/hip_runtime.h>
#include <cfloat>
#include <cstdint>

#define BATCH 2
#define NSEQ 2048
#define CIN 512
#define HEADS 8
#define DIM 64
#define HD 512
#define QKV3 1536

typedef short short8 __attribute__((ext_vector_type(8)));
typedef _Float16 half8 __attribute__((ext_vector_type(8)));
typedef float f32x4 __attribute__((ext_vector_type(4)));
typedef unsigned short ushort_t;

// T2 XOR swizzle (halfword-index units): toggles the 8-half (16B) slot
// within a 64-half (128B) row; bank set then depends only on slot.
#define SWZ(row, col) ((col) ^ (((row) & 7) << 3))

// ---------- convert + transpose BOTH weights to fp16 in one launch --------
__global__ __launch_bounds__(256) void cvt_wT_kernel(
    const float* __restrict__ Wq, const float* __restrict__ Wo,
    _Float16* __restrict__ WqT, _Float16* __restrict__ WoT)
{
    __shared__ float T[64][65];
    const int bx = blockIdx.x;
    const float* W; _Float16* WT; int N, n0;
    if (bx < 24) { W = Wq; WT = WqT; N = QKV3; n0 = bx * 64; }
    else         { W = Wo; WT = WoT; N = HD;   n0 = (bx - 24) * 64; }
    const int K = CIN;
    const int k0 = blockIdx.y * 64;
    const int tid = threadIdx.x;
    #pragma unroll
    for (int i = 0; i < 4; ++i) {
        int c = tid + i * 256;
        int row = c >> 4, c4 = c & 15;
        *(float4*)&T[row][c4*4] = *(const float4*)(W + (size_t)(k0 + row) * N + n0 + c4*4);
    }
    __syncthreads();
    const int n = tid >> 2, kseg = tid & 3;
    _Float16 hv[16];
    #pragma unroll
    for (int e = 0; e < 16; ++e)
        hv[e] = (_Float16)T[kseg*16 + e][n];
    size_t o = (size_t)(n0 + n) * K + k0 + kseg * 16;
    *(uint4*)(WT + o)     = *(uint4*)&hv[0];
    *(uint4*)(WT + o + 8) = *(uint4*)&hv[8];
}

// ---------- fp16 MFMA GEMM: C[M][N] = A[M][K](f32) @ BT[N][K](fp16) -------
// BM=128 BN=64 BK=64; stage-time A->fp16; XOR-swizzled LDS (24.5KB)
__global__ __launch_bounds__(256, 2) void gemm_f16_kernel(
    const float* __restrict__ A, const _Float16* __restrict__ BT,
    float* __restrict__ C, int M, int N, int K)
{
    __shared__ _Float16 As[128][64];   // 16,384 B
    __shared__ _Float16 Bs[64][64];    //  8,192 B
    const int bm = blockIdx.y * 128, bn = blockIdx.x * 64;
    const int tid = threadIdx.x;
    const int wave = tid >> 6, lane = tid & 63;
    const int lg = lane >> 4, lm = lane & 15;
    const int wm = wave >> 1, wn = wave & 1;
    const int arow = tid >> 3, aseg = tid & 7;
    const int scol = SWZ(arow, aseg * 8);

    f32x4 acc[4][2];
    #pragma unroll
    for (int mf = 0; mf < 4; ++mf)
        #pragma unroll
        for (int nf = 0; nf < 2; ++nf) acc[mf][nf] = (f32x4){0.f,0.f,0.f,0.f};

    float4 ar[8];
    uint4 br[2];
    const int nkt = K >> 6;

    #define G_ISSUE(K0)                                                          \
        { _Pragma("unroll")                                                      \
          for (int i = 0; i < 4; ++i) {                                          \
            const float* ap = A + (size_t)(bm + arow + 32*i) * K + (K0) + aseg*8;\
            ar[2*i]   = *(const float4*)ap;                                      \
            ar[2*i+1] = *(const float4*)(ap + 4);                                \
          }                                                                      \
          _Pragma("unroll")                                                      \
          for (int i = 0; i < 2; ++i) {                                          \
            size_t bo = (size_t)(bn + arow + 32*i) * K + (K0) + aseg*8;          \
            br[i] = *(const uint4*)(BT + bo);                                    \
          } }

    G_ISSUE(0)
    for (int kt = 0; kt < nkt; ++kt) {
        __syncthreads();
        #pragma unroll
        for (int i = 0; i < 4; ++i) {
            float av[8];
            *(float4*)&av[0] = ar[2*i];
            *(float4*)&av[4] = ar[2*i+1];
            half8 hh;
            #pragma unroll
            for (int e = 0; e < 8; ++e) hh[e] = (_Float16)av[e];
            *(half8*)&As[arow + 32*i][scol] = hh;
        }
        #pragma unroll
        for (int i = 0; i < 2; ++i)
            *(uint4*)&Bs[arow + 32*i][scol] = br[i];
        if (kt + 1 < nkt) G_ISSUE((kt + 1) * 64)
        __syncthreads();
        #pragma unroll
        for (int ks = 0; ks < 2; ++ks) {
            const int rcol = SWZ(lm, ks*32 + lg*8);
            half8 af[4], bf[2];
            #pragma unroll
            for (int mf = 0; mf < 4; ++mf)
                af[mf] = *(const half8*)&As[wm*64 + mf*16 + lm][rcol];
            #pragma unroll
            for (int nf = 0; nf < 2; ++nf)
                bf[nf] = *(const half8*)&Bs[wn*32 + nf*16 + lm][rcol];
            #pragma unroll
            for (int mf = 0; mf < 4; ++mf)
                #pragma unroll
                for (int nf = 0; nf < 2; ++nf)
                    acc[mf][nf] = __builtin_amdgcn_mfma_f32_16x16x32_f16(af[mf], bf[nf], acc[mf][nf], 0, 0, 0);
        }
    }
    #pragma unroll
    for (int mf = 0; mf < 4; ++mf)
        #pragma unroll
        for (int nf = 0; nf < 2; ++nf)
            #pragma unroll
            for (int r = 0; r < 4; ++r)
                C[(size_t)(bm + wm*64 + mf*16 + lg*4 + r) * N + bn + wn*32 + nf*16 + lm]
                    = acc[mf][nf][r];
    #undef G_ISSUE
}

// ---------- out-proj fp16 GEMM with FUSED 3-way merge (16KB LDS) ----------
// out[M][512] = merge(Opart,Ml) @ WoT;  BM=64 BN=64 BK=64 (h = kt)
__global__ __launch_bounds__(256, 2) void gemm_merge_kernel(
    const float* __restrict__ Opart, const float* __restrict__ Ml,
    const _Float16* __restrict__ BT, float* __restrict__ C)
{
    __shared__ _Float16 As[64][64];   // 8,192 B
    __shared__ _Float16 Bs[64][64];   // 8,192 B
    const int bm = blockIdx.y * 64, bn = blockIdx.x * 64;
    const int tid = threadIdx.x;
    const int wave = tid >> 6, lane = tid & 63;
    const int lg = lane >> 4, lm = lane & 15;
    const int wm = wave >> 1, wn = wave & 1;
    const int srow = tid >> 2, sseg = tid & 3;    // stage: 64 rows x 4 segs of 16
    const int sc0 = SWZ(srow, sseg * 16);
    const int sc1 = SWZ(srow, sseg * 16 + 8);

    f32x4 acc[2][2];
    #pragma unroll
    for (int mf = 0; mf < 2; ++mf)
        #pragma unroll
        for (int nf = 0; nf < 2; ++nf) acc[mf][nf] = (f32x4){0.f,0.f,0.f,0.f};

    float4 ar[4];
    uint4 br[2];

    #define GM_ISSUE(KT) {                                                      \
        const int h_ = (KT);                                                    \
        const int mrow = bm + srow;                                             \
        const int b_ = mrow >> 11, n_ = mrow & (NSEQ - 1);                      \
        float mv0, mv1, mv2, lv0, lv1, lv2;                                     \
        { size_t mi = ((size_t)(b_*8 + h_) * NSEQ + n_) * 2;                    \
          mv0 = Ml[mi]; lv0 = Ml[mi+1];                                         \
          mi = ((size_t)(16 + b_*8 + h_) * NSEQ + n_) * 2;                      \
          mv1 = Ml[mi]; lv1 = Ml[mi+1];                                         \
          mi = ((size_t)(32 + b_*8 + h_) * NSEQ + n_) * 2;                      \
          mv2 = Ml[mi]; lv2 = Ml[mi+1]; }                                       \
        float mm = fmaxf(fmaxf(mv0, mv1), mv2);                                 \
        float w0 = __expf(mv0 - mm), w1 = __expf(mv1 - mm), w2 = __expf(mv2 - mm);\
        float inv = 1.f / (lv0*w0 + lv1*w1 + lv2*w2);                           \
        size_t o0 = ((size_t)(b_*8 + h_) * NSEQ + n_) * 64 + sseg*16;           \
        size_t o1 = ((size_t)(16 + b_*8 + h_) * NSEQ + n_) * 64 + sseg*16;      \
        size_t o2 = ((size_t)(32 + b_*8 + h_) * NSEQ + n_) * 64 + sseg*16;      \
        _Pragma("unroll")                                                       \
        for (int c = 0; c < 4; ++c) {                                           \
            float4 v0 = *(const float4*)(Opart + o0 + c*4);                     \
            float4 v1 = *(const float4*)(Opart + o1 + c*4);                     \
            float4 v2 = *(const float4*)(Opart + o2 + c*4);                     \
            ar[c].x = (v0.x*w0 + v1.x*w1 + v2.x*w2) * inv;                      \
            ar[c].y = (v0.y*w0 + v1.y*w1 + v2.y*w2) * inv;                      \
            ar[c].z = (v0.z*w0 + v1.z*w1 + v2.z*w2) * inv;                      \
            ar[c].w = (v0.w*w0 + v1.w*w1 + v2.w*w2) * inv;                      \
        }                                                                       \
        size_t bo = (size_t)(bn + srow) * CIN + (KT)*64 + sseg*16;              \
        br[0] = *(const uint4*)(BT + bo);                                       \
        br[1] = *(const uint4*)(BT + bo + 8); }

    GM_ISSUE(0)
    for (int kt = 0; kt < 8; ++kt) {
        __syncthreads();
        {   // stage-time f32 -> fp16 (proven stage-convert pattern)
            float av[16];
            *(float4*)&av[0]  = ar[0];
            *(float4*)&av[4]  = ar[1];
            *(float4*)&av[8]  = ar[2];
            *(float4*)&av[12] = ar[3];
            half8 h0, h1;
            #pragma unroll
            for (int e = 0; e < 8; ++e) {
                h0[e] = (_Float16)av[e];
                h1[e] = (_Float16)av[e + 8];
            }
            *(half8*)&As[srow][sc0] = h0;
            *(half8*)&As[srow][sc1] = h1;
        }
        *(uint4*)&Bs[srow][sc0] = br[0];
        *(uint4*)&Bs[srow][sc1] = br[1];
        if (kt + 1 < 8) GM_ISSUE(kt + 1)
        __syncthreads();
        #pragma unroll
        for (int ks = 0; ks < 2; ++ks) {
            const int rcol = SWZ(lm, ks*32 + lg*8);
            half8 af[2], bf[2];
            #pragma unroll
            for (int mf = 0; mf < 2; ++mf)
                af[mf] = *(const half8*)&As[wm*32 + mf*16 + lm][rcol];
            #pragma unroll
            for (int nf = 0; nf < 2; ++nf)
                bf[nf] = *(const half8*)&Bs[wn*32 + nf*16 + lm][rcol];
            #pragma unroll
            for (int mf = 0; mf < 2; ++mf)
                #pragma unroll
                for (int nf = 0; nf < 2; ++nf)
                    acc[mf][nf] = __builtin_amdgcn_mfma_f32_16x16x32_f16(af[mf], bf[nf], acc[mf][nf], 0, 0, 0);
        }
    }
    #pragma unroll
    for (int mf = 0; mf < 2; ++mf)
        #pragma unroll
        for (int nf = 0; nf < 2; ++nf)
            #pragma unroll
            for (int r = 0; r < 4; ++r)
                C[(size_t)(bm + wm*32 + mf*16 + lg*4 + r) * CIN + bn + wn*32 + nf*16 + lm]
                    = acc[mf][nf][r];
    #undef GM_ISSUE
}

// ------- fused qkv prep (fp16): l2norm Q,K -> fp16; V transposed+perm fp16 -
__global__ __launch_bounds__(256) void qkv_prep_kernel(
    const float* __restrict__ qkv,
    _Float16* __restrict__ Q16, _Float16* __restrict__ K16,
    _Float16* __restrict__ Vt16)
{
    __shared__ float Vf[64][65];
    const int id = blockIdx.x;
    const int bh = id >> 5, nt = id & 31;
    const int b = bh >> 3, h = bh & 7;
    const int n0 = nt * 64;
    const int tid = threadIdx.x;
    {
        const int row = tid >> 2, dseg = tid & 3;
        const float* src = qkv + ((size_t)(b * NSEQ + n0 + row)) * QKV3
                         + h * 192 + dseg * 48;
        float f[48];
        #pragma unroll
        for (int i = 0; i < 12; ++i)
            *(float4*)&f[i*4] = *(const float4*)(src + i*4);
        float nq = 0.f, nk = 0.f;
        #pragma unroll
        for (int e = 0; e < 16; ++e) {
            nq = fmaf(f[3*e], f[3*e], nq);
            nk = fmaf(f[3*e+1], f[3*e+1], nk);
        }
        nq += __shfl_xor(nq, 1); nq += __shfl_xor(nq, 2);
        nk += __shfl_xor(nk, 1); nk += __shfl_xor(nk, 2);
        float rq = 1.f / fmaxf(sqrtf(nq), 1e-12f);
        float rk = 1.f / fmaxf(sqrtf(nk), 1e-12f);
        _Float16 q16[16], k16[16];
        #pragma unroll
        for (int e = 0; e < 16; ++e) {
            q16[e] = (_Float16)(f[3*e] * rq);
            k16[e] = (_Float16)(f[3*e+1] * rk);
            Vf[dseg*16 + e][row] = f[3*e+2];
        }
        size_t o = ((size_t)bh * NSEQ + n0 + row) * DIM + dseg * 16;
        *(uint4*)(Q16 + o)     = *(uint4*)&q16[0];
        *(uint4*)(Q16 + o + 8) = *(uint4*)&q16[8];
        *(uint4*)(K16 + o)     = *(uint4*)&k16[0];
        *(uint4*)(K16 + o + 8) = *(uint4*)&k16[8];
    }
    __syncthreads();
    {   // Vt[bh][d][n] with the PV fragment j-permutation (within 32-blocks)
        const int d = tid >> 2, seg = tid & 3;
        _Float16 tv[16];
        #pragma unroll
        for (int t = 0; t < 16; ++t) {
            int p = seg * 16 + t;
            int s = (p & 35) | ((p & 4) << 2) | ((p >> 1) & 12);
            tv[t] = (_Float16)Vf[d][s];
        }
        size_t o = ((size_t)bh * DIM + d) * NSEQ + n0 + seg * 16;
        *(uint4*)(Vt16 + o)     = *(uint4*)&tv[0];
        *(uint4*)(Vt16 + o + 8) = *(uint4*)&tv[8];
    }
}

// ---------------- MFMA flash attention v9: single-term fp16 (R14-proven) --
__global__ __launch_bounds__(256, 3) void attn_mfma_kernel(
    const _Float16* __restrict__ Q16, const _Float16* __restrict__ K16,
    const _Float16* __restrict__ Vt16,
    const float* __restrict__ bias, const float* __restrict__ temp_p,
    const uint8_t* __restrict__ mask,
    float* __restrict__ Opart, float* __restrict__ Ml,
    int ns, int base, int rem)
{
    __shared__ _Float16 Ks[2][32][72];   // [buf][j][d]   9,216 B
    __shared__ _Float16 Vs[2][64][36];   // [buf][d][j']  9,216 B

    const int id = blockIdx.x;
    const int h = id & 7;                  // XCD-grouped
    const int rest = id >> 3;
    const int per_b = 16 * ns;
    const int b = rest / per_b;
    const int r2 = rest - b * per_b;
    const int js = r2 >> 4;
    const int qt = r2 & 15;
    const int bh = b * 8 + h;
    const int i0 = qt * 128;
    const int tid = threadIdx.x;
    const int wave = tid >> 6, lane = tid & 63;
    const int lg = lane >> 4, lm = lane & 15;
    const int qbase = i0 + wave * 32;
    const float temp = *temp_p;
    const int krow = tid >> 3, kseg = tid & 7;
    const int vrow = tid >> 2, vseg = tid & 3;

    half8 qf[2][2];
    #pragma unroll
    for (int m = 0; m < 2; ++m) {
        size_t qo = ((size_t)(bh * NSEQ + qbase + 16*m + lm)) * DIM + lg * 8;
        qf[m][0] = *(const half8*)(Q16 + qo);
        qf[m][1] = *(const half8*)(Q16 + qo + 32);
    }
    bool rowm[2];
    rowm[0] = mask[(size_t)b * NSEQ + qbase + lm] != 0;
    rowm[1] = mask[(size_t)b * NSEQ + qbase + 16 + lm] != 0;
    const bool nomaskrow = __all(!rowm[0] && !rowm[1]);

    const float* bp0 = bias + ((size_t)h * NSEQ + qbase + lm) * NSEQ;
    const float* bp1 = bp0 + (size_t)16 * NSEQ;
    const int lgo = lg * 4;

    float m_r[2] = {-FLT_MAX, -FLT_MAX};
    float l_r[2] = {0.f, 0.f};
    f32x4 oa[2][4];
    #pragma unroll
    for (int m = 0; m < 2; ++m)
        #pragma unroll
        for (int dt = 0; dt < 4; ++dt) oa[m][dt] = (f32x4){0.f,0.f,0.f,0.f};

    const int NT = base + (js < rem ? 1 : 0);
    const int tstart = js * base + (js < rem ? js : rem);
    const int jbase = tstart * 32;
    uint4 skh, svh;

    #define A_ISSUE(J0) {                                                      \
        size_t gk = ((size_t)(bh * NSEQ) + (J0) + krow) * DIM + kseg*8;        \
        size_t gv = ((size_t)(bh * DIM) + vrow) * NSEQ + (J0) + vseg*8;        \
        skh = *(const uint4*)(K16  + gk);                                      \
        svh = *(const uint4*)(Vt16 + gv); }
    #define STAGE(BUF) {                                                       \
        *(uint4*)&Ks[BUF][krow][kseg*8] = skh;                                 \
        *(uint4*)&Vs[BUF][vrow][vseg*8] = svh; }

    A_ISSUE(jbase)
    STAGE(0)
    A_ISSUE(jbase + 32)
    float4 bb[2][2];
    #pragma unroll
    for (int jt = 0; jt < 2; ++jt) {
        bb[0][jt] = *(const float4*)(bp0 + jbase + jt*16 + lgo);
        bb[1][jt] = *(const float4*)(bp1 + jbase + jt*16 + lgo);
    }
    uint8_t mk = mask[(size_t)b * NSEQ + jbase + (lane & 31)];
    __syncthreads();

    #pragma unroll 2
    for (int t = 0; t < NT; ++t) {
        const int cur = t & 1;
        const int j0 = jbase + t * 32;

        float4 bbn[2][2];
        uint8_t mkn = 0;
        if (t + 1 < NT) {
            #pragma unroll
            for (int jt = 0; jt < 2; ++jt) {
                bbn[0][jt] = *(const float4*)(bp0 + j0 + 32 + jt*16 + lgo);
                bbn[1][jt] = *(const float4*)(bp1 + j0 + 32 + jt*16 + lgo);
            }
            mkn = mask[(size_t)b * NSEQ + j0 + 32 + (lane & 31)];
            STAGE(cur ^ 1)
            if (t + 2 < NT) A_ISSUE(j0 + 64)
        }
        unsigned long long bal = __ballot(mk != 0);

        f32x4 sac[2][2];
        #pragma unroll
        for (int m = 0; m < 2; ++m)
            #pragma unroll
            for (int jt = 0; jt < 2; ++jt) sac[m][jt] = (f32x4){0.f,0.f,0.f,0.f};
        __builtin_amdgcn_s_setprio(1);
        #pragma unroll
        for (int jt = 0; jt < 2; ++jt)
            #pragma unroll
            for (int ks = 0; ks < 2; ++ks) {
                half8 kb = *(const half8*)(&Ks[cur][jt*16 + lm][ks*32 + lg*8]);
                #pragma unroll
                for (int m = 0; m < 2; ++m)
                    sac[m][jt] = __builtin_amdgcn_mfma_f32_16x16x32_f16(kb, qf[m][ks], sac[m][jt], 0, 0, 0);
            }
        __builtin_amdgcn_s_setprio(0);

        half8 pah[2];
        #pragma unroll
        for (int m = 0; m < 2; ++m) {
            const float4* bbm = bb[m];
            float sv[2][4];
            if (nomaskrow && bal == 0) {
                #pragma unroll
                for (int jt = 0; jt < 2; ++jt) {
                    sv[jt][0] = fmaf(sac[m][jt][0], temp, bbm[jt].x);
                    sv[jt][1] = fmaf(sac[m][jt][1], temp, bbm[jt].y);
                    sv[jt][2] = fmaf(sac[m][jt][2], temp, bbm[jt].z);
                    sv[jt][3] = fmaf(sac[m][jt][3], temp, bbm[jt].w);
                }
            } else {
                #pragma unroll
                for (int jt = 0; jt < 2; ++jt) {
                    unsigned int nib = (unsigned int)(bal >> (jt*16 + lg*4)) & 0xFu;
                    #pragma unroll
                    for (int r = 0; r < 4; ++r) {
                        bool dead = rowm[m] || ((nib >> r) & 1u);
                        float bv = (r == 0) ? bbm[jt].x : (r == 1) ? bbm[jt].y
                                 : (r == 2) ? bbm[jt].z : bbm[jt].w;
                        sv[jt][r] = dead ? -FLT_MAX : fmaf(sac[m][jt][r], temp, bv);
                    }
                }
            }
            float pmax = fmaxf(fmaxf(fmaxf(sv[0][0], sv[0][1]), fmaxf(sv[0][2], sv[0][3])),
                               fmaxf(fmaxf(sv[1][0], sv[1][1]), fmaxf(sv[1][2], sv[1][3])));
            pmax = fmaxf(pmax, __shfl_xor(pmax, 16));
            pmax = fmaxf(pmax, __shfl_xor(pmax, 32));
            if (!__all(pmax <= m_r[m] + 8.f)) {
                float mn = fmaxf(m_r[m], pmax);
                float sc = __expf(m_r[m] - mn);
                m_r[m] = mn;
                l_r[m] *= sc;
                #pragma unroll
                for (int r = 0; r < 4; ++r) {
                    float sq = __shfl(sc, lg*4 + r);
                    #pragma unroll
                    for (int dt = 0; dt < 4; ++dt) oa[m][dt][r] *= sq;
                }
            }
            float rs = 0.f;
            #pragma unroll
            for (int jt = 0; jt < 2; ++jt)
                #pragma unroll
                for (int r = 0; r < 4; ++r) {
                    float pf = __expf(sv[jt][r] - m_r[m]);
                    _Float16 p16 = (_Float16)pf;
                    rs += (float)p16;            // l consistent with fp16 P
                    pah[m][jt*4 + r] = p16;
                }
            rs += __shfl_xor(rs, 16);
            rs += __shfl_xor(rs, 32);
            l_r[m] += rs;
        }

        __builtin_amdgcn_s_setprio(1);
        #pragma unroll
        for (int dt = 0; dt < 4; ++dt) {
            half8 vb = *(const half8*)(&Vs[cur][dt*16 + lm][lg*8]);
            #pragma unroll
            for (int m = 0; m < 2; ++m)
                oa[m][dt] = __builtin_amdgcn_mfma_f32_16x16x32_f16(pah[m], vb, oa[m][dt], 0, 0, 0);
        }
        __builtin_amdgcn_s_setprio(0);
        __syncthreads();
        #pragma unroll
        for (int m = 0; m < 2; ++m)
            #pragma unroll
            for (int jt = 0; jt < 2; ++jt) bb[m][jt] = bbn[m][jt];
        mk = mkn;
    }
    #undef A_ISSUE
    #undef STAGE

    #pragma unroll
    for (int m = 0; m < 2; ++m)
        #pragma unroll
        for (int dt = 0; dt < 4; ++dt)
            #pragma unroll
            for (int r = 0; r < 4; ++r)
                Opart[((size_t)(js*16 + bh) * NSEQ + qbase + 16*m + lg*4 + r) * 64
                      + dt*16 + lm] = oa[m][dt][r];
    if (lane < 16) {
        #pragma unroll
        for (int m = 0; m < 2; ++m) {
            size_t mi = ((size_t)(js*16 + bh) * NSEQ + qbase + 16*m + lm) * 2;
            Ml[mi]     = m_r[m];
            Ml[mi + 1] = l_r[m];
        }
    }
}

extern "C" void kernel_launch(void* const* d_in, const int* in_sizes, int n_in,
                              void* d_out, int out_size, void* d_ws, size_t ws_size,
                              hipStream_t stream)
{
    const float*   x        = (const float*)d_in[0];
    const float*   w_qkv    = (const float*)d_in[1];
    const float*   w_out    = (const float*)d_in[2];
    const float*   pos_bias = (const float*)d_in[3];
    const float*   temp     = (const float*)d_in[4];
    const uint8_t* mask     = (const uint8_t*)d_in[5];
    float* out = (float*)d_out;

    const int M = BATCH * NSEQ;                        // 4096
    const size_t NE = (size_t)BATCH * HEADS * NSEQ * DIM;
    const int ns = 3;                                  // grid 768 = 3 blocks/CU exactly
    const int base = 64 / ns, rem = 64 % ns;

    char* ws = (char*)d_ws;
    // region 0 (25.2 MB): qkv_lin f32; exactly reused by the 3-split f32 Opart
    float* qkv_lin = (float*)ws;
    float* OpartP  = (float*)ws;    // 3*16*2048*64*4 B == M*QKV3*4 B exactly
    size_t off = (size_t)M * QKV3 * 4;
    // region 1: fp16 transposed weights + Ml
    _Float16* WqkvT = (_Float16*)(ws + off); off += (size_t)QKV3 * CIN * 2;
    _Float16* WoutT = (_Float16*)(ws + off); off += (size_t)HD * CIN * 2;
    float*    MlP   = (float*)(ws + off);    off += (size_t)ns * 16 * NSEQ * 2 * 4;
    // region 2 (12.6 MB): Q16/K16/Vt16 fp16
    char* reg2 = ws + off;
    _Float16* Q16  = (_Float16*)reg2;
    _Float16* K16  = Q16 + NE;
    _Float16* Vt16 = K16 + NE;

    // 1. both weight converts in one launch
    cvt_wT_kernel<<<dim3(32, CIN/64), 256, 0, stream>>>(
        w_qkv, w_out, WqkvT, WoutT);
    // 2. qkv projection (fp16 single-term GEMM)
    gemm_f16_kernel<<<dim3(QKV3/64, M/128), 256, 0, stream>>>(
        x, WqkvT, qkv_lin, M, QKV3, CIN);
    // 3. fused l2norm + V transpose -> fp16
    qkv_prep_kernel<<<dim3(BATCH * HEADS * (NSEQ/64)), 256, 0, stream>>>(
        qkv_lin, Q16, K16, Vt16);
    // 4. attention (fp16 single-term; Opart overwrites qkv_lin)
    attn_mfma_kernel<<<dim3(256 * ns), 256, 0, stream>>>(
        Q16, K16, Vt16, pos_bias, temp, mask, OpartP, MlP, ns, base, rem);
    // 5. out projection with fused 3-way merge (fp16)
    gemm_merge_kernel<<<dim3(CIN/64, M/64), 256, 0, stream>>>(
        OpartP, MlP, WoutT, out);
}

// Round 17
// 125.309 us; speedup vs baseline: 1.8763x; 1.0007x over previous
//
#include <hip/hip_runtime.h>
#include <cfloat>
#include <cstdint>

#define BATCH 2
#define NSEQ 2048
#define CIN 512
#define HEADS 8
#define DIM 64
#define HD 512
#define QKV3 1536

typedef short short8 __attribute__((ext_vector_type(8)));
typedef _Float16 half8 __attribute__((ext_vector_type(8)));
typedef float f32x4 __attribute__((ext_vector_type(4)));
typedef unsigned short ushort_t;

// T2 XOR swizzle (halfword-index units): toggles the 8-half (16B) slot
// within a 64-half (128B) row; bank set then depends only on slot.
#define SWZ(row, col) ((col) ^ (((row) & 7) << 3))

// ---------- convert + transpose BOTH weights to fp16 in one launch --------
__global__ __launch_bounds__(256) void cvt_wT_kernel(
    const float* __restrict__ Wq, const float* __restrict__ Wo,
    _Float16* __restrict__ WqT, _Float16* __restrict__ WoT)
{
    __shared__ float T[64][65];
    const int bx = blockIdx.x;
    const float* W; _Float16* WT; int N, n0;
    if (bx < 24) { W = Wq; WT = WqT; N = QKV3; n0 = bx * 64; }
    else         { W = Wo; WT = WoT; N = HD;   n0 = (bx - 24) * 64; }
    const int K = CIN;
    const int k0 = blockIdx.y * 64;
    const int tid = threadIdx.x;
    #pragma unroll
    for (int i = 0; i < 4; ++i) {
        int c = tid + i * 256;
        int row = c >> 4, c4 = c & 15;
        *(float4*)&T[row][c4*4] = *(const float4*)(W + (size_t)(k0 + row) * N + n0 + c4*4);
    }
    __syncthreads();
    const int n = tid >> 2, kseg = tid & 3;
    _Float16 hv[16];
    #pragma unroll
    for (int e = 0; e < 16; ++e)
        hv[e] = (_Float16)T[kseg*16 + e][n];
    size_t o = (size_t)(n0 + n) * K + k0 + kseg * 16;
    *(uint4*)(WT + o)     = *(uint4*)&hv[0];
    *(uint4*)(WT + o + 8) = *(uint4*)&hv[8];
}

// ---------- fp16 MFMA GEMM: C[M][N] = A[M][K](f32) @ BT[N][K](fp16) -------
// BM=128 BN=64 BK=64; stage-time A->fp16; XOR-swizzled LDS (24.5KB)
__global__ __launch_bounds__(256, 2) void gemm_f16_kernel(
    const float* __restrict__ A, const _Float16* __restrict__ BT,
    float* __restrict__ C, int M, int N, int K)
{
    __shared__ _Float16 As[128][64];   // 16,384 B
    __shared__ _Float16 Bs[64][64];    //  8,192 B
    const int bm = blockIdx.y * 128, bn = blockIdx.x * 64;
    const int tid = threadIdx.x;
    const int wave = tid >> 6, lane = tid & 63;
    const int lg = lane >> 4, lm = lane & 15;
    const int wm = wave >> 1, wn = wave & 1;
    const int arow = tid >> 3, aseg = tid & 7;
    const int scol = SWZ(arow, aseg * 8);

    f32x4 acc[4][2];
    #pragma unroll
    for (int mf = 0; mf < 4; ++mf)
        #pragma unroll
        for (int nf = 0; nf < 2; ++nf) acc[mf][nf] = (f32x4){0.f,0.f,0.f,0.f};

    float4 ar[8];
    uint4 br[2];
    const int nkt = K >> 6;

    #define G_ISSUE(K0)                                                          \
        { _Pragma("unroll")                                                      \
          for (int i = 0; i < 4; ++i) {                                          \
            const float* ap = A + (size_t)(bm + arow + 32*i) * K + (K0) + aseg*8;\
            ar[2*i]   = *(const float4*)ap;                                      \
            ar[2*i+1] = *(const float4*)(ap + 4);                                \
          }                                                                      \
          _Pragma("unroll")                                                      \
          for (int i = 0; i < 2; ++i) {                                          \
            size_t bo = (size_t)(bn + arow + 32*i) * K + (K0) + aseg*8;          \
            br[i] = *(const uint4*)(BT + bo);                                    \
          } }

    G_ISSUE(0)
    for (int kt = 0; kt < nkt; ++kt) {
        __syncthreads();
        #pragma unroll
        for (int i = 0; i < 4; ++i) {
            float av[8];
            *(float4*)&av[0] = ar[2*i];
            *(float4*)&av[4] = ar[2*i+1];
            half8 hh;
            #pragma unroll
            for (int e = 0; e < 8; ++e) hh[e] = (_Float16)av[e];
            *(half8*)&As[arow + 32*i][scol] = hh;
        }
        #pragma unroll
        for (int i = 0; i < 2; ++i)
            *(uint4*)&Bs[arow + 32*i][scol] = br[i];
        if (kt + 1 < nkt) G_ISSUE((kt + 1) * 64)
        __syncthreads();
        #pragma unroll
        for (int ks = 0; ks < 2; ++ks) {
            const int rcol = SWZ(lm, ks*32 + lg*8);
            half8 af[4], bf[2];
            #pragma unroll
            for (int mf = 0; mf < 4; ++mf)
                af[mf] = *(const half8*)&As[wm*64 + mf*16 + lm][rcol];
            #pragma unroll
            for (int nf = 0; nf < 2; ++nf)
                bf[nf] = *(const half8*)&Bs[wn*32 + nf*16 + lm][rcol];
            #pragma unroll
            for (int mf = 0; mf < 4; ++mf)
                #pragma unroll
                for (int nf = 0; nf < 2; ++nf)
                    acc[mf][nf] = __builtin_amdgcn_mfma_f32_16x16x32_f16(af[mf], bf[nf], acc[mf][nf], 0, 0, 0);
        }
    }
    #pragma unroll
    for (int mf = 0; mf < 4; ++mf)
        #pragma unroll
        for (int nf = 0; nf < 2; ++nf)
            #pragma unroll
            for (int r = 0; r < 4; ++r)
                C[(size_t)(bm + wm*64 + mf*16 + lg*4 + r) * N + bn + wn*32 + nf*16 + lm]
                    = acc[mf][nf][r];
    #undef G_ISSUE
}

// ---------- out-proj fp16 GEMM with FUSED 3-way merge (16KB LDS) ----------
// out[M][512] = merge(Opart,Ml) @ WoT;  BM=64 BN=64 BK=64 (h = kt)
__global__ __launch_bounds__(256, 2) void gemm_merge_kernel(
    const float* __restrict__ Opart, const float* __restrict__ Ml,
    const _Float16* __restrict__ BT, float* __restrict__ C)
{
    __shared__ _Float16 As[64][64];   // 8,192 B
    __shared__ _Float16 Bs[64][64];   // 8,192 B
    const int bm = blockIdx.y * 64, bn = blockIdx.x * 64;
    const int tid = threadIdx.x;
    const int wave = tid >> 6, lane = tid & 63;
    const int lg = lane >> 4, lm = lane & 15;
    const int wm = wave >> 1, wn = wave & 1;
    const int srow = tid >> 2, sseg = tid & 3;    // stage: 64 rows x 4 segs of 16
    const int sc0 = SWZ(srow, sseg * 16);
    const int sc1 = SWZ(srow, sseg * 16 + 8);

    f32x4 acc[2][2];
    #pragma unroll
    for (int mf = 0; mf < 2; ++mf)
        #pragma unroll
        for (int nf = 0; nf < 2; ++nf) acc[mf][nf] = (f32x4){0.f,0.f,0.f,0.f};

    float4 ar[4];
    uint4 br[2];

    #define GM_ISSUE(KT) {                                                      \
        const int h_ = (KT);                                                    \
        const int mrow = bm + srow;                                             \
        const int b_ = mrow >> 11, n_ = mrow & (NSEQ - 1);                      \
        float mv0, mv1, mv2, lv0, lv1, lv2;                                     \
        { size_t mi = ((size_t)(b_*8 + h_) * NSEQ + n_) * 2;                    \
          mv0 = Ml[mi]; lv0 = Ml[mi+1];                                         \
          mi = ((size_t)(16 + b_*8 + h_) * NSEQ + n_) * 2;                      \
          mv1 = Ml[mi]; lv1 = Ml[mi+1];                                         \
          mi = ((size_t)(32 + b_*8 + h_) * NSEQ + n_) * 2;                      \
          mv2 = Ml[mi]; lv2 = Ml[mi+1]; }                                       \
        float mm = fmaxf(fmaxf(mv0, mv1), mv2);                                 \
        float w0 = __expf(mv0 - mm), w1 = __expf(mv1 - mm), w2 = __expf(mv2 - mm);\
        float inv = 1.f / (lv0*w0 + lv1*w1 + lv2*w2);                           \
        size_t o0 = ((size_t)(b_*8 + h_) * NSEQ + n_) * 64 + sseg*16;           \
        size_t o1 = ((size_t)(16 + b_*8 + h_) * NSEQ + n_) * 64 + sseg*16;      \
        size_t o2 = ((size_t)(32 + b_*8 + h_) * NSEQ + n_) * 64 + sseg*16;      \
        _Pragma("unroll")                                                       \
        for (int c = 0; c < 4; ++c) {                                           \
            float4 v0 = *(const float4*)(Opart + o0 + c*4);                     \
            float4 v1 = *(const float4*)(Opart + o1 + c*4);                     \
            float4 v2 = *(const float4*)(Opart + o2 + c*4);                     \
            ar[c].x = (v0.x*w0 + v1.x*w1 + v2.x*w2) * inv;                      \
            ar[c].y = (v0.y*w0 + v1.y*w1 + v2.y*w2) * inv;                      \
            ar[c].z = (v0.z*w0 + v1.z*w1 + v2.z*w2) * inv;                      \
            ar[c].w = (v0.w*w0 + v1.w*w1 + v2.w*w2) * inv;                      \
        }                                                                       \
        size_t bo = (size_t)(bn + srow) * CIN + (KT)*64 + sseg*16;              \
        br[0] = *(const uint4*)(BT + bo);                                       \
        br[1] = *(const uint4*)(BT + bo + 8); }

    GM_ISSUE(0)
    for (int kt = 0; kt < 8; ++kt) {
        __syncthreads();
        {   // stage-time f32 -> fp16 (proven stage-convert pattern)
            float av[16];
            *(float4*)&av[0]  = ar[0];
            *(float4*)&av[4]  = ar[1];
            *(float4*)&av[8]  = ar[2];
            *(float4*)&av[12] = ar[3];
            half8 h0, h1;
            #pragma unroll
            for (int e = 0; e < 8; ++e) {
                h0[e] = (_Float16)av[e];
                h1[e] = (_Float16)av[e + 8];
            }
            *(half8*)&As[srow][sc0] = h0;
            *(half8*)&As[srow][sc1] = h1;
        }
        *(uint4*)&Bs[srow][sc0] = br[0];
        *(uint4*)&Bs[srow][sc1] = br[1];
        if (kt + 1 < 8) GM_ISSUE(kt + 1)
        __syncthreads();
        #pragma unroll
        for (int ks = 0; ks < 2; ++ks) {
            const int rcol = SWZ(lm, ks*32 + lg*8);
            half8 af[2], bf[2];
            #pragma unroll
            for (int mf = 0; mf < 2; ++mf)
                af[mf] = *(const half8*)&As[wm*32 + mf*16 + lm][rcol];
            #pragma unroll
            for (int nf = 0; nf < 2; ++nf)
                bf[nf] = *(const half8*)&Bs[wn*32 + nf*16 + lm][rcol];
            #pragma unroll
            for (int mf = 0; mf < 2; ++mf)
                #pragma unroll
                for (int nf = 0; nf < 2; ++nf)
                    acc[mf][nf] = __builtin_amdgcn_mfma_f32_16x16x32_f16(af[mf], bf[nf], acc[mf][nf], 0, 0, 0);
        }
    }
    #pragma unroll
    for (int mf = 0; mf < 2; ++mf)
        #pragma unroll
        for (int nf = 0; nf < 2; ++nf)
            #pragma unroll
            for (int r = 0; r < 4; ++r)
                C[(size_t)(bm + wm*32 + mf*16 + lg*4 + r) * CIN + bn + wn*32 + nf*16 + lm]
                    = acc[mf][nf][r];
    #undef GM_ISSUE
}

// ------- fused qkv prep (fp16): l2norm Q,K -> fp16; V transposed+perm fp16 -
__global__ __launch_bounds__(256) void qkv_prep_kernel(
    const float* __restrict__ qkv,
    _Float16* __restrict__ Q16, _Float16* __restrict__ K16,
    _Float16* __restrict__ Vt16)
{
    __shared__ float Vf[64][65];
    const int id = blockIdx.x;
    const int bh = id >> 5, nt = id & 31;
    const int b = bh >> 3, h = bh & 7;
    const int n0 = nt * 64;
    const int tid = threadIdx.x;
    {
        const int row = tid >> 2, dseg = tid & 3;
        const float* src = qkv + ((size_t)(b * NSEQ + n0 + row)) * QKV3
                         + h * 192 + dseg * 48;
        float f[48];
        #pragma unroll
        for (int i = 0; i < 12; ++i)
            *(float4*)&f[i*4] = *(const float4*)(src + i*4);
        float nq = 0.f, nk = 0.f;
        #pragma unroll
        for (int e = 0; e < 16; ++e) {
            nq = fmaf(f[3*e], f[3*e], nq);
            nk = fmaf(f[3*e+1], f[3*e+1], nk);
        }
        nq += __shfl_xor(nq, 1); nq += __shfl_xor(nq, 2);
        nk += __shfl_xor(nk, 1); nk += __shfl_xor(nk, 2);
        float rq = 1.f / fmaxf(sqrtf(nq), 1e-12f);
        float rk = 1.f / fmaxf(sqrtf(nk), 1e-12f);
        _Float16 q16[16], k16[16];
        #pragma unroll
        for (int e = 0; e < 16; ++e) {
            q16[e] = (_Float16)(f[3*e] * rq);
            k16[e] = (_Float16)(f[3*e+1] * rk);
            Vf[dseg*16 + e][row] = f[3*e+2];
        }
        size_t o = ((size_t)bh * NSEQ + n0 + row) * DIM + dseg * 16;
        *(uint4*)(Q16 + o)     = *(uint4*)&q16[0];
        *(uint4*)(Q16 + o + 8) = *(uint4*)&q16[8];
        *(uint4*)(K16 + o)     = *(uint4*)&k16[0];
        *(uint4*)(K16 + o + 8) = *(uint4*)&k16[8];
    }
    __syncthreads();
    {   // Vt[bh][d][n] with the PV fragment j-permutation (within 32-blocks)
        const int d = tid >> 2, seg = tid & 3;
        _Float16 tv[16];
        #pragma unroll
        for (int t = 0; t < 16; ++t) {
            int p = seg * 16 + t;
            int s = (p & 35) | ((p & 4) << 2) | ((p >> 1) & 12);
            tv[t] = (_Float16)Vf[d][s];
        }
        size_t o = ((size_t)bh * DIM + d) * NSEQ + n0 + seg * 16;
        *(uint4*)(Vt16 + o)     = *(uint4*)&tv[0];
        *(uint4*)(Vt16 + o + 8) = *(uint4*)&tv[8];
    }
}

// ---------------- MFMA flash attention v9: single-term fp16 (R14-proven) --
__global__ __launch_bounds__(256, 3) void attn_mfma_kernel(
    const _Float16* __restrict__ Q16, const _Float16* __restrict__ K16,
    const _Float16* __restrict__ Vt16,
    const float* __restrict__ bias, const float* __restrict__ temp_p,
    const uint8_t* __restrict__ mask,
    float* __restrict__ Opart, float* __restrict__ Ml,
    int ns, int base, int rem)
{
    __shared__ _Float16 Ks[2][32][72];   // [buf][j][d]   9,216 B
    __shared__ _Float16 Vs[2][64][36];   // [buf][d][j']  9,216 B

    const int id = blockIdx.x;
    const int h = id & 7;                  // XCD-grouped
    const int rest = id >> 3;
    const int per_b = 16 * ns;
    const int b = rest / per_b;
    const int r2 = rest - b * per_b;
    const int js = r2 >> 4;
    const int qt = r2 & 15;
    const int bh = b * 8 + h;
    const int i0 = qt * 128;
    const int tid = threadIdx.x;
    const int wave = tid >> 6, lane = tid & 63;
    const int lg = lane >> 4, lm = lane & 15;
    const int qbase = i0 + wave * 32;
    const float temp = *temp_p;
    const int krow = tid >> 3, kseg = tid & 7;
    const int vrow = tid >> 2, vseg = tid & 3;

    half8 qf[2][2];
    #pragma unroll
    for (int m = 0; m < 2; ++m) {
        size_t qo = ((size_t)(bh * NSEQ + qbase + 16*m + lm)) * DIM + lg * 8;
        qf[m][0] = *(const half8*)(Q16 + qo);
        qf[m][1] = *(const half8*)(Q16 + qo + 32);
    }
    bool rowm[2];
    rowm[0] = mask[(size_t)b * NSEQ + qbase + lm] != 0;
    rowm[1] = mask[(size_t)b * NSEQ + qbase + 16 + lm] != 0;
    const bool nomaskrow = __all(!rowm[0] && !rowm[1]);

    const float* bp0 = bias + ((size_t)h * NSEQ + qbase + lm) * NSEQ;
    const float* bp1 = bp0 + (size_t)16 * NSEQ;
    const int lgo = lg * 4;

    float m_r[2] = {-FLT_MAX, -FLT_MAX};
    float l_r[2] = {0.f, 0.f};
    f32x4 oa[2][4];
    #pragma unroll
    for (int m = 0; m < 2; ++m)
        #pragma unroll
        for (int dt = 0; dt < 4; ++dt) oa[m][dt] = (f32x4){0.f,0.f,0.f,0.f};

    const int NT = base + (js < rem ? 1 : 0);
    const int tstart = js * base + (js < rem ? js : rem);
    const int jbase = tstart * 32;
    uint4 skh, svh;

    #define A_ISSUE(J0) {                                                      \
        size_t gk = ((size_t)(bh * NSEQ) + (J0) + krow) * DIM + kseg*8;        \
        size_t gv = ((size_t)(bh * DIM) + vrow) * NSEQ + (J0) + vseg*8;        \
        skh = *(const uint4*)(K16  + gk);                                      \
        svh = *(const uint4*)(Vt16 + gv); }
    #define STAGE(BUF) {                                                       \
        *(uint4*)&Ks[BUF][krow][kseg*8] = skh;                                 \
        *(uint4*)&Vs[BUF][vrow][vseg*8] = svh; }

    A_ISSUE(jbase)
    STAGE(0)
    A_ISSUE(jbase + 32)
    float4 bb[2][2];
    #pragma unroll
    for (int jt = 0; jt < 2; ++jt) {
        bb[0][jt] = *(const float4*)(bp0 + jbase + jt*16 + lgo);
        bb[1][jt] = *(const float4*)(bp1 + jbase + jt*16 + lgo);
    }
    uint8_t mk = mask[(size_t)b * NSEQ + jbase + (lane & 31)];
    __syncthreads();

    #pragma unroll 2
    for (int t = 0; t < NT; ++t) {
        const int cur = t & 1;
        const int j0 = jbase + t * 32;

        float4 bbn[2][2];
        uint8_t mkn = 0;
        if (t + 1 < NT) {
            #pragma unroll
            for (int jt = 0; jt < 2; ++jt) {
                bbn[0][jt] = *(const float4*)(bp0 + j0 + 32 + jt*16 + lgo);
                bbn[1][jt] = *(const float4*)(bp1 + j0 + 32 + jt*16 + lgo);
            }
            mkn = mask[(size_t)b * NSEQ + j0 + 32 + (lane & 31)];
            STAGE(cur ^ 1)
            if (t + 2 < NT) A_ISSUE(j0 + 64)
        }
        unsigned long long bal = __ballot(mk != 0);

        f32x4 sac[2][2];
        #pragma unroll
        for (int m = 0; m < 2; ++m)
            #pragma unroll
            for (int jt = 0; jt < 2; ++jt) sac[m][jt] = (f32x4){0.f,0.f,0.f,0.f};
        __builtin_amdgcn_s_setprio(1);
        #pragma unroll
        for (int jt = 0; jt < 2; ++jt)
            #pragma unroll
            for (int ks = 0; ks < 2; ++ks) {
                half8 kb = *(const half8*)(&Ks[cur][jt*16 + lm][ks*32 + lg*8]);
                #pragma unroll
                for (int m = 0; m < 2; ++m)
                    sac[m][jt] = __builtin_amdgcn_mfma_f32_16x16x32_f16(kb, qf[m][ks], sac[m][jt], 0, 0, 0);
            }
        __builtin_amdgcn_s_setprio(0);

        half8 pah[2];
        #pragma unroll
        for (int m = 0; m < 2; ++m) {
            const float4* bbm = bb[m];
            float sv[2][4];
            if (nomaskrow && bal == 0) {
                #pragma unroll
                for (int jt = 0; jt < 2; ++jt) {
                    sv[jt][0] = fmaf(sac[m][jt][0], temp, bbm[jt].x);
                    sv[jt][1] = fmaf(sac[m][jt][1], temp, bbm[jt].y);
                    sv[jt][2] = fmaf(sac[m][jt][2], temp, bbm[jt].z);
                    sv[jt][3] = fmaf(sac[m][jt][3], temp, bbm[jt].w);
                }
            } else {
                #pragma unroll
                for (int jt = 0; jt < 2; ++jt) {
                    unsigned int nib = (unsigned int)(bal >> (jt*16 + lg*4)) & 0xFu;
                    #pragma unroll
                    for (int r = 0; r < 4; ++r) {
                        bool dead = rowm[m] || ((nib >> r) & 1u);
                        float bv = (r == 0) ? bbm[jt].x : (r == 1) ? bbm[jt].y
                                 : (r == 2) ? bbm[jt].z : bbm[jt].w;
                        sv[jt][r] = dead ? -FLT_MAX : fmaf(sac[m][jt][r], temp, bv);
                    }
                }
            }
            float pmax = fmaxf(fmaxf(fmaxf(sv[0][0], sv[0][1]), fmaxf(sv[0][2], sv[0][3])),
                               fmaxf(fmaxf(sv[1][0], sv[1][1]), fmaxf(sv[1][2], sv[1][3])));
            pmax = fmaxf(pmax, __shfl_xor(pmax, 16));
            pmax = fmaxf(pmax, __shfl_xor(pmax, 32));
            if (!__all(pmax <= m_r[m] + 8.f)) {
                float mn = fmaxf(m_r[m], pmax);
                float sc = __expf(m_r[m] - mn);
                m_r[m] = mn;
                l_r[m] *= sc;
                #pragma unroll
                for (int r = 0; r < 4; ++r) {
                    float sq = __shfl(sc, lg*4 + r);
                    #pragma unroll
                    for (int dt = 0; dt < 4; ++dt) oa[m][dt][r] *= sq;
                }
            }
            float rs = 0.f;
            #pragma unroll
            for (int jt = 0; jt < 2; ++jt)
                #pragma unroll
                for (int r = 0; r < 4; ++r) {
                    float pf = __expf(sv[jt][r] - m_r[m]);
                    _Float16 p16 = (_Float16)pf;
                    rs += (float)p16;            // l consistent with fp16 P
                    pah[m][jt*4 + r] = p16;
                }
            rs += __shfl_xor(rs, 16);
            rs += __shfl_xor(rs, 32);
            l_r[m] += rs;
        }

        __builtin_amdgcn_s_setprio(1);
        #pragma unroll
        for (int dt = 0; dt < 4; ++dt) {
            half8 vb = *(const half8*)(&Vs[cur][dt*16 + lm][lg*8]);
            #pragma unroll
            for (int m = 0; m < 2; ++m)
                oa[m][dt] = __builtin_amdgcn_mfma_f32_16x16x32_f16(pah[m], vb, oa[m][dt], 0, 0, 0);
        }
        __builtin_amdgcn_s_setprio(0);
        __syncthreads();
        #pragma unroll
        for (int m = 0; m < 2; ++m)
            #pragma unroll
            for (int jt = 0; jt < 2; ++jt) bb[m][jt] = bbn[m][jt];
        mk = mkn;
    }
    #undef A_ISSUE
    #undef STAGE

    #pragma unroll
    for (int m = 0; m < 2; ++m)
        #pragma unroll
        for (int dt = 0; dt < 4; ++dt)
            #pragma unroll
            for (int r = 0; r < 4; ++r)
                Opart[((size_t)(js*16 + bh) * NSEQ + qbase + 16*m + lg*4 + r) * 64
                      + dt*16 + lm] = oa[m][dt][r];
    if (lane < 16) {
        #pragma unroll
        for (int m = 0; m < 2; ++m) {
            size_t mi = ((size_t)(js*16 + bh) * NSEQ + qbase + 16*m + lm) * 2;
            Ml[mi]     = m_r[m];
            Ml[mi + 1] = l_r[m];
        }
    }
}

extern "C" void kernel_launch(void* const* d_in, const int* in_sizes, int n_in,
                              void* d_out, int out_size, void* d_ws, size_t ws_size,
                              hipStream_t stream)
{
    const float*   x        = (const float*)d_in[0];
    const float*   w_qkv    = (const float*)d_in[1];
    const float*   w_out    = (const float*)d_in[2];
    const float*   pos_bias = (const float*)d_in[3];
    const float*   temp     = (const float*)d_in[4];
    const uint8_t* mask     = (const uint8_t*)d_in[5];
    float* out = (float*)d_out;

    const int M = BATCH * NSEQ;                        // 4096
    const size_t NE = (size_t)BATCH * HEADS * NSEQ * DIM;
    const int ns = 3;                                  // grid 768 = 3 blocks/CU exactly
    const int base = 64 / ns, rem = 64 % ns;

    char* ws = (char*)d_ws;
    // region 0 (25.2 MB): qkv_lin f32; exactly reused by the 3-split f32 Opart
    float* qkv_lin = (float*)ws;
    float* OpartP  = (float*)ws;    // 3*16*2048*64*4 B == M*QKV3*4 B exactly
    size_t off = (size_t)M * QKV3 * 4;
    // region 1: fp16 transposed weights + Ml
    _Float16* WqkvT = (_Float16*)(ws + off); off += (size_t)QKV3 * CIN * 2;
    _Float16* WoutT = (_Float16*)(ws + off); off += (size_t)HD * CIN * 2;
    float*    MlP   = (float*)(ws + off);    off += (size_t)ns * 16 * NSEQ * 2 * 4;
    // region 2 (12.6 MB): Q16/K16/Vt16 fp16
    char* reg2 = ws + off;
    _Float16* Q16  = (_Float16*)reg2;
    _Float16* K16  = Q16 + NE;
    _Float16* Vt16 = K16 + NE;

    // 1. both weight converts in one launch
    cvt_wT_kernel<<<dim3(32, CIN/64), 256, 0, stream>>>(
        w_qkv, w_out, WqkvT, WoutT);
    // 2. qkv projection (fp16 single-term GEMM)
    gemm_f16_kernel<<<dim3(QKV3/64, M/128), 256, 0, stream>>>(
        x, WqkvT, qkv_lin, M, QKV3, CIN);
    // 3. fused l2norm + V transpose -> fp16
    qkv_prep_kernel<<<dim3(BATCH * HEADS * (NSEQ/64)), 256, 0, stream>>>(
        qkv_lin, Q16, K16, Vt16);
    // 4. attention (fp16 single-term; Opart overwrites qkv_lin)
    attn_mfma_kernel<<<dim3(256 * ns), 256, 0, stream>>>(
        Q16, K16, Vt16, pos_bias, temp, mask, OpartP, MlP, ns, base, rem);
    // 5. out projection with fused 3-way merge (fp16)
    gemm_merge_kernel<<<dim3(CIN/64, M/64), 256, 0, stream>>>(
        OpartP, MlP, WoutT, out);
}